// Round 9
// baseline (1054.413 us; speedup 1.0000x reference)
//
#include <hip/hip_runtime.h>

#define NN 50000
#define EE 800000
#define GG 64
#define FF 128
#define NBES 8
#define RECW 24   // floats per edge record: eb[8], db[8], s0, s1, x, y, z, inv_r, snd, rcv
#define RMAXF 5.0f
#define PI_F 3.14159265358979323846f

// spherical harmonic constants
#define S3  1.7320508075688772f
#define S5  2.23606797749979f
#define S15 3.872983346207417f
#define C1c 2.091650066335189f   // sqrt(35/8)
#define C2c 10.246950765959598f  // sqrt(105)
#define C3c 1.62018517460196f    // sqrt(21/8)
#define C4c 1.3228756555322954f  // sqrt(7)/2
#define C5c 5.123475382979799f   // sqrt(105)/2
#define CCB 0.6324555320336759f  // sqrt(2/5)

__device__ __forceinline__ float shc_s(float x, float y, float z, const float* __restrict__ w) {
    float x2 = x * x, y2 = y * y, z2 = z * z;
    return w[0]
        + w[1] * (S3 * x) + w[2] * (S3 * y) + w[3] * (S3 * z)
        + w[4] * (S15 * x * y) + w[5] * (S15 * y * z) + w[6] * (0.5f * S5 * (3.f * z2 - 1.f))
        + w[7] * (S15 * x * z) + w[8] * (0.5f * S15 * (x2 - y2))
        + w[9] * (C1c * y * (3.f * x2 - y2)) + w[10] * (C2c * x * y * z)
        + w[11] * (C3c * y * (5.f * z2 - 1.f)) + w[12] * (C4c * z * (5.f * z2 - 3.f))
        + w[13] * (C3c * x * (5.f * z2 - 1.f)) + w[14] * (C5c * z * (x2 - y2))
        + w[15] * (C1c * x * (x2 - 3.f * y2));
}

__device__ __forceinline__ void shc_grad(float x, float y, float z, const float* __restrict__ w,
                                         float& gx, float& gy, float& gz) {
    float x2 = x * x, y2 = y * y, z2 = z * z;
    gx = w[1] * S3 + w[4] * (S15 * y) + w[7] * (S15 * z) + w[8] * (S15 * x)
       + w[9] * (6.f * C1c * x * y) + w[10] * (C2c * y * z) + w[13] * (C3c * (5.f * z2 - 1.f))
       + w[14] * (2.f * C5c * x * z) + w[15] * (3.f * C1c * (x2 - y2));
    gy = w[2] * S3 + w[4] * (S15 * x) + w[5] * (S15 * z) - w[8] * (S15 * y)
       + w[9] * (3.f * C1c * (x2 - y2)) + w[10] * (C2c * x * z) + w[11] * (C3c * (5.f * z2 - 1.f))
       - w[14] * (2.f * C5c * y * z) - w[15] * (6.f * C1c * x * y);
    gz = w[3] * S3 + w[5] * (S15 * y) + w[6] * (3.f * S5 * z) + w[7] * (S15 * x)
       + w[10] * (C2c * x * y) + w[11] * (10.f * C3c * y * z) + w[12] * (C4c * (15.f * z2 - 3.f))
       + w[13] * (10.f * C3c * x * z) + w[14] * (C5c * (x2 - y2));
}

// -------------------- CSR build (rcv only) --------------------

__global__ __launch_bounds__(256) void count_kernel(const int* __restrict__ ei,
                                                    int* __restrict__ cnt) {
    int e = blockIdx.x * 256 + threadIdx.x;
    if (e >= EE) return;
    atomicAdd(&cnt[ei[EE + e]], 1);
}

// single block, chunked scan of cnt[NN] -> off[NN+1]
__global__ __launch_bounds__(256) void scan_kernel(const int* __restrict__ cnt,
                                                   int* __restrict__ off) {
    __shared__ int wsum[4];
    __shared__ int carry_s;
    if (threadIdx.x == 0) carry_s = 0;
    __syncthreads();
    int lane = threadIdx.x & 63;
    int wid = threadIdx.x >> 6;
    for (int base = 0; base < NN; base += 256) {
        int i = base + threadIdx.x;
        int v = (i < NN) ? cnt[i] : 0;
        int x = v;
#pragma unroll
        for (int d = 1; d < 64; d <<= 1) {
            int y = __shfl_up(x, d);
            if (lane >= d) x += y;
        }
        if (lane == 63) wsum[wid] = x;
        __syncthreads();
        int pre = 0;
#pragma unroll
        for (int w = 0; w < 4; w++) if (w < wid) pre += wsum[w];
        int total = wsum[0] + wsum[1] + wsum[2] + wsum[3];
        int carry = carry_s;
        if (i < NN) off[i] = carry + pre + x - v;
        __syncthreads();
        if (threadIdx.x == 0) carry_s = carry + total;
        __syncthreads();
    }
    if (threadIdx.x == 0) off[NN] = carry_s;
}

// perm[slot] = edge id (rcv-CSR order)
__global__ __launch_bounds__(256) void fill_kernel(const int* __restrict__ ei,
                                                   const int* __restrict__ off,
                                                   int* __restrict__ cur,
                                                   int* __restrict__ perm) {
    int e = blockIdx.x * 256 + threadIdx.x;
    if (e >= EE) return;
    int rcv = ei[EE + e];
    int slot = off[rcv] + atomicAdd(&cur[rcv], 1);
    perm[slot] = e;
}

// -------------------- geometry: thread = CSR slot, gather edge, write coalesced -------

__global__ __launch_bounds__(256) void edge_geom(const float* __restrict__ pos,
                                                 const float* __restrict__ shifts,
                                                 const int* __restrict__ ei,
                                                 const float* __restrict__ wsh,
                                                 const int* __restrict__ perm,
                                                 float* __restrict__ rec,
                                                 float* __restrict__ E1) {
    int j = blockIdx.x * 256 + threadIdx.x;
    if (j >= EE) return;
    int e = perm[j];
    int snd = ei[e];
    int rcv = ei[EE + e];
    float vx = pos[rcv * 3 + 0] - pos[snd * 3 + 0] + shifts[e * 3 + 0];
    float vy = pos[rcv * 3 + 1] - pos[snd * 3 + 1] + shifts[e * 3 + 1];
    float vz = pos[rcv * 3 + 2] - pos[snd * 3 + 2] + shifts[e * 3 + 2];
    float r2 = vx * vx + vy * vy + vz * vz + 1e-12f;
    float r = sqrtf(r2);
    float inv_r = 1.0f / r;
    float x = vx * inv_r, y = vy * inv_r, z = vz * inv_r;
    float valid = (r < RMAXF) ? 1.f : 0.f;

    float s0 = shc_s(x, y, z, wsh);
    float s1v = shc_s(x, y, z, wsh + 16);

    float u = r * (1.0f / RMAXF);
    float th = PI_F * u;
    float s1 = sinf(th), c1 = cosf(th);
    float u2 = u * u, u3 = u2 * u, u5 = u2 * u3, u6 = u3 * u3, u7 = u6 * u, u8 = u6 * u2;
    float env = (1.f - 28.f * u6 + 48.f * u7 - 21.f * u8) * valid;
    float denv = (-168.f * u5 + 336.f * u6 - 168.f * u7) * (1.0f / RMAXF) * valid;
    float sk = s1, skm = 0.f, ck = c1, ckm = 1.f;
    float tc = 2.f * c1;
    float ebv[NBES], dbv[NBES];
#pragma unroll
    for (int k = 1; k <= NBES; k++) {
        float b = CCB * sk * inv_r;
        ebv[k - 1] = b * env;
        dbv[k - 1] = CCB * (((float)k * PI_F * (1.0f / RMAXF)) * ck * inv_r
                            - sk * inv_r * inv_r) * env
                     + b * denv;
        float sn = tc * sk - skm; skm = sk; sk = sn;
        float cn = tc * ck - ckm; ckm = ck; ck = cn;
    }

    // E1[n,k] = sum_{e: snd=n} eb[k] * s1
#pragma unroll
    for (int k = 0; k < NBES; k++)
        atomicAdd(&E1[(size_t)snd * 8 + k], ebv[k] * s1v);

    float* rc = rec + (size_t)j * RECW;
    *(float4*)&rc[0]  = make_float4(ebv[0], ebv[1], ebv[2], ebv[3]);
    *(float4*)&rc[4]  = make_float4(ebv[4], ebv[5], ebv[6], ebv[7]);
    *(float4*)&rc[8]  = make_float4(dbv[0], dbv[1], dbv[2], dbv[3]);
    *(float4*)&rc[12] = make_float4(dbv[4], dbv[5], dbv[6], dbv[7]);
    *(float4*)&rc[16] = make_float4(s0, s1v, x, y);
    *(float4*)&rc[20] = make_float4(z, inv_r, __int_as_float(snd), __int_as_float(rcv));
}

// -------------------- small precomputes --------------------

__global__ __launch_bounds__(128) void a1_kernel(const float* __restrict__ Wout1,
                                                 const float* __restrict__ wread1,
                                                 const float* __restrict__ Wskip1,
                                                 const float* __restrict__ ae,
                                                 float* __restrict__ a1,
                                                 float* __restrict__ askip) {
    int f = threadIdx.x;
    float s = 0.f;
    for (int k = 0; k < FF; k++) s += Wout1[f * FF + k] * wread1[k];
    a1[f] = s;
    if (f < 10) {
        float t = 0.f;
        for (int k = 0; k < FF; k++) t += Wskip1[f * FF + k] * wread1[k];
        askip[f] = t + ae[f];
    }
}

// c0[f'] = sum_f wread0[f] Wout0[f',f];  D[k,f'] = sum_f a1[f] Wr1[k,f] Wout0[f',f]
__global__ __launch_bounds__(128) void cd_kernel(const float* __restrict__ Wout0,
                                                 const float* __restrict__ wread0,
                                                 const float* __restrict__ a1,
                                                 const float* __restrict__ Wr1,
                                                 float* __restrict__ c0,
                                                 float* __restrict__ D) {
    int fp = threadIdx.x;
    float c = 0.f;
    float d[NBES];
#pragma unroll
    for (int k = 0; k < NBES; k++) d[k] = 0.f;
    for (int f = 0; f < FF; f++) {
        float w = Wout0[fp * FF + f];
        c += wread0[f] * w;
        float aw = a1[f] * w;
#pragma unroll
        for (int k = 0; k < NBES; k++) d[k] += aw * Wr1[k * FF + f];
    }
    c0[fp] = c;
#pragma unroll
    for (int k = 0; k < NBES; k++) D[k * FF + fp] = d[k];
}

// GW[p=a*8+k][f'] = sum_f W_emb[a,f] Wr0[k,f] Wout0[f,f']
__global__ __launch_bounds__(256) void gw_kernel(const float* __restrict__ W_emb,
                                                 const float* __restrict__ Wr0,
                                                 const float* __restrict__ Wout0,
                                                 float* __restrict__ GW) {
    int idx = blockIdx.x * 256 + threadIdx.x;
    if (idx >= 80 * FF) return;
    int fp = idx & 127;
    int p = idx >> 7;
    int a = p >> 3, k = p & 7;
    float s = 0.f;
    for (int f = 0; f < FF; f++)
        s += W_emb[a * FF + f] * Wr0[k * FF + f] * Wout0[f * FF + fp];
    GW[p * FF + fp] = s;
}

// T[k'][p0=k*10+a] = sum_f D[k',f] W_emb[a,f] Wr0[k,f];  Mc[p0] = sum_f c0[f] W_emb Wr0
__global__ __launch_bounds__(256) void tmc_kernel(const float* __restrict__ D,
                                                  const float* __restrict__ c0,
                                                  const float* __restrict__ W_emb,
                                                  const float* __restrict__ Wr0,
                                                  float* __restrict__ T,
                                                  float* __restrict__ Mc) {
    for (int i = threadIdx.x; i < 720; i += 256) {
        if (i < 640) {
            int kp = i / 80;
            int p0 = i - kp * 80;
            int k = p0 / 10, a = p0 - k * 10;
            float s = 0.f;
            for (int f = 0; f < FF; f++)
                s += D[kp * FF + f] * W_emb[a * FF + f] * Wr0[k * FF + f];
            T[i] = s;
        } else {
            int p0 = i - 640;
            int k = p0 / 10, a = p0 - k * 10;
            float s = 0.f;
            for (int f = 0; f < FF; f++)
                s += c0[f] * W_emb[a * FF + f] * Wr0[k * FF + f];
            Mc[p0] = s;
        }
    }
}

// -------------------- P0[n, p=a*8+k] = sum_{e:rcv=n} attrs[snd,a] eb[e,k] s0_e --------

#define P0_BLOCKS 2048
__global__ __launch_bounds__(256) void p0_kernel(const float* __restrict__ rec,
                                                 const int* __restrict__ off,
                                                 const float* __restrict__ attrs,
                                                 float* __restrict__ P0) {
    int wv = (blockIdx.x * 256 + threadIdx.x) >> 6;
    int lane = threadIdx.x & 63;
    int nwaves = P0_BLOCKS * 4;
    int a_lo = lane >> 3;
    int k_l = lane & 7;

    for (int n = wv; n < NN; n += nwaves) {
        int beg = off[n], end = off[n + 1];
        float acc = 0.f, acc2 = 0.f;
        for (int j = beg; j < end; j++) {
            const float* rc = rec + (size_t)j * RECW;
            float s0 = rc[16];
            int snd = __float_as_int(rc[22]);
            float eb = rc[k_l];
            float es = eb * s0;
            acc += attrs[snd * 10 + a_lo] * es;
            if (lane < 16) acc2 += attrs[snd * 10 + 8 + a_lo] * es;
        }
        P0[(size_t)n * 80 + lane] = acc;
        if (lane < 16) P0[(size_t)n * 80 + 64 + lane] = acc2;
    }
}

// -------------------- h1 GEMM: h1 = P0 @ GW + attrs @ Wskip0 ; node_e = h1.wread0 ------

#define GEMM_BLOCKS 512
__global__ __launch_bounds__(256, 2) void h1_gemm(const float* __restrict__ P0,
                                                  const float* __restrict__ GW,
                                                  const float* __restrict__ attrs,
                                                  const float* __restrict__ Wskip,
                                                  const float* __restrict__ wread,
                                                  float* __restrict__ h1,
                                                  float* __restrict__ node_e) {
    __shared__ float sb[80][FF];   // 40 KB
    __shared__ float sa[32][80];   // 10 KB
    int t = threadIdx.x;
#pragma unroll
    for (int j = 0; j < 10; j++) {
        int flat4 = j * 256 + t;     // 0..2559
        int row = flat4 >> 5;
        int col = (flat4 & 31) * 4;
        *(float4*)&sb[row][col] = *(const float4*)&GW[row * FF + col];
    }

    int g = t >> 5;
    int f0 = (t & 31) * 4;
    const int NTILES = (NN + 31) / 32;

    for (int tile = blockIdx.x; tile < NTILES; tile += GEMM_BLOCKS) {
        __syncthreads();
#pragma unroll
        for (int j = 0; j < 3; j++) {
            int flat4 = j * 256 + t;   // need 640
            if (flat4 < 640) {
                int row = flat4 / 20;
                int col = (flat4 - row * 20) * 4;
                int n = tile * 32 + row;
                float4 v = make_float4(0.f, 0.f, 0.f, 0.f);
                if (n < NN) v = *(const float4*)&P0[(size_t)n * 80 + col];
                *(float4*)&sa[row][col] = v;
            }
        }
        __syncthreads();

        float acc[4][4];
#pragma unroll
        for (int i = 0; i < 4; i++)
#pragma unroll
            for (int j = 0; j < 4; j++) acc[i][j] = 0.f;

        for (int kk = 0; kk < 80; kk += 4) {
            float4 bv0 = *(const float4*)&sb[kk + 0][f0];
            float4 bv1 = *(const float4*)&sb[kk + 1][f0];
            float4 bv2 = *(const float4*)&sb[kk + 2][f0];
            float4 bv3 = *(const float4*)&sb[kk + 3][f0];
#pragma unroll
            for (int ni = 0; ni < 4; ni++) {
                float4 av = *(const float4*)&sa[g * 4 + ni][kk];
                acc[ni][0] += av.x * bv0.x + av.y * bv1.x + av.z * bv2.x + av.w * bv3.x;
                acc[ni][1] += av.x * bv0.y + av.y * bv1.y + av.z * bv2.y + av.w * bv3.y;
                acc[ni][2] += av.x * bv0.z + av.y * bv1.z + av.z * bv2.z + av.w * bv3.z;
                acc[ni][3] += av.x * bv0.w + av.y * bv1.w + av.z * bv2.w + av.w * bv3.w;
            }
        }

#pragma unroll
        for (int ni = 0; ni < 4; ni++) {
            int n = tile * 32 + g * 4 + ni;
            bool valid = (n < NN);
#pragma unroll
            for (int a = 0; a < 10; a++) {
                float att = valid ? attrs[n * 10 + a] : 0.f;
                float4 wk = *(const float4*)&Wskip[a * FF + f0];
                acc[ni][0] += att * wk.x;
                acc[ni][1] += att * wk.y;
                acc[ni][2] += att * wk.z;
                acc[ni][3] += att * wk.w;
            }
            if (valid) {
                float4 out;
                out.x = acc[ni][0]; out.y = acc[ni][1];
                out.z = acc[ni][2]; out.w = acc[ni][3];
                *(float4*)&h1[(size_t)n * FF + f0] = out;
            }
            float4 wv = *(const float4*)&wread[f0];
            float p = acc[ni][0] * wv.x + acc[ni][1] * wv.y
                    + acc[ni][2] * wv.z + acc[ni][3] * wv.w;
#pragma unroll
            for (int o = 16; o > 0; o >>= 1) p += __shfl_xor(p, o);
            if (valid && (t & 31) == 0) node_e[n] = p;
        }
    }
}

// -------------------- t1[n,k] = sum_f a1[f] h1[n,f] Wr1[k,f] --------------------

__global__ __launch_bounds__(256) void t1_kernel(const float* __restrict__ h1,
                                                 const float* __restrict__ a1,
                                                 const float* __restrict__ Wr1,
                                                 float* __restrict__ t1) {
    int w = threadIdx.x >> 6;
    int lane = threadIdx.x & 63;
    int n = blockIdx.x * 4 + w;
    if (n >= NN) return;
    int f0 = lane, f1 = lane + 64;
    float v0 = a1[f0] * h1[(size_t)n * FF + f0];
    float v1 = a1[f1] * h1[(size_t)n * FF + f1];
    float p[NBES];
#pragma unroll
    for (int k = 0; k < NBES; k++)
        p[k] = v0 * Wr1[k * FF + f0] + v1 * Wr1[k * FF + f1];
#pragma unroll
    for (int o = 32; o > 0; o >>= 1) {
#pragma unroll
        for (int k = 0; k < NBES; k++) p[k] += __shfl_xor(p[k], o);
    }
    if (lane == 0) {
        *(float4*)&t1[(size_t)n * 8]     = make_float4(p[0], p[1], p[2], p[3]);
        *(float4*)&t1[(size_t)n * 8 + 4] = make_float4(p[4], p[5], p[6], p[7]);
    }
}

// -------------------- M[n][p0=k*10+a] = Mc + sum_k' E1[n,k'] T[k'][p0] ----------------

__global__ __launch_bounds__(256) void m_kernel(const float* __restrict__ E1,
                                                const float* __restrict__ T,
                                                const float* __restrict__ Mc,
                                                float* __restrict__ M) {
    __shared__ float sT[720];
    int t = threadIdx.x;
    for (int i = t; i < 720; i += 256) sT[i] = (i < 640) ? T[i] : Mc[i - 640];
    __syncthreads();
    int n = blockIdx.x * 256 + t;
    if (n >= NN) return;
    float4 ea = *(const float4*)&E1[(size_t)n * 8];
    float4 eb = *(const float4*)&E1[(size_t)n * 8 + 4];
    float e1v[8] = {ea.x, ea.y, ea.z, ea.w, eb.x, eb.y, eb.z, eb.w};
#pragma unroll
    for (int c = 0; c < 20; c++) {
        float4 m = *(const float4*)&sT[640 + c * 4];
#pragma unroll
        for (int kp = 0; kp < 8; kp++) {
            float4 tv = *(const float4*)&sT[kp * 80 + c * 4];
            m.x += e1v[kp] * tv.x;
            m.y += e1v[kp] * tv.y;
            m.z += e1v[kp] * tv.z;
            m.w += e1v[kp] * tv.w;
        }
        *(float4*)&M[(size_t)n * 80 + c * 4] = m;
    }
}

// -------------------- fused per-edge pass: dsp/drp both layers + energy1 + forces -----

#define EP_BLOCKS 512
__global__ __launch_bounds__(256) void edge_pass(const float* __restrict__ rec,
                                                 const float* __restrict__ t1,
                                                 const float* __restrict__ M,
                                                 const float* __restrict__ attrs,
                                                 const int* __restrict__ batch,
                                                 const float* __restrict__ wsh,
                                                 float* __restrict__ forces,
                                                 float* __restrict__ energy) {
    __shared__ float eacc[GG];
    int t = threadIdx.x;
    int lane = t & 63;
    if (t < GG) eacc[t] = 0.f;
    __syncthreads();

    for (int j0 = blockIdx.x * 256; j0 < EE; j0 += EP_BLOCKS * 256) {
        int j = j0 + t;
        bool act = (j < EE);
        int jc = act ? j : 0;
        const float* rc = rec + (size_t)jc * RECW;
        float4 q0 = *(const float4*)&rc[0];
        float4 q1 = *(const float4*)&rc[4];
        float4 q2 = *(const float4*)&rc[8];
        float4 q3 = *(const float4*)&rc[12];
        float4 q4 = *(const float4*)&rc[16];
        float4 q5 = *(const float4*)&rc[20];
        float eb[8] = {q0.x, q0.y, q0.z, q0.w, q1.x, q1.y, q1.z, q1.w};
        float db[8] = {q2.x, q2.y, q2.z, q2.w, q3.x, q3.y, q3.z, q3.w};
        float s0 = q4.x, s1v = q4.y, x = q4.z, y = q4.w;
        float z = q5.x, ivr = q5.y;
        int snd = __float_as_int(q5.z);
        int rcv = __float_as_int(q5.w);

        // layer 1: dsp1/drp1 via t1[snd]
        float4 ta = *(const float4*)&t1[(size_t)snd * 8];
        float4 tb = *(const float4*)&t1[(size_t)snd * 8 + 4];
        float tg[8] = {ta.x, ta.y, ta.z, ta.w, tb.x, tb.y, tb.z, tb.w};
        float dsp1 = 0.f, drp1 = 0.f;
#pragma unroll
        for (int k = 0; k < 8; k++) {
            dsp1 += eb[k] * tg[k];
            drp1 += db[k] * tg[k];
        }

        // layer 0: t0[k] = sum_a attrs[snd,a] M[rcv,k,a]
        float at[10];
#pragma unroll
        for (int i = 0; i < 5; i++) {
            float2 v = *(const float2*)&attrs[snd * 10 + 2 * i];
            at[2 * i] = v.x; at[2 * i + 1] = v.y;
        }
        const float* Mr = M + (size_t)rcv * 80;
        float dsp0 = 0.f, drp0 = 0.f;
#pragma unroll
        for (int k = 0; k < 8; k++) {
            float t0 = 0.f;
#pragma unroll
            for (int a = 0; a < 10; a++) t0 += at[a] * Mr[k * 10 + a];
            dsp0 += eb[k] * t0;
            drp0 += db[k] * t0;
        }

        // layer-1 energy contribution: s1 * dsp1, grouped by batch[rcv]
        float el = act ? s1v * dsp1 : 0.f;
        int b = act ? batch[rcv] : -1;
        int ub = __builtin_amdgcn_readfirstlane(b);
        if (__all(b == ub)) {
            float es = el;
#pragma unroll
            for (int o = 32; o > 0; o >>= 1) es += __shfl_xor(es, o);
            if (lane == 0 && ub >= 0) atomicAdd(&eacc[ub], es);
        } else {
            if (act) atomicAdd(&eacc[b], el);
        }

        // forces
        float g0x, g0y, g0z, g1x, g1y, g1z;
        shc_grad(x, y, z, wsh, g0x, g0y, g0z);
        shc_grad(x, y, z, wsh + 16, g1x, g1y, g1z);
        float gux = dsp0 * g0x + dsp1 * g1x;
        float guy = dsp0 * g0y + dsp1 * g1y;
        float guz = dsp0 * g0z + dsp1 * g1z;
        float gr = s0 * drp0 + s1v * drp1;
        float dgu = gux * x + guy * y + guz * z;
        float gvx = gr * x + ivr * (gux - dgu * x);
        float gvy = gr * y + ivr * (guy - dgu * y);
        float gvz = gr * z + ivr * (guz - dgu * z);
        if (act) {
            atomicAdd(&forces[snd * 3 + 0], gvx);
            atomicAdd(&forces[snd * 3 + 1], gvy);
            atomicAdd(&forces[snd * 3 + 2], gvz);
            atomicAdd(&forces[rcv * 3 + 0], -gvx);
            atomicAdd(&forces[rcv * 3 + 1], -gvy);
            atomicAdd(&forces[rcv * 3 + 2], -gvz);
        }
    }
    __syncthreads();
    if (t < GG && eacc[t] != 0.f) atomicAdd(&energy[t], eacc[t]);
}

// -------------------- energy finalize: node_e + attrs.askip --------------------

#define EF_BLOCKS 128
__global__ __launch_bounds__(256) void efinal_kernel(const float* __restrict__ node_e,
                                                     const float* __restrict__ attrs,
                                                     const float* __restrict__ askip,
                                                     const int* __restrict__ batch,
                                                     float* __restrict__ energy) {
    __shared__ float eacc[GG];
    int t = threadIdx.x;
    if (t < GG) eacc[t] = 0.f;
    __syncthreads();
    for (int n = blockIdx.x * 256 + t; n < NN; n += EF_BLOCKS * 256) {
        float v = node_e[n];
#pragma unroll
        for (int a = 0; a < 10; a++) v += attrs[n * 10 + a] * askip[a];
        atomicAdd(&eacc[batch[n]], v);
    }
    __syncthreads();
    if (t < GG && eacc[t] != 0.f) atomicAdd(&energy[t], eacc[t]);
}

// -------------------- launch --------------------

extern "C" void kernel_launch(void* const* d_in, const int* in_sizes, int n_in,
                              void* d_out, int out_size, void* d_ws, size_t ws_size,
                              hipStream_t stream) {
    const float* pos    = (const float*)d_in[0];
    const float* attrs  = (const float*)d_in[1];
    const float* shifts = (const float*)d_in[2];
    const int*   ei     = (const int*)d_in[3];
    const int*   batch  = (const int*)d_in[4];
    const float* W_emb  = (const float*)d_in[6];
    const float* ae     = (const float*)d_in[7];
    const float* W_r    = (const float*)d_in[8];   // (2,8,F)
    const float* w_sh   = (const float*)d_in[9];   // (2,16)
    const float* W_out  = (const float*)d_in[10];  // (2,F,F)
    const float* W_skip = (const float*)d_in[11];  // (2,10,F)
    const float* w_read = (const float*)d_in[12];  // (2,F)

    const float* Wr0 = W_r;
    const float* Wr1 = W_r + NBES * FF;
    const float* Wout0 = W_out;
    const float* Wout1 = W_out + FF * FF;

    float* energy = (float*)d_out;
    float* forces = energy + GG;

    float* ws  = (float*)d_ws;
    float* h1  = ws;                        // N*F
    float* P0  = h1 + (size_t)NN * FF;      // N*80
    float* M   = P0 + (size_t)NN * 80;      // N*80
    float* E1  = M + (size_t)NN * 80;       // N*8
    float* t1  = E1 + (size_t)NN * 8;       // N*8
    float* node_e = t1 + (size_t)NN * 8;    // N
    float* rec = node_e + NN;               // EE*24
    float* a1  = rec + (size_t)EE * RECW;   // 128
    float* askip = a1 + FF;                 // 16
    float* c0  = askip + 16;                // 128
    float* D   = c0 + FF;                   // 8*128
    float* GW  = D + NBES * FF;             // 80*128
    float* T   = GW + 80 * FF;              // 640
    float* Mc  = T + 640;                   // 80

    int* cnt = (int*)(Mc + 80);             // N
    int* cur = cnt + NN;                    // N
    int* off = cur + NN;                    // N+1
    int* perm = off + NN + 1;               // EE

    const int edgeBlocks = (EE + 255) / 256;

    hipMemsetAsync(d_out, 0, (size_t)out_size * sizeof(float), stream);
    hipMemsetAsync(E1, 0, (size_t)NN * 8 * sizeof(float), stream);
    hipMemsetAsync(cnt, 0, (size_t)2 * NN * sizeof(int), stream);   // cnt + cur

    // CSR (rcv): perm[slot] = edge
    count_kernel<<<edgeBlocks, 256, 0, stream>>>(ei, cnt);
    scan_kernel<<<1, 256, 0, stream>>>(cnt, off);
    fill_kernel<<<edgeBlocks, 256, 0, stream>>>(ei, off, cur, perm);

    // small precomputes
    a1_kernel<<<1, 128, 0, stream>>>(Wout1, w_read + FF, W_skip + 10 * FF, ae, a1, askip);
    cd_kernel<<<1, 128, 0, stream>>>(Wout0, w_read, a1, Wr1, c0, D);
    gw_kernel<<<40, 256, 0, stream>>>(W_emb, Wr0, Wout0, GW);
    tmc_kernel<<<1, 256, 0, stream>>>(D, c0, W_emb, Wr0, T, Mc);

    // geometry: thread = CSR slot, coalesced record writes
    edge_geom<<<edgeBlocks, 256, 0, stream>>>(pos, shifts, ei, w_sh, perm, rec, E1);

    // P0, then h1, t1, M
    p0_kernel<<<P0_BLOCKS, 256, 0, stream>>>(rec, off, attrs, P0);
    h1_gemm<<<GEMM_BLOCKS, 256, 0, stream>>>(P0, GW, attrs, W_skip, w_read, h1, node_e);
    t1_kernel<<<(NN + 3) / 4, 256, 0, stream>>>(h1, a1, Wr1, t1);
    m_kernel<<<(NN + 255) / 256, 256, 0, stream>>>(E1, T, Mc, M);

    // fused per-edge: dsp/drp both layers, layer-1 energy, forces
    edge_pass<<<EP_BLOCKS, 256, 0, stream>>>(rec, t1, M, attrs, batch, w_sh,
                                             forces, energy);

    // energy finalize (layer-0 node energies + layer-1 skip + e0)
    efinal_kernel<<<EF_BLOCKS, 256, 0, stream>>>(node_e, attrs, askip, batch, energy);
}

// Round 10
// 672.797 us; speedup vs baseline: 1.5672x; 1.5672x over previous
//
#include <hip/hip_runtime.h>

#define NN 50000
#define EE 800000
#define GG 64
#define FF 128
#define NBES 8
#define RECW 24   // floats per edge record: eb[8], db[8], s0, s1, x, y, z, inv_r, snd, rcv
#define RMAXF 5.0f
#define PI_F 3.14159265358979323846f

// spherical harmonic constants
#define S3  1.7320508075688772f
#define S5  2.23606797749979f
#define S15 3.872983346207417f
#define C1c 2.091650066335189f   // sqrt(35/8)
#define C2c 10.246950765959598f  // sqrt(105)
#define C3c 1.62018517460196f    // sqrt(21/8)
#define C4c 1.3228756555322954f  // sqrt(7)/2
#define C5c 5.123475382979799f   // sqrt(105)/2
#define CCB 0.6324555320336759f  // sqrt(2/5)

__device__ __forceinline__ float shc_s(float x, float y, float z, const float* __restrict__ w) {
    float x2 = x * x, y2 = y * y, z2 = z * z;
    return w[0]
        + w[1] * (S3 * x) + w[2] * (S3 * y) + w[3] * (S3 * z)
        + w[4] * (S15 * x * y) + w[5] * (S15 * y * z) + w[6] * (0.5f * S5 * (3.f * z2 - 1.f))
        + w[7] * (S15 * x * z) + w[8] * (0.5f * S15 * (x2 - y2))
        + w[9] * (C1c * y * (3.f * x2 - y2)) + w[10] * (C2c * x * y * z)
        + w[11] * (C3c * y * (5.f * z2 - 1.f)) + w[12] * (C4c * z * (5.f * z2 - 3.f))
        + w[13] * (C3c * x * (5.f * z2 - 1.f)) + w[14] * (C5c * z * (x2 - y2))
        + w[15] * (C1c * x * (x2 - 3.f * y2));
}

__device__ __forceinline__ void shc_grad(float x, float y, float z, const float* __restrict__ w,
                                         float& gx, float& gy, float& gz) {
    float x2 = x * x, y2 = y * y, z2 = z * z;
    gx = w[1] * S3 + w[4] * (S15 * y) + w[7] * (S15 * z) + w[8] * (S15 * x)
       + w[9] * (6.f * C1c * x * y) + w[10] * (C2c * y * z) + w[13] * (C3c * (5.f * z2 - 1.f))
       + w[14] * (2.f * C5c * x * z) + w[15] * (3.f * C1c * (x2 - y2));
    gy = w[2] * S3 + w[4] * (S15 * x) + w[5] * (S15 * z) - w[8] * (S15 * y)
       + w[9] * (3.f * C1c * (x2 - y2)) + w[10] * (C2c * x * z) + w[11] * (C3c * (5.f * z2 - 1.f))
       - w[14] * (2.f * C5c * y * z) - w[15] * (6.f * C1c * x * y);
    gz = w[3] * S3 + w[5] * (S15 * y) + w[6] * (3.f * S5 * z) + w[7] * (S15 * x)
       + w[10] * (C2c * x * y) + w[11] * (10.f * C3c * y * z) + w[12] * (C4c * (15.f * z2 - 3.f))
       + w[13] * (10.f * C3c * x * z) + w[14] * (C5c * (x2 - y2));
}

// -------------------- CSR build (rcv + snd) --------------------

__global__ __launch_bounds__(256) void count_kernel(const int* __restrict__ ei,
                                                    int* __restrict__ cnt) {
    int e = blockIdx.x * 256 + threadIdx.x;
    if (e >= EE) return;
    atomicAdd(&cnt[ei[EE + e]], 1);        // rcv counts
    atomicAdd(&cnt[NN + ei[e]], 1);        // snd counts
}

// one block per half (rcv / snd); chunked scan cnt[NN] -> off[NN+1]
__global__ __launch_bounds__(256) void scan_kernel(const int* __restrict__ cnt,
                                                   int* __restrict__ off) {
    const int* c = cnt + (size_t)blockIdx.x * NN;
    int* o = off + (size_t)blockIdx.x * (NN + 1);
    __shared__ int wsum[4];
    __shared__ int carry_s;
    if (threadIdx.x == 0) carry_s = 0;
    __syncthreads();
    int lane = threadIdx.x & 63;
    int wid = threadIdx.x >> 6;
    for (int base = 0; base < NN; base += 256) {
        int i = base + threadIdx.x;
        int v = (i < NN) ? c[i] : 0;
        int x = v;
#pragma unroll
        for (int d = 1; d < 64; d <<= 1) {
            int y = __shfl_up(x, d);
            if (lane >= d) x += y;
        }
        if (lane == 63) wsum[wid] = x;
        __syncthreads();
        int pre = 0;
#pragma unroll
        for (int w = 0; w < 4; w++) if (w < wid) pre += wsum[w];
        int total = wsum[0] + wsum[1] + wsum[2] + wsum[3];
        int carry = carry_s;
        if (i < NN) o[i] = carry + pre + x - v;
        __syncthreads();
        if (threadIdx.x == 0) carry_s = carry + total;
        __syncthreads();
    }
    if (threadIdx.x == 0) o[NN] = carry_s;
}

// perm_rcv[slot_r] = e;  psl_e[slot_s] = e;  psl_j[slot_s] = slot_r
__global__ __launch_bounds__(256) void fill_kernel(const int* __restrict__ ei,
                                                   const int* __restrict__ off,
                                                   int* __restrict__ cur,
                                                   int* __restrict__ perm_rcv,
                                                   int* __restrict__ psl_e,
                                                   int* __restrict__ psl_j) {
    int e = blockIdx.x * 256 + threadIdx.x;
    if (e >= EE) return;
    int snd = ei[e], rcv = ei[EE + e];
    int sr = off[rcv] + atomicAdd(&cur[rcv], 1);
    perm_rcv[sr] = e;
    int ss = off[(NN + 1) + snd] + atomicAdd(&cur[NN + snd], 1);
    psl_e[ss] = e;
    psl_j[ss] = sr;
}

// -------------------- geometry: thread = CSR slot, gather edge, write coalesced -------

__global__ __launch_bounds__(256) void edge_geom(const float* __restrict__ pos,
                                                 const float* __restrict__ shifts,
                                                 const int* __restrict__ ei,
                                                 const float* __restrict__ wsh,
                                                 const int* __restrict__ perm,
                                                 float* __restrict__ rec) {
    int j = blockIdx.x * 256 + threadIdx.x;
    if (j >= EE) return;
    int e = perm[j];
    int snd = ei[e];
    int rcv = ei[EE + e];
    float vx = pos[rcv * 3 + 0] - pos[snd * 3 + 0] + shifts[e * 3 + 0];
    float vy = pos[rcv * 3 + 1] - pos[snd * 3 + 1] + shifts[e * 3 + 1];
    float vz = pos[rcv * 3 + 2] - pos[snd * 3 + 2] + shifts[e * 3 + 2];
    float r2 = vx * vx + vy * vy + vz * vz + 1e-12f;
    float r = sqrtf(r2);
    float inv_r = 1.0f / r;
    float x = vx * inv_r, y = vy * inv_r, z = vz * inv_r;
    float valid = (r < RMAXF) ? 1.f : 0.f;

    float s0 = shc_s(x, y, z, wsh);
    float s1v = shc_s(x, y, z, wsh + 16);

    float u = r * (1.0f / RMAXF);
    float th = PI_F * u;
    float s1 = sinf(th), c1 = cosf(th);
    float u2 = u * u, u3 = u2 * u, u5 = u2 * u3, u6 = u3 * u3, u7 = u6 * u, u8 = u6 * u2;
    float env = (1.f - 28.f * u6 + 48.f * u7 - 21.f * u8) * valid;
    float denv = (-168.f * u5 + 336.f * u6 - 168.f * u7) * (1.0f / RMAXF) * valid;
    float sk = s1, skm = 0.f, ck = c1, ckm = 1.f;
    float tc = 2.f * c1;
    float ebv[NBES], dbv[NBES];
#pragma unroll
    for (int k = 1; k <= NBES; k++) {
        float b = CCB * sk * inv_r;
        ebv[k - 1] = b * env;
        dbv[k - 1] = CCB * (((float)k * PI_F * (1.0f / RMAXF)) * ck * inv_r
                            - sk * inv_r * inv_r) * env
                     + b * denv;
        float sn = tc * sk - skm; skm = sk; sk = sn;
        float cn = tc * ck - ckm; ckm = ck; ck = cn;
    }

    float* rc = rec + (size_t)j * RECW;
    *(float4*)&rc[0]  = make_float4(ebv[0], ebv[1], ebv[2], ebv[3]);
    *(float4*)&rc[4]  = make_float4(ebv[4], ebv[5], ebv[6], ebv[7]);
    *(float4*)&rc[8]  = make_float4(dbv[0], dbv[1], dbv[2], dbv[3]);
    *(float4*)&rc[12] = make_float4(dbv[4], dbv[5], dbv[6], dbv[7]);
    *(float4*)&rc[16] = make_float4(s0, s1v, x, y);
    *(float4*)&rc[20] = make_float4(z, inv_r, __int_as_float(snd), __int_as_float(rcv));
}

// -------------------- E1 over snd-CSR (thread-per-node, no atomics) -------------------
// E1[n,k] = sum_{e: snd=n} eb[k] * s1  — recomputes the cheap radial terms per edge.

__global__ __launch_bounds__(256) void e1_csr(const float* __restrict__ pos,
                                              const float* __restrict__ shifts,
                                              const int* __restrict__ ei,
                                              const float* __restrict__ wsh1,
                                              const int* __restrict__ off_snd,
                                              const int* __restrict__ psl_e,
                                              float* __restrict__ E1) {
    int n = blockIdx.x * 256 + threadIdx.x;
    if (n >= NN) return;
    float px = pos[n * 3 + 0], py = pos[n * 3 + 1], pz = pos[n * 3 + 2];
    float acc[NBES];
#pragma unroll
    for (int k = 0; k < NBES; k++) acc[k] = 0.f;
    int beg = off_snd[n], end = off_snd[n + 1];
    for (int s = beg; s < end; s++) {
        int e = psl_e[s];
        int rcv = ei[EE + e];
        float vx = pos[rcv * 3 + 0] - px + shifts[e * 3 + 0];
        float vy = pos[rcv * 3 + 1] - py + shifts[e * 3 + 1];
        float vz = pos[rcv * 3 + 2] - pz + shifts[e * 3 + 2];
        float r2 = vx * vx + vy * vy + vz * vz + 1e-12f;
        float r = sqrtf(r2);
        float inv_r = 1.0f / r;
        float x = vx * inv_r, y = vy * inv_r, z = vz * inv_r;
        float valid = (r < RMAXF) ? 1.f : 0.f;
        float s1v = shc_s(x, y, z, wsh1);

        float u = r * (1.0f / RMAXF);
        float th = PI_F * u;
        float s1 = sinf(th), c1 = cosf(th);
        float u2 = u * u, u3 = u2 * u, u6 = u3 * u3, u7 = u6 * u, u8 = u6 * u2;
        float env = (1.f - 28.f * u6 + 48.f * u7 - 21.f * u8) * valid;
        float sk = s1, skm = 0.f;
        float tc = 2.f * c1;
        float es = env * s1v * CCB * inv_r;
#pragma unroll
        for (int k = 1; k <= NBES; k++) {
            acc[k - 1] += sk * es;
            float sn = tc * sk - skm; skm = sk; sk = sn;
        }
    }
    *(float4*)&E1[(size_t)n * 8]     = make_float4(acc[0], acc[1], acc[2], acc[3]);
    *(float4*)&E1[(size_t)n * 8 + 4] = make_float4(acc[4], acc[5], acc[6], acc[7]);
}

// -------------------- small precomputes --------------------

__global__ __launch_bounds__(128) void a1_kernel(const float* __restrict__ Wout1,
                                                 const float* __restrict__ wread1,
                                                 const float* __restrict__ Wskip1,
                                                 const float* __restrict__ ae,
                                                 float* __restrict__ a1,
                                                 float* __restrict__ askip) {
    int f = threadIdx.x;
    float s = 0.f;
    for (int k = 0; k < FF; k++) s += Wout1[f * FF + k] * wread1[k];
    a1[f] = s;
    if (f < 10) {
        float t = 0.f;
        for (int k = 0; k < FF; k++) t += Wskip1[f * FF + k] * wread1[k];
        askip[f] = t + ae[f];
    }
}

// c0[f'] = sum_f wread0[f] Wout0[f',f];  D[k,f'] = sum_f a1[f] Wr1[k,f] Wout0[f',f]
__global__ __launch_bounds__(128) void cd_kernel(const float* __restrict__ Wout0,
                                                 const float* __restrict__ wread0,
                                                 const float* __restrict__ a1,
                                                 const float* __restrict__ Wr1,
                                                 float* __restrict__ c0,
                                                 float* __restrict__ D) {
    int fp = threadIdx.x;
    float c = 0.f;
    float d[NBES];
#pragma unroll
    for (int k = 0; k < NBES; k++) d[k] = 0.f;
    for (int f = 0; f < FF; f++) {
        float w = Wout0[fp * FF + f];
        c += wread0[f] * w;
        float aw = a1[f] * w;
#pragma unroll
        for (int k = 0; k < NBES; k++) d[k] += aw * Wr1[k * FF + f];
    }
    c0[fp] = c;
#pragma unroll
    for (int k = 0; k < NBES; k++) D[k * FF + fp] = d[k];
}

// GW[p=a*8+k][f'] = sum_f W_emb[a,f] Wr0[k,f] Wout0[f,f']
__global__ __launch_bounds__(256) void gw_kernel(const float* __restrict__ W_emb,
                                                 const float* __restrict__ Wr0,
                                                 const float* __restrict__ Wout0,
                                                 float* __restrict__ GW) {
    int idx = blockIdx.x * 256 + threadIdx.x;
    if (idx >= 80 * FF) return;
    int fp = idx & 127;
    int p = idx >> 7;
    int a = p >> 3, k = p & 7;
    float s = 0.f;
    for (int f = 0; f < FF; f++)
        s += W_emb[a * FF + f] * Wr0[k * FF + f] * Wout0[f * FF + fp];
    GW[p * FF + fp] = s;
}

// T[k'][p0=k*10+a] = sum_f D[k',f] W_emb[a,f] Wr0[k,f];  Mc[p0] = sum_f c0[f] W_emb Wr0
__global__ __launch_bounds__(256) void tmc_kernel(const float* __restrict__ D,
                                                  const float* __restrict__ c0,
                                                  const float* __restrict__ W_emb,
                                                  const float* __restrict__ Wr0,
                                                  float* __restrict__ T,
                                                  float* __restrict__ Mc) {
    for (int i = threadIdx.x; i < 720; i += 256) {
        if (i < 640) {
            int kp = i / 80;
            int p0 = i - kp * 80;
            int k = p0 / 10, a = p0 - k * 10;
            float s = 0.f;
            for (int f = 0; f < FF; f++)
                s += D[kp * FF + f] * W_emb[a * FF + f] * Wr0[k * FF + f];
            T[i] = s;
        } else {
            int p0 = i - 640;
            int k = p0 / 10, a = p0 - k * 10;
            float s = 0.f;
            for (int f = 0; f < FF; f++)
                s += c0[f] * W_emb[a * FF + f] * Wr0[k * FF + f];
            Mc[p0] = s;
        }
    }
}

// -------------------- P0[n, p=a*8+k] = sum_{e:rcv=n} attrs[snd,a] eb[e,k] s0_e --------

#define P0_BLOCKS 2048
__global__ __launch_bounds__(256) void p0_kernel(const float* __restrict__ rec,
                                                 const int* __restrict__ off,
                                                 const float* __restrict__ attrs,
                                                 float* __restrict__ P0) {
    int wv = (blockIdx.x * 256 + threadIdx.x) >> 6;
    int lane = threadIdx.x & 63;
    int nwaves = P0_BLOCKS * 4;
    int a_lo = lane >> 3;
    int k_l = lane & 7;

    for (int n = wv; n < NN; n += nwaves) {
        int beg = off[n], end = off[n + 1];
        float acc = 0.f, acc2 = 0.f;
        for (int j = beg; j < end; j++) {
            const float* rc = rec + (size_t)j * RECW;
            float s0 = rc[16];
            int snd = __float_as_int(rc[22]);
            float eb = rc[k_l];
            float es = eb * s0;
            acc += attrs[snd * 10 + a_lo] * es;
            if (lane < 16) acc2 += attrs[snd * 10 + 8 + a_lo] * es;
        }
        P0[(size_t)n * 80 + lane] = acc;
        if (lane < 16) P0[(size_t)n * 80 + 64 + lane] = acc2;
    }
}

// -------------------- h1 GEMM: h1 = P0 @ GW + attrs @ Wskip0 ; node_e = h1.wread0 ------

#define GEMM_BLOCKS 512
__global__ __launch_bounds__(256, 2) void h1_gemm(const float* __restrict__ P0,
                                                  const float* __restrict__ GW,
                                                  const float* __restrict__ attrs,
                                                  const float* __restrict__ Wskip,
                                                  const float* __restrict__ wread,
                                                  float* __restrict__ h1,
                                                  float* __restrict__ node_e) {
    __shared__ float sb[80][FF];   // 40 KB
    __shared__ float sa[32][80];   // 10 KB
    int t = threadIdx.x;
#pragma unroll
    for (int j = 0; j < 10; j++) {
        int flat4 = j * 256 + t;     // 0..2559
        int row = flat4 >> 5;
        int col = (flat4 & 31) * 4;
        *(float4*)&sb[row][col] = *(const float4*)&GW[row * FF + col];
    }

    int g = t >> 5;
    int f0 = (t & 31) * 4;
    const int NTILES = (NN + 31) / 32;

    for (int tile = blockIdx.x; tile < NTILES; tile += GEMM_BLOCKS) {
        __syncthreads();
#pragma unroll
        for (int j = 0; j < 3; j++) {
            int flat4 = j * 256 + t;   // need 640
            if (flat4 < 640) {
                int row = flat4 / 20;
                int col = (flat4 - row * 20) * 4;
                int n = tile * 32 + row;
                float4 v = make_float4(0.f, 0.f, 0.f, 0.f);
                if (n < NN) v = *(const float4*)&P0[(size_t)n * 80 + col];
                *(float4*)&sa[row][col] = v;
            }
        }
        __syncthreads();

        float acc[4][4];
#pragma unroll
        for (int i = 0; i < 4; i++)
#pragma unroll
            for (int j = 0; j < 4; j++) acc[i][j] = 0.f;

        for (int kk = 0; kk < 80; kk += 4) {
            float4 bv0 = *(const float4*)&sb[kk + 0][f0];
            float4 bv1 = *(const float4*)&sb[kk + 1][f0];
            float4 bv2 = *(const float4*)&sb[kk + 2][f0];
            float4 bv3 = *(const float4*)&sb[kk + 3][f0];
#pragma unroll
            for (int ni = 0; ni < 4; ni++) {
                float4 av = *(const float4*)&sa[g * 4 + ni][kk];
                acc[ni][0] += av.x * bv0.x + av.y * bv1.x + av.z * bv2.x + av.w * bv3.x;
                acc[ni][1] += av.x * bv0.y + av.y * bv1.y + av.z * bv2.y + av.w * bv3.y;
                acc[ni][2] += av.x * bv0.z + av.y * bv1.z + av.z * bv2.z + av.w * bv3.z;
                acc[ni][3] += av.x * bv0.w + av.y * bv1.w + av.z * bv2.w + av.w * bv3.w;
            }
        }

#pragma unroll
        for (int ni = 0; ni < 4; ni++) {
            int n = tile * 32 + g * 4 + ni;
            bool valid = (n < NN);
#pragma unroll
            for (int a = 0; a < 10; a++) {
                float att = valid ? attrs[n * 10 + a] : 0.f;
                float4 wk = *(const float4*)&Wskip[a * FF + f0];
                acc[ni][0] += att * wk.x;
                acc[ni][1] += att * wk.y;
                acc[ni][2] += att * wk.z;
                acc[ni][3] += att * wk.w;
            }
            if (valid) {
                float4 out;
                out.x = acc[ni][0]; out.y = acc[ni][1];
                out.z = acc[ni][2]; out.w = acc[ni][3];
                *(float4*)&h1[(size_t)n * FF + f0] = out;
            }
            float4 wv = *(const float4*)&wread[f0];
            float p = acc[ni][0] * wv.x + acc[ni][1] * wv.y
                    + acc[ni][2] * wv.z + acc[ni][3] * wv.w;
#pragma unroll
            for (int o = 16; o > 0; o >>= 1) p += __shfl_xor(p, o);
            if (valid && (t & 31) == 0) node_e[n] = p;
        }
    }
}

// -------------------- t1[n,k] = sum_f a1[f] h1[n,f] Wr1[k,f] --------------------

__global__ __launch_bounds__(256) void t1_kernel(const float* __restrict__ h1,
                                                 const float* __restrict__ a1,
                                                 const float* __restrict__ Wr1,
                                                 float* __restrict__ t1) {
    int w = threadIdx.x >> 6;
    int lane = threadIdx.x & 63;
    int n = blockIdx.x * 4 + w;
    if (n >= NN) return;
    int f0 = lane, f1 = lane + 64;
    float v0 = a1[f0] * h1[(size_t)n * FF + f0];
    float v1 = a1[f1] * h1[(size_t)n * FF + f1];
    float p[NBES];
#pragma unroll
    for (int k = 0; k < NBES; k++)
        p[k] = v0 * Wr1[k * FF + f0] + v1 * Wr1[k * FF + f1];
#pragma unroll
    for (int o = 32; o > 0; o >>= 1) {
#pragma unroll
        for (int k = 0; k < NBES; k++) p[k] += __shfl_xor(p[k], o);
    }
    if (lane == 0) {
        *(float4*)&t1[(size_t)n * 8]     = make_float4(p[0], p[1], p[2], p[3]);
        *(float4*)&t1[(size_t)n * 8 + 4] = make_float4(p[4], p[5], p[6], p[7]);
    }
}

// -------------------- M[n][p0=k*10+a] = Mc + sum_k' E1[n,k'] T[k'][p0] ----------------

__global__ __launch_bounds__(256) void m_kernel(const float* __restrict__ E1,
                                                const float* __restrict__ T,
                                                const float* __restrict__ Mc,
                                                float* __restrict__ M) {
    __shared__ float sT[720];
    int t = threadIdx.x;
    for (int i = t; i < 720; i += 256) sT[i] = (i < 640) ? T[i] : Mc[i - 640];
    __syncthreads();
    int n = blockIdx.x * 256 + t;
    if (n >= NN) return;
    float4 ea = *(const float4*)&E1[(size_t)n * 8];
    float4 eb = *(const float4*)&E1[(size_t)n * 8 + 4];
    float e1v[8] = {ea.x, ea.y, ea.z, ea.w, eb.x, eb.y, eb.z, eb.w};
#pragma unroll
    for (int c = 0; c < 20; c++) {
        float4 m = *(const float4*)&sT[640 + c * 4];
#pragma unroll
        for (int kp = 0; kp < 8; kp++) {
            float4 tv = *(const float4*)&sT[kp * 80 + c * 4];
            m.x += e1v[kp] * tv.x;
            m.y += e1v[kp] * tv.y;
            m.z += e1v[kp] * tv.z;
            m.w += e1v[kp] * tv.w;
        }
        *(float4*)&M[(size_t)n * 80 + c * 4] = m;
    }
}

// -------------------- fused per-edge pass: dsp/drp both layers + energy1 + gv ---------

#define EP_BLOCKS 512
__global__ __launch_bounds__(256) void edge_pass(const float* __restrict__ rec,
                                                 const float* __restrict__ t1,
                                                 const float* __restrict__ M,
                                                 const float* __restrict__ attrs,
                                                 const int* __restrict__ batch,
                                                 const float* __restrict__ wsh,
                                                 float4* __restrict__ gvp,
                                                 float* __restrict__ energy) {
    __shared__ float eacc[GG];
    int t = threadIdx.x;
    int lane = t & 63;
    if (t < GG) eacc[t] = 0.f;
    __syncthreads();

    for (int j0 = blockIdx.x * 256; j0 < EE; j0 += EP_BLOCKS * 256) {
        int j = j0 + t;
        bool act = (j < EE);
        int jc = act ? j : 0;
        const float* rc = rec + (size_t)jc * RECW;
        float4 q0 = *(const float4*)&rc[0];
        float4 q1 = *(const float4*)&rc[4];
        float4 q2 = *(const float4*)&rc[8];
        float4 q3 = *(const float4*)&rc[12];
        float4 q4 = *(const float4*)&rc[16];
        float4 q5 = *(const float4*)&rc[20];
        float eb[8] = {q0.x, q0.y, q0.z, q0.w, q1.x, q1.y, q1.z, q1.w};
        float db[8] = {q2.x, q2.y, q2.z, q2.w, q3.x, q3.y, q3.z, q3.w};
        float s0 = q4.x, s1v = q4.y, x = q4.z, y = q4.w;
        float z = q5.x, ivr = q5.y;
        int snd = __float_as_int(q5.z);
        int rcv = __float_as_int(q5.w);

        // layer 1: dsp1/drp1 via t1[snd]
        float4 ta = *(const float4*)&t1[(size_t)snd * 8];
        float4 tb = *(const float4*)&t1[(size_t)snd * 8 + 4];
        float tg[8] = {ta.x, ta.y, ta.z, ta.w, tb.x, tb.y, tb.z, tb.w};
        float dsp1 = 0.f, drp1 = 0.f;
#pragma unroll
        for (int k = 0; k < 8; k++) {
            dsp1 += eb[k] * tg[k];
            drp1 += db[k] * tg[k];
        }

        // layer 0: t0[k] = sum_a attrs[snd,a] M[rcv,k,a]
        float at[10];
#pragma unroll
        for (int i = 0; i < 5; i++) {
            float2 v = *(const float2*)&attrs[snd * 10 + 2 * i];
            at[2 * i] = v.x; at[2 * i + 1] = v.y;
        }
        const float* Mr = M + (size_t)rcv * 80;
        float dsp0 = 0.f, drp0 = 0.f;
#pragma unroll
        for (int k = 0; k < 8; k++) {
            float t0 = 0.f;
#pragma unroll
            for (int a = 0; a < 10; a++) t0 += at[a] * Mr[k * 10 + a];
            dsp0 += eb[k] * t0;
            drp0 += db[k] * t0;
        }

        // layer-1 energy contribution: s1 * dsp1, grouped by batch[rcv]
        float el = act ? s1v * dsp1 : 0.f;
        int b = act ? batch[rcv] : -1;
        int ub = __builtin_amdgcn_readfirstlane(b);
        if (__all(b == ub)) {
            float es = el;
#pragma unroll
            for (int o = 32; o > 0; o >>= 1) es += __shfl_xor(es, o);
            if (lane == 0 && ub >= 0) atomicAdd(&eacc[ub], es);
        } else {
            if (act) atomicAdd(&eacc[b], el);
        }

        // per-edge force vector (coalesced write; gathered later)
        float g0x, g0y, g0z, g1x, g1y, g1z;
        shc_grad(x, y, z, wsh, g0x, g0y, g0z);
        shc_grad(x, y, z, wsh + 16, g1x, g1y, g1z);
        float gux = dsp0 * g0x + dsp1 * g1x;
        float guy = dsp0 * g0y + dsp1 * g1y;
        float guz = dsp0 * g0z + dsp1 * g1z;
        float gr = s0 * drp0 + s1v * drp1;
        float dgu = gux * x + guy * y + guz * z;
        float gvx = gr * x + ivr * (gux - dgu * x);
        float gvy = gr * y + ivr * (guy - dgu * y);
        float gvz = gr * z + ivr * (guz - dgu * z);
        if (act) gvp[j] = make_float4(gvx, gvy, gvz, 0.f);
    }
    __syncthreads();
    if (t < GG && eacc[t] != 0.f) atomicAdd(&energy[t], eacc[t]);
}

// -------------------- force gather (thread-per-node, no atomics) ----------------------
// forces[n] = sum_{e:snd=n} gv_e  -  sum_{e:rcv=n} gv_e

__global__ __launch_bounds__(256) void force_gather(const int* __restrict__ off_rcv,
                                                    const int* __restrict__ off_snd,
                                                    const int* __restrict__ psl_j,
                                                    const float4* __restrict__ gvp,
                                                    float* __restrict__ forces) {
    int n = blockIdx.x * 256 + threadIdx.x;
    if (n >= NN) return;
    float fx = 0.f, fy = 0.f, fz = 0.f;
    int beg = off_rcv[n], end = off_rcv[n + 1];
    for (int j = beg; j < end; j++) {
        float4 g = gvp[j];
        fx -= g.x; fy -= g.y; fz -= g.z;
    }
    beg = off_snd[n]; end = off_snd[n + 1];
    for (int s = beg; s < end; s++) {
        float4 g = gvp[psl_j[s]];
        fx += g.x; fy += g.y; fz += g.z;
    }
    forces[n * 3 + 0] = fx;
    forces[n * 3 + 1] = fy;
    forces[n * 3 + 2] = fz;
}

// -------------------- energy finalize: node_e + attrs.askip --------------------

#define EF_BLOCKS 128
__global__ __launch_bounds__(256) void efinal_kernel(const float* __restrict__ node_e,
                                                     const float* __restrict__ attrs,
                                                     const float* __restrict__ askip,
                                                     const int* __restrict__ batch,
                                                     float* __restrict__ energy) {
    __shared__ float eacc[GG];
    int t = threadIdx.x;
    if (t < GG) eacc[t] = 0.f;
    __syncthreads();
    for (int n = blockIdx.x * 256 + t; n < NN; n += EF_BLOCKS * 256) {
        float v = node_e[n];
#pragma unroll
        for (int a = 0; a < 10; a++) v += attrs[n * 10 + a] * askip[a];
        atomicAdd(&eacc[batch[n]], v);
    }
    __syncthreads();
    if (t < GG && eacc[t] != 0.f) atomicAdd(&energy[t], eacc[t]);
}

// -------------------- launch --------------------

extern "C" void kernel_launch(void* const* d_in, const int* in_sizes, int n_in,
                              void* d_out, int out_size, void* d_ws, size_t ws_size,
                              hipStream_t stream) {
    const float* pos    = (const float*)d_in[0];
    const float* attrs  = (const float*)d_in[1];
    const float* shifts = (const float*)d_in[2];
    const int*   ei     = (const int*)d_in[3];
    const int*   batch  = (const int*)d_in[4];
    const float* W_emb  = (const float*)d_in[6];
    const float* ae     = (const float*)d_in[7];
    const float* W_r    = (const float*)d_in[8];   // (2,8,F)
    const float* w_sh   = (const float*)d_in[9];   // (2,16)
    const float* W_out  = (const float*)d_in[10];  // (2,F,F)
    const float* W_skip = (const float*)d_in[11];  // (2,10,F)
    const float* w_read = (const float*)d_in[12];  // (2,F)

    const float* Wr0 = W_r;
    const float* Wr1 = W_r + NBES * FF;
    const float* Wout0 = W_out;
    const float* Wout1 = W_out + FF * FF;

    float* energy = (float*)d_out;
    float* forces = energy + GG;

    float* ws  = (float*)d_ws;
    float* h1  = ws;                        // N*F
    float* P0  = h1 + (size_t)NN * FF;      // N*80
    float* M   = P0 + (size_t)NN * 80;      // N*80
    float* E1  = M + (size_t)NN * 80;       // N*8
    float* t1  = E1 + (size_t)NN * 8;       // N*8
    float* node_e = t1 + (size_t)NN * 8;    // N
    float* rec = node_e + NN;               // EE*24
    float4* gvp = (float4*)(rec + (size_t)EE * RECW);  // EE*4 floats
    float* a1  = (float*)(gvp + EE);        // 128
    float* askip = a1 + FF;                 // 16
    float* c0  = askip + 16;                // 128
    float* D   = c0 + FF;                   // 8*128
    float* GW  = D + NBES * FF;             // 80*128
    float* T   = GW + 80 * FF;              // 640
    float* Mc  = T + 640;                   // 80

    int* cnt  = (int*)(Mc + 80);            // 2N
    int* cur  = cnt + 2 * NN;               // 2N
    int* off  = cur + 2 * NN;               // 2(N+1)
    int* perm_rcv = off + 2 * (NN + 1);     // EE
    int* psl_e = perm_rcv + EE;             // EE
    int* psl_j = psl_e + EE;                // EE
    const int* off_rcv = off;
    const int* off_snd = off + (NN + 1);

    const int edgeBlocks = (EE + 255) / 256;
    const int nodeBlocks = (NN + 255) / 256;

    hipMemsetAsync(d_out, 0, (size_t)out_size * sizeof(float), stream);
    hipMemsetAsync(cnt, 0, (size_t)4 * NN * sizeof(int), stream);   // cnt + cur

    // CSR build (rcv + snd)
    count_kernel<<<edgeBlocks, 256, 0, stream>>>(ei, cnt);
    scan_kernel<<<2, 256, 0, stream>>>(cnt, off);
    fill_kernel<<<edgeBlocks, 256, 0, stream>>>(ei, off, cur, perm_rcv, psl_e, psl_j);

    // small precomputes
    a1_kernel<<<1, 128, 0, stream>>>(Wout1, w_read + FF, W_skip + 10 * FF, ae, a1, askip);
    cd_kernel<<<1, 128, 0, stream>>>(Wout0, w_read, a1, Wr1, c0, D);
    gw_kernel<<<40, 256, 0, stream>>>(W_emb, Wr0, Wout0, GW);
    tmc_kernel<<<1, 256, 0, stream>>>(D, c0, W_emb, Wr0, T, Mc);

    // geometry records (coalesced, rcv-CSR order) + E1 over snd-CSR (no atomics)
    edge_geom<<<edgeBlocks, 256, 0, stream>>>(pos, shifts, ei, w_sh, perm_rcv, rec);
    e1_csr<<<nodeBlocks, 256, 0, stream>>>(pos, shifts, ei, w_sh + 16, off_snd, psl_e, E1);

    // P0, then h1, t1, M
    p0_kernel<<<P0_BLOCKS, 256, 0, stream>>>(rec, off_rcv, attrs, P0);
    h1_gemm<<<GEMM_BLOCKS, 256, 0, stream>>>(P0, GW, attrs, W_skip, w_read, h1, node_e);
    t1_kernel<<<(NN + 3) / 4, 256, 0, stream>>>(h1, a1, Wr1, t1);
    m_kernel<<<nodeBlocks, 256, 0, stream>>>(E1, T, Mc, M);

    // fused per-edge: dsp/drp both layers, layer-1 energy, per-edge force vectors
    edge_pass<<<EP_BLOCKS, 256, 0, stream>>>(rec, t1, M, attrs, batch, w_sh, gvp, energy);

    // forces via CSR gather (no atomics)
    force_gather<<<nodeBlocks, 256, 0, stream>>>(off_rcv, off_snd, psl_j, gvp, forces);

    // energy finalize (layer-0 node energies + layer-1 skip + e0)
    efinal_kernel<<<EF_BLOCKS, 256, 0, stream>>>(node_e, attrs, askip, batch, energy);
}

// Round 11
// 562.135 us; speedup vs baseline: 1.8757x; 1.1969x over previous
//
#include <hip/hip_runtime.h>

#define NN 50000
#define EE 800000
#define GG 64
#define FF 128
#define NBES 8
#define RECW 8    // compact record: x, y, z, inv_r, s0, s1, snd, rcv  (32 B)
#define RMAXF 5.0f
#define PI_F 3.14159265358979323846f

// spherical harmonic constants
#define S3  1.7320508075688772f
#define S5  2.23606797749979f
#define S15 3.872983346207417f
#define C1c 2.091650066335189f   // sqrt(35/8)
#define C2c 10.246950765959598f  // sqrt(105)
#define C3c 1.62018517460196f    // sqrt(21/8)
#define C4c 1.3228756555322954f  // sqrt(7)/2
#define C5c 5.123475382979799f   // sqrt(105)/2
#define CCB 0.6324555320336759f  // sqrt(2/5)

__device__ __forceinline__ float shc_s(float x, float y, float z, const float* __restrict__ w) {
    float x2 = x * x, y2 = y * y, z2 = z * z;
    return w[0]
        + w[1] * (S3 * x) + w[2] * (S3 * y) + w[3] * (S3 * z)
        + w[4] * (S15 * x * y) + w[5] * (S15 * y * z) + w[6] * (0.5f * S5 * (3.f * z2 - 1.f))
        + w[7] * (S15 * x * z) + w[8] * (0.5f * S15 * (x2 - y2))
        + w[9] * (C1c * y * (3.f * x2 - y2)) + w[10] * (C2c * x * y * z)
        + w[11] * (C3c * y * (5.f * z2 - 1.f)) + w[12] * (C4c * z * (5.f * z2 - 3.f))
        + w[13] * (C3c * x * (5.f * z2 - 1.f)) + w[14] * (C5c * z * (x2 - y2))
        + w[15] * (C1c * x * (x2 - 3.f * y2));
}

__device__ __forceinline__ void shc_grad(float x, float y, float z, const float* __restrict__ w,
                                         float& gx, float& gy, float& gz) {
    float x2 = x * x, y2 = y * y, z2 = z * z;
    gx = w[1] * S3 + w[4] * (S15 * y) + w[7] * (S15 * z) + w[8] * (S15 * x)
       + w[9] * (6.f * C1c * x * y) + w[10] * (C2c * y * z) + w[13] * (C3c * (5.f * z2 - 1.f))
       + w[14] * (2.f * C5c * x * z) + w[15] * (3.f * C1c * (x2 - y2));
    gy = w[2] * S3 + w[4] * (S15 * x) + w[5] * (S15 * z) - w[8] * (S15 * y)
       + w[9] * (3.f * C1c * (x2 - y2)) + w[10] * (C2c * x * z) + w[11] * (C3c * (5.f * z2 - 1.f))
       - w[14] * (2.f * C5c * y * z) - w[15] * (6.f * C1c * x * y);
    gz = w[3] * S3 + w[5] * (S15 * y) + w[6] * (3.f * S5 * z) + w[7] * (S15 * x)
       + w[10] * (C2c * x * y) + w[11] * (10.f * C3c * y * z) + w[12] * (C4c * (15.f * z2 - 3.f))
       + w[13] * (10.f * C3c * x * z) + w[14] * (C5c * (x2 - y2));
}

// -------------------- CSR build --------------------

// ranks via atomic return value (the only atomics in the build)
__global__ __launch_bounds__(256) void count_kernel(const int* __restrict__ ei,
                                                    int* __restrict__ cnt,
                                                    int* __restrict__ rank_r,
                                                    int* __restrict__ rank_s) {
    int e = blockIdx.x * 256 + threadIdx.x;
    if (e >= EE) return;
    rank_r[e] = atomicAdd(&cnt[ei[EE + e]], 1);
    rank_s[e] = atomicAdd(&cnt[NN + ei[e]], 1);
}

// one block per half (rcv / snd); chunked scan cnt[NN] -> off[NN+1]
__global__ __launch_bounds__(256) void scan_kernel(const int* __restrict__ cnt,
                                                   int* __restrict__ off) {
    const int* c = cnt + (size_t)blockIdx.x * NN;
    int* o = off + (size_t)blockIdx.x * (NN + 1);
    __shared__ int wsum[4];
    __shared__ int carry_s;
    if (threadIdx.x == 0) carry_s = 0;
    __syncthreads();
    int lane = threadIdx.x & 63;
    int wid = threadIdx.x >> 6;
    for (int base = 0; base < NN; base += 256) {
        int i = base + threadIdx.x;
        int v = (i < NN) ? c[i] : 0;
        int x = v;
#pragma unroll
        for (int d = 1; d < 64; d <<= 1) {
            int y = __shfl_up(x, d);
            if (lane >= d) x += y;
        }
        if (lane == 63) wsum[wid] = x;
        __syncthreads();
        int pre = 0;
#pragma unroll
        for (int w = 0; w < 4; w++) if (w < wid) pre += wsum[w];
        int total = wsum[0] + wsum[1] + wsum[2] + wsum[3];
        int carry = carry_s;
        if (i < NN) o[i] = carry + pre + x - v;
        __syncthreads();
        if (threadIdx.x == 0) carry_s = carry + total;
        __syncthreads();
    }
    if (threadIdx.x == 0) o[NN] = carry_s;
}

// jr[e] = rcv-slot of e (coalesced); psl_j[snd-slot] = rcv-slot (single 4B scatter)
__global__ __launch_bounds__(256) void fill_kernel(const int* __restrict__ ei,
                                                   const int* __restrict__ off,
                                                   const int* __restrict__ rank_r,
                                                   const int* __restrict__ rank_s,
                                                   int* __restrict__ jr,
                                                   int* __restrict__ psl_j) {
    int e = blockIdx.x * 256 + threadIdx.x;
    if (e >= EE) return;
    int snd = ei[e], rcv = ei[EE + e];
    int sr = off[rcv] + rank_r[e];
    int ss = off[(NN + 1) + snd] + rank_s[e];
    jr[e] = sr;
    psl_j[ss] = sr;
}

// -------------------- geometry: thread = edge (coalesced in), 32B sector scatter out --

__global__ __launch_bounds__(256) void edge_geom(const float* __restrict__ pos,
                                                 const float* __restrict__ shifts,
                                                 const int* __restrict__ ei,
                                                 const float* __restrict__ wsh,
                                                 const int* __restrict__ jr,
                                                 float* __restrict__ rec) {
    int e = blockIdx.x * 256 + threadIdx.x;
    if (e >= EE) return;
    int snd = ei[e];
    int rcv = ei[EE + e];
    float vx = pos[rcv * 3 + 0] - pos[snd * 3 + 0] + shifts[e * 3 + 0];
    float vy = pos[rcv * 3 + 1] - pos[snd * 3 + 1] + shifts[e * 3 + 1];
    float vz = pos[rcv * 3 + 2] - pos[snd * 3 + 2] + shifts[e * 3 + 2];
    float r2 = vx * vx + vy * vy + vz * vz + 1e-12f;
    float r = sqrtf(r2);
    float inv_r = 1.0f / r;
    float x = vx * inv_r, y = vy * inv_r, z = vz * inv_r;

    float s0 = shc_s(x, y, z, wsh);
    float s1v = shc_s(x, y, z, wsh + 16);

    float* rc = rec + (size_t)jr[e] * RECW;
    *(float4*)&rc[0] = make_float4(x, y, z, inv_r);
    *(float4*)&rc[4] = make_float4(s0, s1v, __int_as_float(snd), __int_as_float(rcv));
}

// -------------------- E1 over snd-CSR: 8 lanes per node, gather compact records -------
// E1[n,k] = sum_{e: snd=n} eb[k] * s1

__global__ __launch_bounds__(256) void e1_csr(const float* __restrict__ rec,
                                              const int* __restrict__ off_snd,
                                              const int* __restrict__ psl_j,
                                              float* __restrict__ E1) {
    int gid = blockIdx.x * 256 + threadIdx.x;
    int n = gid >> 3;
    int k_l = gid & 7;
    if (n >= NN) return;
    int beg = off_snd[n], end = off_snd[n + 1];
    float acc = 0.f;
    for (int s = beg; s < end; s++) {
        int j = psl_j[s];
        const float* rc = rec + (size_t)j * RECW;
        float4 q0 = *(const float4*)&rc[0];
        float4 q1 = *(const float4*)&rc[4];
        float inv_r = q0.w;
        float s1v = q1.y;
        float r = 1.0f / inv_r;
        float u = r * (1.0f / RMAXF);
        float th = PI_F * u;
        float s1 = sinf(th), c1 = cosf(th);
        float u2 = u * u, u3 = u2 * u, u6 = u3 * u3, u7 = u6 * u, u8 = u6 * u2;
        float valid = (r < RMAXF) ? 1.f : 0.f;
        float env = (1.f - 28.f * u6 + 48.f * u7 - 21.f * u8) * valid;
        float sk = s1, skm = 0.f;
        float tc = 2.f * c1;
        float my = 0.f;
#pragma unroll
        for (int kk = 1; kk <= NBES; kk++) {
            if (kk - 1 == k_l) my = sk;
            float sn = tc * sk - skm; skm = sk; sk = sn;
        }
        acc += my * (CCB * inv_r * env * s1v);
    }
    E1[(size_t)n * 8 + k_l] = acc;
}

// -------------------- small precomputes --------------------

__global__ __launch_bounds__(128) void a1_kernel(const float* __restrict__ Wout1,
                                                 const float* __restrict__ wread1,
                                                 const float* __restrict__ Wskip1,
                                                 const float* __restrict__ ae,
                                                 float* __restrict__ a1,
                                                 float* __restrict__ askip) {
    int f = threadIdx.x;
    float s = 0.f;
    for (int k = 0; k < FF; k++) s += Wout1[f * FF + k] * wread1[k];
    a1[f] = s;
    if (f < 10) {
        float t = 0.f;
        for (int k = 0; k < FF; k++) t += Wskip1[f * FF + k] * wread1[k];
        askip[f] = t + ae[f];
    }
}

// c0[f'] = sum_f wread0[f] Wout0[f',f];  D[k,f'] = sum_f a1[f] Wr1[k,f] Wout0[f',f]
__global__ __launch_bounds__(128) void cd_kernel(const float* __restrict__ Wout0,
                                                 const float* __restrict__ wread0,
                                                 const float* __restrict__ a1,
                                                 const float* __restrict__ Wr1,
                                                 float* __restrict__ c0,
                                                 float* __restrict__ D) {
    int fp = threadIdx.x;
    float c = 0.f;
    float d[NBES];
#pragma unroll
    for (int k = 0; k < NBES; k++) d[k] = 0.f;
    for (int f = 0; f < FF; f++) {
        float w = Wout0[fp * FF + f];
        c += wread0[f] * w;
        float aw = a1[f] * w;
#pragma unroll
        for (int k = 0; k < NBES; k++) d[k] += aw * Wr1[k * FF + f];
    }
    c0[fp] = c;
#pragma unroll
    for (int k = 0; k < NBES; k++) D[k * FF + fp] = d[k];
}

// GW[p=a*8+k][f'] = sum_f W_emb[a,f] Wr0[k,f] Wout0[f,f']
__global__ __launch_bounds__(256) void gw_kernel(const float* __restrict__ W_emb,
                                                 const float* __restrict__ Wr0,
                                                 const float* __restrict__ Wout0,
                                                 float* __restrict__ GW) {
    int idx = blockIdx.x * 256 + threadIdx.x;
    if (idx >= 80 * FF) return;
    int fp = idx & 127;
    int p = idx >> 7;
    int a = p >> 3, k = p & 7;
    float s = 0.f;
    for (int f = 0; f < FF; f++)
        s += W_emb[a * FF + f] * Wr0[k * FF + f] * Wout0[f * FF + fp];
    GW[p * FF + fp] = s;
}

// T[k'][p0=k*10+a] = sum_f D[k',f] W_emb[a,f] Wr0[k,f];  Mc[p0] = sum_f c0[f] W_emb Wr0
__global__ __launch_bounds__(256) void tmc_kernel(const float* __restrict__ D,
                                                  const float* __restrict__ c0,
                                                  const float* __restrict__ W_emb,
                                                  const float* __restrict__ Wr0,
                                                  float* __restrict__ T,
                                                  float* __restrict__ Mc) {
    for (int i = threadIdx.x; i < 720; i += 256) {
        if (i < 640) {
            int kp = i / 80;
            int p0 = i - kp * 80;
            int k = p0 / 10, a = p0 - k * 10;
            float s = 0.f;
            for (int f = 0; f < FF; f++)
                s += D[kp * FF + f] * W_emb[a * FF + f] * Wr0[k * FF + f];
            T[i] = s;
        } else {
            int p0 = i - 640;
            int k = p0 / 10, a = p0 - k * 10;
            float s = 0.f;
            for (int f = 0; f < FF; f++)
                s += c0[f] * W_emb[a * FF + f] * Wr0[k * FF + f];
            Mc[p0] = s;
        }
    }
}

// -------------------- P0[n, p=a*8+k] = sum_{e:rcv=n} attrs[snd,a] eb[e,k] s0_e --------

#define P0_BLOCKS 2048
__global__ __launch_bounds__(256) void p0_kernel(const float* __restrict__ rec,
                                                 const int* __restrict__ off,
                                                 const float* __restrict__ attrs,
                                                 float* __restrict__ P0) {
    int wv = (blockIdx.x * 256 + threadIdx.x) >> 6;
    int lane = threadIdx.x & 63;
    int nwaves = P0_BLOCKS * 4;
    int a_lo = lane >> 3;
    int k_l = lane & 7;

    for (int n = wv; n < NN; n += nwaves) {
        int beg = off[n], end = off[n + 1];
        float acc = 0.f, acc2 = 0.f;
        for (int j = beg; j < end; j++) {
            const float* rc = rec + (size_t)j * RECW;
            float4 q0 = *(const float4*)&rc[0];
            float4 q1 = *(const float4*)&rc[4];
            float inv_r = q0.w;
            float s0 = q1.x;
            int snd = __float_as_int(q1.z);
            float r = 1.0f / inv_r;
            float u = r * (1.0f / RMAXF);
            float th = PI_F * u;
            float s1 = sinf(th), c1 = cosf(th);
            float u2 = u * u, u3 = u2 * u, u6 = u3 * u3, u7 = u6 * u, u8 = u6 * u2;
            float valid = (r < RMAXF) ? 1.f : 0.f;
            float env = (1.f - 28.f * u6 + 48.f * u7 - 21.f * u8) * valid;
            float sk = s1, skm = 0.f;
            float tc = 2.f * c1;
            float my = 0.f;
#pragma unroll
            for (int kk = 1; kk <= NBES; kk++) {
                if (kk - 1 == k_l) my = sk;
                float sn = tc * sk - skm; skm = sk; sk = sn;
            }
            float es = my * (CCB * inv_r * env) * s0;
            acc += attrs[snd * 10 + a_lo] * es;
            if (lane < 16) acc2 += attrs[snd * 10 + 8 + a_lo] * es;
        }
        P0[(size_t)n * 80 + lane] = acc;
        if (lane < 16) P0[(size_t)n * 80 + 64 + lane] = acc2;
    }
}

// -------------------- h1 GEMM: h1 = P0 @ GW + attrs @ Wskip0 ; node_e = h1.wread0 ------

#define GEMM_BLOCKS 512
__global__ __launch_bounds__(256, 2) void h1_gemm(const float* __restrict__ P0,
                                                  const float* __restrict__ GW,
                                                  const float* __restrict__ attrs,
                                                  const float* __restrict__ Wskip,
                                                  const float* __restrict__ wread,
                                                  float* __restrict__ h1,
                                                  float* __restrict__ node_e) {
    __shared__ float sb[80][FF];   // 40 KB
    __shared__ float sa[32][80];   // 10 KB
    int t = threadIdx.x;
#pragma unroll
    for (int j = 0; j < 10; j++) {
        int flat4 = j * 256 + t;
        int row = flat4 >> 5;
        int col = (flat4 & 31) * 4;
        *(float4*)&sb[row][col] = *(const float4*)&GW[row * FF + col];
    }

    int g = t >> 5;
    int f0 = (t & 31) * 4;
    const int NTILES = (NN + 31) / 32;

    for (int tile = blockIdx.x; tile < NTILES; tile += GEMM_BLOCKS) {
        __syncthreads();
#pragma unroll
        for (int j = 0; j < 3; j++) {
            int flat4 = j * 256 + t;
            if (flat4 < 640) {
                int row = flat4 / 20;
                int col = (flat4 - row * 20) * 4;
                int n = tile * 32 + row;
                float4 v = make_float4(0.f, 0.f, 0.f, 0.f);
                if (n < NN) v = *(const float4*)&P0[(size_t)n * 80 + col];
                *(float4*)&sa[row][col] = v;
            }
        }
        __syncthreads();

        float acc[4][4];
#pragma unroll
        for (int i = 0; i < 4; i++)
#pragma unroll
            for (int j = 0; j < 4; j++) acc[i][j] = 0.f;

        for (int kk = 0; kk < 80; kk += 4) {
            float4 bv0 = *(const float4*)&sb[kk + 0][f0];
            float4 bv1 = *(const float4*)&sb[kk + 1][f0];
            float4 bv2 = *(const float4*)&sb[kk + 2][f0];
            float4 bv3 = *(const float4*)&sb[kk + 3][f0];
#pragma unroll
            for (int ni = 0; ni < 4; ni++) {
                float4 av = *(const float4*)&sa[g * 4 + ni][kk];
                acc[ni][0] += av.x * bv0.x + av.y * bv1.x + av.z * bv2.x + av.w * bv3.x;
                acc[ni][1] += av.x * bv0.y + av.y * bv1.y + av.z * bv2.y + av.w * bv3.y;
                acc[ni][2] += av.x * bv0.z + av.y * bv1.z + av.z * bv2.z + av.w * bv3.z;
                acc[ni][3] += av.x * bv0.w + av.y * bv1.w + av.z * bv2.w + av.w * bv3.w;
            }
        }

#pragma unroll
        for (int ni = 0; ni < 4; ni++) {
            int n = tile * 32 + g * 4 + ni;
            bool valid = (n < NN);
#pragma unroll
            for (int a = 0; a < 10; a++) {
                float att = valid ? attrs[n * 10 + a] : 0.f;
                float4 wk = *(const float4*)&Wskip[a * FF + f0];
                acc[ni][0] += att * wk.x;
                acc[ni][1] += att * wk.y;
                acc[ni][2] += att * wk.z;
                acc[ni][3] += att * wk.w;
            }
            if (valid) {
                float4 out;
                out.x = acc[ni][0]; out.y = acc[ni][1];
                out.z = acc[ni][2]; out.w = acc[ni][3];
                *(float4*)&h1[(size_t)n * FF + f0] = out;
            }
            float4 wv = *(const float4*)&wread[f0];
            float p = acc[ni][0] * wv.x + acc[ni][1] * wv.y
                    + acc[ni][2] * wv.z + acc[ni][3] * wv.w;
#pragma unroll
            for (int o = 16; o > 0; o >>= 1) p += __shfl_xor(p, o);
            if (valid && (t & 31) == 0) node_e[n] = p;
        }
    }
}

// -------------------- t1[n,k] = sum_f a1[f] h1[n,f] Wr1[k,f] --------------------

__global__ __launch_bounds__(256) void t1_kernel(const float* __restrict__ h1,
                                                 const float* __restrict__ a1,
                                                 const float* __restrict__ Wr1,
                                                 float* __restrict__ t1) {
    int w = threadIdx.x >> 6;
    int lane = threadIdx.x & 63;
    int n = blockIdx.x * 4 + w;
    if (n >= NN) return;
    int f0 = lane, f1 = lane + 64;
    float v0 = a1[f0] * h1[(size_t)n * FF + f0];
    float v1 = a1[f1] * h1[(size_t)n * FF + f1];
    float p[NBES];
#pragma unroll
    for (int k = 0; k < NBES; k++)
        p[k] = v0 * Wr1[k * FF + f0] + v1 * Wr1[k * FF + f1];
#pragma unroll
    for (int o = 32; o > 0; o >>= 1) {
#pragma unroll
        for (int k = 0; k < NBES; k++) p[k] += __shfl_xor(p[k], o);
    }
    if (lane == 0) {
        *(float4*)&t1[(size_t)n * 8]     = make_float4(p[0], p[1], p[2], p[3]);
        *(float4*)&t1[(size_t)n * 8 + 4] = make_float4(p[4], p[5], p[6], p[7]);
    }
}

// -------------------- M[n][p0=k*10+a] = Mc + sum_k' E1[n,k'] T[k'][p0] ----------------

__global__ __launch_bounds__(256) void m_kernel(const float* __restrict__ E1,
                                                const float* __restrict__ T,
                                                const float* __restrict__ Mc,
                                                float* __restrict__ M) {
    __shared__ float sT[720];
    int t = threadIdx.x;
    for (int i = t; i < 720; i += 256) sT[i] = (i < 640) ? T[i] : Mc[i - 640];
    __syncthreads();
    int n = blockIdx.x * 256 + t;
    if (n >= NN) return;
    float4 ea = *(const float4*)&E1[(size_t)n * 8];
    float4 eb = *(const float4*)&E1[(size_t)n * 8 + 4];
    float e1v[8] = {ea.x, ea.y, ea.z, ea.w, eb.x, eb.y, eb.z, eb.w};
#pragma unroll
    for (int c = 0; c < 20; c++) {
        float4 m = *(const float4*)&sT[640 + c * 4];
#pragma unroll
        for (int kp = 0; kp < 8; kp++) {
            float4 tv = *(const float4*)&sT[kp * 80 + c * 4];
            m.x += e1v[kp] * tv.x;
            m.y += e1v[kp] * tv.y;
            m.z += e1v[kp] * tv.z;
            m.w += e1v[kp] * tv.w;
        }
        *(float4*)&M[(size_t)n * 80 + c * 4] = m;
    }
}

// -------------------- fused per-edge pass: recompute radial, dsp/drp, energy1, gv -----

#define EP_BLOCKS 512
__global__ __launch_bounds__(256) void edge_pass(const float* __restrict__ rec,
                                                 const float* __restrict__ t1,
                                                 const float* __restrict__ M,
                                                 const float* __restrict__ attrs,
                                                 const int* __restrict__ batch,
                                                 const float* __restrict__ wsh,
                                                 float4* __restrict__ gvp,
                                                 float* __restrict__ energy) {
    __shared__ float eacc[GG];
    int t = threadIdx.x;
    int lane = t & 63;
    if (t < GG) eacc[t] = 0.f;
    __syncthreads();

    for (int j0 = blockIdx.x * 256; j0 < EE; j0 += EP_BLOCKS * 256) {
        int j = j0 + t;
        bool act = (j < EE);
        int jc = act ? j : 0;
        const float* rc = rec + (size_t)jc * RECW;
        float4 q0 = *(const float4*)&rc[0];
        float4 q1 = *(const float4*)&rc[4];
        float x = q0.x, y = q0.y, z = q0.z, ivr = q0.w;
        float s0 = q1.x, s1v = q1.y;
        int snd = __float_as_int(q1.z);
        int rcv = __float_as_int(q1.w);

        // recompute radial eb/db
        float r = 1.0f / ivr;
        float u = r * (1.0f / RMAXF);
        float th = PI_F * u;
        float s1 = sinf(th), c1 = cosf(th);
        float u2 = u * u, u3 = u2 * u, u5 = u2 * u3, u6 = u3 * u3, u7 = u6 * u, u8 = u6 * u2;
        float valid = (r < RMAXF) ? 1.f : 0.f;
        float env = (1.f - 28.f * u6 + 48.f * u7 - 21.f * u8) * valid;
        float denv = (-168.f * u5 + 336.f * u6 - 168.f * u7) * (1.0f / RMAXF) * valid;
        float eb[NBES], db[NBES];
        {
            float sk = s1, skm = 0.f, ck = c1, ckm = 1.f;
            float tc = 2.f * c1;
#pragma unroll
            for (int k = 1; k <= NBES; k++) {
                float b = CCB * sk * ivr;
                eb[k - 1] = b * env;
                db[k - 1] = CCB * (((float)k * PI_F * (1.0f / RMAXF)) * ck * ivr
                                   - sk * ivr * ivr) * env
                            + b * denv;
                float sn = tc * sk - skm; skm = sk; sk = sn;
                float cn = tc * ck - ckm; ckm = ck; ck = cn;
            }
        }

        // layer 1: dsp1/drp1 via t1[snd]
        float4 ta = *(const float4*)&t1[(size_t)snd * 8];
        float4 tb = *(const float4*)&t1[(size_t)snd * 8 + 4];
        float tg[8] = {ta.x, ta.y, ta.z, ta.w, tb.x, tb.y, tb.z, tb.w};
        float dsp1 = 0.f, drp1 = 0.f;
#pragma unroll
        for (int k = 0; k < 8; k++) {
            dsp1 += eb[k] * tg[k];
            drp1 += db[k] * tg[k];
        }

        // layer 0: t0[k] = sum_a attrs[snd,a] M[rcv,k,a]
        float at[10];
#pragma unroll
        for (int i = 0; i < 5; i++) {
            float2 v = *(const float2*)&attrs[snd * 10 + 2 * i];
            at[2 * i] = v.x; at[2 * i + 1] = v.y;
        }
        const float* Mr = M + (size_t)rcv * 80;
        float dsp0 = 0.f, drp0 = 0.f;
#pragma unroll
        for (int k = 0; k < 8; k++) {
            float t0 = 0.f;
#pragma unroll
            for (int a = 0; a < 10; a++) t0 += at[a] * Mr[k * 10 + a];
            dsp0 += eb[k] * t0;
            drp0 += db[k] * t0;
        }

        // layer-1 energy contribution: s1 * dsp1, grouped by batch[rcv]
        float el = act ? s1v * dsp1 : 0.f;
        int b = act ? batch[rcv] : -1;
        int ub = __builtin_amdgcn_readfirstlane(b);
        if (__all(b == ub)) {
            float es = el;
#pragma unroll
            for (int o = 32; o > 0; o >>= 1) es += __shfl_xor(es, o);
            if (lane == 0 && ub >= 0) atomicAdd(&eacc[ub], es);
        } else {
            if (act) atomicAdd(&eacc[b], el);
        }

        // per-edge force vector (coalesced write)
        float g0x, g0y, g0z, g1x, g1y, g1z;
        shc_grad(x, y, z, wsh, g0x, g0y, g0z);
        shc_grad(x, y, z, wsh + 16, g1x, g1y, g1z);
        float gux = dsp0 * g0x + dsp1 * g1x;
        float guy = dsp0 * g0y + dsp1 * g1y;
        float guz = dsp0 * g0z + dsp1 * g1z;
        float gr = s0 * drp0 + s1v * drp1;
        float dgu = gux * x + guy * y + guz * z;
        float gvx = gr * x + ivr * (gux - dgu * x);
        float gvy = gr * y + ivr * (guy - dgu * y);
        float gvz = gr * z + ivr * (guz - dgu * z);
        if (act) gvp[j] = make_float4(gvx, gvy, gvz, 0.f);
    }
    __syncthreads();
    if (t < GG && eacc[t] != 0.f) atomicAdd(&energy[t], eacc[t]);
}

// -------------------- force gather (thread-per-node, no atomics) ----------------------

__global__ __launch_bounds__(256) void force_gather(const int* __restrict__ off_rcv,
                                                    const int* __restrict__ off_snd,
                                                    const int* __restrict__ psl_j,
                                                    const float4* __restrict__ gvp,
                                                    float* __restrict__ forces) {
    int n = blockIdx.x * 256 + threadIdx.x;
    if (n >= NN) return;
    float fx = 0.f, fy = 0.f, fz = 0.f;
    int beg = off_rcv[n], end = off_rcv[n + 1];
    for (int j = beg; j < end; j++) {
        float4 g = gvp[j];
        fx -= g.x; fy -= g.y; fz -= g.z;
    }
    beg = off_snd[n]; end = off_snd[n + 1];
    for (int s = beg; s < end; s++) {
        float4 g = gvp[psl_j[s]];
        fx += g.x; fy += g.y; fz += g.z;
    }
    forces[n * 3 + 0] = fx;
    forces[n * 3 + 1] = fy;
    forces[n * 3 + 2] = fz;
}

// -------------------- energy finalize: node_e + attrs.askip --------------------

#define EF_BLOCKS 128
__global__ __launch_bounds__(256) void efinal_kernel(const float* __restrict__ node_e,
                                                     const float* __restrict__ attrs,
                                                     const float* __restrict__ askip,
                                                     const int* __restrict__ batch,
                                                     float* __restrict__ energy) {
    __shared__ float eacc[GG];
    int t = threadIdx.x;
    if (t < GG) eacc[t] = 0.f;
    __syncthreads();
    for (int n = blockIdx.x * 256 + t; n < NN; n += EF_BLOCKS * 256) {
        float v = node_e[n];
#pragma unroll
        for (int a = 0; a < 10; a++) v += attrs[n * 10 + a] * askip[a];
        atomicAdd(&eacc[batch[n]], v);
    }
    __syncthreads();
    if (t < GG && eacc[t] != 0.f) atomicAdd(&energy[t], eacc[t]);
}

// -------------------- launch --------------------

extern "C" void kernel_launch(void* const* d_in, const int* in_sizes, int n_in,
                              void* d_out, int out_size, void* d_ws, size_t ws_size,
                              hipStream_t stream) {
    const float* pos    = (const float*)d_in[0];
    const float* attrs  = (const float*)d_in[1];
    const float* shifts = (const float*)d_in[2];
    const int*   ei     = (const int*)d_in[3];
    const int*   batch  = (const int*)d_in[4];
    const float* W_emb  = (const float*)d_in[6];
    const float* ae     = (const float*)d_in[7];
    const float* W_r    = (const float*)d_in[8];   // (2,8,F)
    const float* w_sh   = (const float*)d_in[9];   // (2,16)
    const float* W_out  = (const float*)d_in[10];  // (2,F,F)
    const float* W_skip = (const float*)d_in[11];  // (2,10,F)
    const float* w_read = (const float*)d_in[12];  // (2,F)

    const float* Wr0 = W_r;
    const float* Wr1 = W_r + NBES * FF;
    const float* Wout0 = W_out;
    const float* Wout1 = W_out + FF * FF;

    float* energy = (float*)d_out;
    float* forces = energy + GG;

    float* ws  = (float*)d_ws;
    float* h1  = ws;                        // N*F
    float* P0  = h1 + (size_t)NN * FF;      // N*80
    float* M   = P0 + (size_t)NN * 80;      // N*80
    float* E1  = M + (size_t)NN * 80;       // N*8
    float* t1  = E1 + (size_t)NN * 8;       // N*8
    float* node_e = t1 + (size_t)NN * 8;    // N
    float* rec = node_e + NN;               // EE*8
    float4* gvp = (float4*)(rec + (size_t)EE * RECW);  // EE*4 floats
    float* a1  = (float*)(gvp + EE);        // 128
    float* askip = a1 + FF;                 // 16
    float* c0  = askip + 16;                // 128
    float* D   = c0 + FF;                   // 8*128
    float* GW  = D + NBES * FF;             // 80*128
    float* T   = GW + 80 * FF;              // 640
    float* Mc  = T + 640;                   // 80

    int* cnt    = (int*)(Mc + 80);          // 2N
    int* off    = cnt + 2 * NN;             // 2(N+1)
    int* rank_r = off + 2 * (NN + 1);       // EE
    int* rank_s = rank_r + EE;              // EE
    int* jr     = rank_s + EE;              // EE
    int* psl_j  = jr + EE;                  // EE
    const int* off_rcv = off;
    const int* off_snd = off + (NN + 1);

    const int edgeBlocks = (EE + 255) / 256;
    const int nodeBlocks = (NN + 255) / 256;

    hipMemsetAsync(d_out, 0, (size_t)out_size * sizeof(float), stream);
    hipMemsetAsync(cnt, 0, (size_t)2 * NN * sizeof(int), stream);

    // CSR build: atomics only in count (rank capture); fill is atomic-free
    count_kernel<<<edgeBlocks, 256, 0, stream>>>(ei, cnt, rank_r, rank_s);
    scan_kernel<<<2, 256, 0, stream>>>(cnt, off);
    fill_kernel<<<edgeBlocks, 256, 0, stream>>>(ei, off, rank_r, rank_s, jr, psl_j);

    // small precomputes
    a1_kernel<<<1, 128, 0, stream>>>(Wout1, w_read + FF, W_skip + 10 * FF, ae, a1, askip);
    cd_kernel<<<1, 128, 0, stream>>>(Wout0, w_read, a1, Wr1, c0, D);
    gw_kernel<<<40, 256, 0, stream>>>(W_emb, Wr0, Wout0, GW);
    tmc_kernel<<<1, 256, 0, stream>>>(D, c0, W_emb, Wr0, T, Mc);

    // compact geometry records (32B sector scatter via jr)
    edge_geom<<<edgeBlocks, 256, 0, stream>>>(pos, shifts, ei, w_sh, jr, rec);

    // E1 via snd-CSR gather of records (8 lanes/node, no atomics)
    e1_csr<<<(NN * 8 + 255) / 256, 256, 0, stream>>>(rec, off_snd, psl_j, E1);

    // P0, then h1, t1, M
    p0_kernel<<<P0_BLOCKS, 256, 0, stream>>>(rec, off_rcv, attrs, P0);
    h1_gemm<<<GEMM_BLOCKS, 256, 0, stream>>>(P0, GW, attrs, W_skip, w_read, h1, node_e);
    t1_kernel<<<(NN + 3) / 4, 256, 0, stream>>>(h1, a1, Wr1, t1);
    m_kernel<<<nodeBlocks, 256, 0, stream>>>(E1, T, Mc, M);

    // fused per-edge: recompute radial, dsp/drp both layers, layer-1 energy, gv
    edge_pass<<<EP_BLOCKS, 256, 0, stream>>>(rec, t1, M, attrs, batch, w_sh, gvp, energy);

    // forces via CSR gather (no atomics)
    force_gather<<<nodeBlocks, 256, 0, stream>>>(off_rcv, off_snd, psl_j, gvp, forces);

    // energy finalize (layer-0 node energies + layer-1 skip + e0)
    efinal_kernel<<<EF_BLOCKS, 256, 0, stream>>>(node_e, attrs, askip, batch, energy);
}

// Round 12
// 526.460 us; speedup vs baseline: 2.0028x; 1.0678x over previous
//
#include <hip/hip_runtime.h>

#define NN 50000
#define EE 800000
#define GG 64
#define FF 128
#define NBES 8
#define RECW 8    // compact record: x, y, z, inv_r, s0, s1, snd, rcv  (32 B)
#define RMAXF 5.0f
#define PI_F 3.14159265358979323846f

// spherical harmonic constants
#define S3  1.7320508075688772f
#define S5  2.23606797749979f
#define S15 3.872983346207417f
#define C1c 2.091650066335189f   // sqrt(35/8)
#define C2c 10.246950765959598f  // sqrt(105)
#define C3c 1.62018517460196f    // sqrt(21/8)
#define C4c 1.3228756555322954f  // sqrt(7)/2
#define C5c 5.123475382979799f   // sqrt(105)/2
#define CCB 0.6324555320336759f  // sqrt(2/5)

__device__ __forceinline__ float shc_s(float x, float y, float z, const float* __restrict__ w) {
    float x2 = x * x, y2 = y * y, z2 = z * z;
    return w[0]
        + w[1] * (S3 * x) + w[2] * (S3 * y) + w[3] * (S3 * z)
        + w[4] * (S15 * x * y) + w[5] * (S15 * y * z) + w[6] * (0.5f * S5 * (3.f * z2 - 1.f))
        + w[7] * (S15 * x * z) + w[8] * (0.5f * S15 * (x2 - y2))
        + w[9] * (C1c * y * (3.f * x2 - y2)) + w[10] * (C2c * x * y * z)
        + w[11] * (C3c * y * (5.f * z2 - 1.f)) + w[12] * (C4c * z * (5.f * z2 - 3.f))
        + w[13] * (C3c * x * (5.f * z2 - 1.f)) + w[14] * (C5c * z * (x2 - y2))
        + w[15] * (C1c * x * (x2 - 3.f * y2));
}

__device__ __forceinline__ void shc_grad(float x, float y, float z, const float* __restrict__ w,
                                         float& gx, float& gy, float& gz) {
    float x2 = x * x, y2 = y * y, z2 = z * z;
    gx = w[1] * S3 + w[4] * (S15 * y) + w[7] * (S15 * z) + w[8] * (S15 * x)
       + w[9] * (6.f * C1c * x * y) + w[10] * (C2c * y * z) + w[13] * (C3c * (5.f * z2 - 1.f))
       + w[14] * (2.f * C5c * x * z) + w[15] * (3.f * C1c * (x2 - y2));
    gy = w[2] * S3 + w[4] * (S15 * x) + w[5] * (S15 * z) - w[8] * (S15 * y)
       + w[9] * (3.f * C1c * (x2 - y2)) + w[10] * (C2c * x * z) + w[11] * (C3c * (5.f * z2 - 1.f))
       - w[14] * (2.f * C5c * y * z) - w[15] * (6.f * C1c * x * y);
    gz = w[3] * S3 + w[5] * (S15 * y) + w[6] * (3.f * S5 * z) + w[7] * (S15 * x)
       + w[10] * (C2c * x * y) + w[11] * (10.f * C3c * y * z) + w[12] * (C4c * (15.f * z2 - 3.f))
       + w[13] * (10.f * C3c * x * z) + w[14] * (C5c * (x2 - y2));
}

// -------------------- CSR build --------------------

// ranks via atomic return value (the only atomics in the build)
__global__ __launch_bounds__(256) void count_kernel(const int* __restrict__ ei,
                                                    int* __restrict__ cnt,
                                                    int* __restrict__ rank_r,
                                                    int* __restrict__ rank_s) {
    int e = blockIdx.x * 256 + threadIdx.x;
    if (e >= EE) return;
    rank_r[e] = atomicAdd(&cnt[ei[EE + e]], 1);
    rank_s[e] = atomicAdd(&cnt[NN + ei[e]], 1);
}

// one block per half (rcv / snd); chunked scan cnt[NN] -> off[NN+1]
__global__ __launch_bounds__(256) void scan_kernel(const int* __restrict__ cnt,
                                                   int* __restrict__ off) {
    const int* c = cnt + (size_t)blockIdx.x * NN;
    int* o = off + (size_t)blockIdx.x * (NN + 1);
    __shared__ int wsum[4];
    __shared__ int carry_s;
    if (threadIdx.x == 0) carry_s = 0;
    __syncthreads();
    int lane = threadIdx.x & 63;
    int wid = threadIdx.x >> 6;
    for (int base = 0; base < NN; base += 256) {
        int i = base + threadIdx.x;
        int v = (i < NN) ? c[i] : 0;
        int x = v;
#pragma unroll
        for (int d = 1; d < 64; d <<= 1) {
            int y = __shfl_up(x, d);
            if (lane >= d) x += y;
        }
        if (lane == 63) wsum[wid] = x;
        __syncthreads();
        int pre = 0;
#pragma unroll
        for (int w = 0; w < 4; w++) if (w < wid) pre += wsum[w];
        int total = wsum[0] + wsum[1] + wsum[2] + wsum[3];
        int carry = carry_s;
        if (i < NN) o[i] = carry + pre + x - v;
        __syncthreads();
        if (threadIdx.x == 0) carry_s = carry + total;
        __syncthreads();
    }
    if (threadIdx.x == 0) o[NN] = carry_s;
}

// jr[e] = rcv-slot of e (coalesced); psl_j[snd-slot] = rcv-slot (single 4B scatter)
__global__ __launch_bounds__(256) void fill_kernel(const int* __restrict__ ei,
                                                   const int* __restrict__ off,
                                                   const int* __restrict__ rank_r,
                                                   const int* __restrict__ rank_s,
                                                   int* __restrict__ jr,
                                                   int* __restrict__ psl_j) {
    int e = blockIdx.x * 256 + threadIdx.x;
    if (e >= EE) return;
    int snd = ei[e], rcv = ei[EE + e];
    int sr = off[rcv] + rank_r[e];
    int ss = off[(NN + 1) + snd] + rank_s[e];
    jr[e] = sr;
    psl_j[ss] = sr;
}

// -------------------- geometry: thread = edge (coalesced in), 32B sector scatter out --

__global__ __launch_bounds__(256) void edge_geom(const float* __restrict__ pos,
                                                 const float* __restrict__ shifts,
                                                 const int* __restrict__ ei,
                                                 const float* __restrict__ wsh,
                                                 const int* __restrict__ jr,
                                                 float* __restrict__ rec) {
    int e = blockIdx.x * 256 + threadIdx.x;
    if (e >= EE) return;
    int snd = ei[e];
    int rcv = ei[EE + e];
    float vx = pos[rcv * 3 + 0] - pos[snd * 3 + 0] + shifts[e * 3 + 0];
    float vy = pos[rcv * 3 + 1] - pos[snd * 3 + 1] + shifts[e * 3 + 1];
    float vz = pos[rcv * 3 + 2] - pos[snd * 3 + 2] + shifts[e * 3 + 2];
    float r2 = vx * vx + vy * vy + vz * vz + 1e-12f;
    float r = sqrtf(r2);
    float inv_r = 1.0f / r;
    float x = vx * inv_r, y = vy * inv_r, z = vz * inv_r;

    float s0 = shc_s(x, y, z, wsh);
    float s1v = shc_s(x, y, z, wsh + 16);

    float* rc = rec + (size_t)jr[e] * RECW;
    *(float4*)&rc[0] = make_float4(x, y, z, inv_r);
    *(float4*)&rc[4] = make_float4(s0, s1v, __int_as_float(snd), __int_as_float(rcv));
}

// -------------------- E1 over snd-CSR: 8 lanes per node, gather compact records -------
// E1[n,k] = sum_{e: snd=n} eb[k] * s1 ;  eb[k] = CCB*inv_r*env * sin((k+1)*th)

__global__ __launch_bounds__(256) void e1_csr(const float* __restrict__ rec,
                                              const int* __restrict__ off_snd,
                                              const int* __restrict__ psl_j,
                                              float* __restrict__ E1) {
    int gid = blockIdx.x * 256 + threadIdx.x;
    int n = gid >> 3;
    int k_l = gid & 7;
    if (n >= NN) return;
    float kf = (float)(k_l + 1);
    int beg = off_snd[n], end = off_snd[n + 1];
    float acc = 0.f;
    for (int s = beg; s < end; s++) {
        int j = psl_j[s];
        const float* rc = rec + (size_t)j * RECW;
        float inv_r = rc[3];
        float s1v = rc[5];
        float r = 1.0f / inv_r;
        float u = r * (1.0f / RMAXF);
        float th = PI_F * u;
        float u2 = u * u, u3 = u2 * u, u6 = u3 * u3, u7 = u6 * u, u8 = u6 * u2;
        float valid = (r < RMAXF) ? 1.f : 0.f;
        float env = (1.f - 28.f * u6 + 48.f * u7 - 21.f * u8) * valid;
        float my = sinf(kf * th);
        acc += my * (CCB * inv_r * env * s1v);
    }
    E1[(size_t)n * 8 + k_l] = acc;
}

// -------------------- small precomputes --------------------

__global__ __launch_bounds__(128) void a1_kernel(const float* __restrict__ Wout1,
                                                 const float* __restrict__ wread1,
                                                 const float* __restrict__ Wskip1,
                                                 const float* __restrict__ ae,
                                                 float* __restrict__ a1,
                                                 float* __restrict__ askip) {
    int f = threadIdx.x;
    float s = 0.f;
    for (int k = 0; k < FF; k++) s += Wout1[f * FF + k] * wread1[k];
    a1[f] = s;
    if (f < 10) {
        float t = 0.f;
        for (int k = 0; k < FF; k++) t += Wskip1[f * FF + k] * wread1[k];
        askip[f] = t + ae[f];
    }
}

// c0[f'] = sum_f wread0[f] Wout0[f',f];  D[k,f'] = sum_f a1[f] Wr1[k,f] Wout0[f',f]
__global__ __launch_bounds__(128) void cd_kernel(const float* __restrict__ Wout0,
                                                 const float* __restrict__ wread0,
                                                 const float* __restrict__ a1,
                                                 const float* __restrict__ Wr1,
                                                 float* __restrict__ c0,
                                                 float* __restrict__ D) {
    int fp = threadIdx.x;
    float c = 0.f;
    float d[NBES];
#pragma unroll
    for (int k = 0; k < NBES; k++) d[k] = 0.f;
    for (int f = 0; f < FF; f++) {
        float w = Wout0[fp * FF + f];
        c += wread0[f] * w;
        float aw = a1[f] * w;
#pragma unroll
        for (int k = 0; k < NBES; k++) d[k] += aw * Wr1[k * FF + f];
    }
    c0[fp] = c;
#pragma unroll
    for (int k = 0; k < NBES; k++) D[k * FF + fp] = d[k];
}

// GW[p=a*8+k][f'] = sum_f W_emb[a,f] Wr0[k,f] Wout0[f,f']
__global__ __launch_bounds__(256) void gw_kernel(const float* __restrict__ W_emb,
                                                 const float* __restrict__ Wr0,
                                                 const float* __restrict__ Wout0,
                                                 float* __restrict__ GW) {
    int idx = blockIdx.x * 256 + threadIdx.x;
    if (idx >= 80 * FF) return;
    int fp = idx & 127;
    int p = idx >> 7;
    int a = p >> 3, k = p & 7;
    float s = 0.f;
    for (int f = 0; f < FF; f++)
        s += W_emb[a * FF + f] * Wr0[k * FF + f] * Wout0[f * FF + fp];
    GW[p * FF + fp] = s;
}

// T[k'][p0=k*10+a] = sum_f D[k',f] W_emb[a,f] Wr0[k,f];  Mc[p0] = sum_f c0[f] W_emb Wr0
__global__ __launch_bounds__(256) void tmc_kernel(const float* __restrict__ D,
                                                  const float* __restrict__ c0,
                                                  const float* __restrict__ W_emb,
                                                  const float* __restrict__ Wr0,
                                                  float* __restrict__ T,
                                                  float* __restrict__ Mc) {
    for (int i = threadIdx.x; i < 720; i += 256) {
        if (i < 640) {
            int kp = i / 80;
            int p0 = i - kp * 80;
            int k = p0 / 10, a = p0 - k * 10;
            float s = 0.f;
            for (int f = 0; f < FF; f++)
                s += D[kp * FF + f] * W_emb[a * FF + f] * Wr0[k * FF + f];
            T[i] = s;
        } else {
            int p0 = i - 640;
            int k = p0 / 10, a = p0 - k * 10;
            float s = 0.f;
            for (int f = 0; f < FF; f++)
                s += c0[f] * W_emb[a * FF + f] * Wr0[k * FF + f];
            Mc[p0] = s;
        }
    }
}

// -------------------- P0[n, p=a*8+k] = sum_{e:rcv=n} attrs[snd,a] eb[e,k] s0_e --------

#define P0_BLOCKS 2048
__global__ __launch_bounds__(256) void p0_kernel(const float* __restrict__ rec,
                                                 const int* __restrict__ off,
                                                 const float* __restrict__ attrs,
                                                 float* __restrict__ P0) {
    int wv = (blockIdx.x * 256 + threadIdx.x) >> 6;
    int lane = threadIdx.x & 63;
    int nwaves = P0_BLOCKS * 4;
    int a_lo = lane >> 3;
    int k_l = lane & 7;
    float kf = (float)(k_l + 1);

    for (int n = wv; n < NN; n += nwaves) {
        int beg = off[n], end = off[n + 1];
        float acc = 0.f, acc2 = 0.f;
        for (int j = beg; j < end; j++) {
            const float* rc = rec + (size_t)j * RECW;
            float inv_r = rc[3];
            float s0 = rc[4];
            int snd = __float_as_int(rc[6]);
            float r = 1.0f / inv_r;
            float u = r * (1.0f / RMAXF);
            float th = PI_F * u;
            float u2 = u * u, u3 = u2 * u, u6 = u3 * u3, u7 = u6 * u, u8 = u6 * u2;
            float valid = (r < RMAXF) ? 1.f : 0.f;
            float env = (1.f - 28.f * u6 + 48.f * u7 - 21.f * u8) * valid;
            float my = sinf(kf * th);
            float es = my * (CCB * inv_r * env) * s0;
            acc += attrs[snd * 10 + a_lo] * es;
            if (lane < 16) acc2 += attrs[snd * 10 + 8 + a_lo] * es;
        }
        P0[(size_t)n * 80 + lane] = acc;
        if (lane < 16) P0[(size_t)n * 80 + 64 + lane] = acc2;
    }
}

// -------------------- h1 GEMM: h1 = P0 @ GW + attrs @ Wskip0 ; node_e = h1.wread0 ------

#define GEMM_BLOCKS 512
__global__ __launch_bounds__(256, 2) void h1_gemm(const float* __restrict__ P0,
                                                  const float* __restrict__ GW,
                                                  const float* __restrict__ attrs,
                                                  const float* __restrict__ Wskip,
                                                  const float* __restrict__ wread,
                                                  float* __restrict__ h1,
                                                  float* __restrict__ node_e) {
    __shared__ float sb[80][FF];   // 40 KB
    __shared__ float sa[32][80];   // 10 KB
    int t = threadIdx.x;
#pragma unroll
    for (int j = 0; j < 10; j++) {
        int flat4 = j * 256 + t;
        int row = flat4 >> 5;
        int col = (flat4 & 31) * 4;
        *(float4*)&sb[row][col] = *(const float4*)&GW[row * FF + col];
    }

    int g = t >> 5;
    int f0 = (t & 31) * 4;
    const int NTILES = (NN + 31) / 32;

    for (int tile = blockIdx.x; tile < NTILES; tile += GEMM_BLOCKS) {
        __syncthreads();
#pragma unroll
        for (int j = 0; j < 3; j++) {
            int flat4 = j * 256 + t;
            if (flat4 < 640) {
                int row = flat4 / 20;
                int col = (flat4 - row * 20) * 4;
                int n = tile * 32 + row;
                float4 v = make_float4(0.f, 0.f, 0.f, 0.f);
                if (n < NN) v = *(const float4*)&P0[(size_t)n * 80 + col];
                *(float4*)&sa[row][col] = v;
            }
        }
        __syncthreads();

        float acc[4][4];
#pragma unroll
        for (int i = 0; i < 4; i++)
#pragma unroll
            for (int j = 0; j < 4; j++) acc[i][j] = 0.f;

        for (int kk = 0; kk < 80; kk += 4) {
            float4 bv0 = *(const float4*)&sb[kk + 0][f0];
            float4 bv1 = *(const float4*)&sb[kk + 1][f0];
            float4 bv2 = *(const float4*)&sb[kk + 2][f0];
            float4 bv3 = *(const float4*)&sb[kk + 3][f0];
#pragma unroll
            for (int ni = 0; ni < 4; ni++) {
                float4 av = *(const float4*)&sa[g * 4 + ni][kk];
                acc[ni][0] += av.x * bv0.x + av.y * bv1.x + av.z * bv2.x + av.w * bv3.x;
                acc[ni][1] += av.x * bv0.y + av.y * bv1.y + av.z * bv2.y + av.w * bv3.y;
                acc[ni][2] += av.x * bv0.z + av.y * bv1.z + av.z * bv2.z + av.w * bv3.z;
                acc[ni][3] += av.x * bv0.w + av.y * bv1.w + av.z * bv2.w + av.w * bv3.w;
            }
        }

#pragma unroll
        for (int ni = 0; ni < 4; ni++) {
            int n = tile * 32 + g * 4 + ni;
            bool valid = (n < NN);
#pragma unroll
            for (int a = 0; a < 10; a++) {
                float att = valid ? attrs[n * 10 + a] : 0.f;
                float4 wk = *(const float4*)&Wskip[a * FF + f0];
                acc[ni][0] += att * wk.x;
                acc[ni][1] += att * wk.y;
                acc[ni][2] += att * wk.z;
                acc[ni][3] += att * wk.w;
            }
            if (valid) {
                float4 out;
                out.x = acc[ni][0]; out.y = acc[ni][1];
                out.z = acc[ni][2]; out.w = acc[ni][3];
                *(float4*)&h1[(size_t)n * FF + f0] = out;
            }
            float4 wv = *(const float4*)&wread[f0];
            float p = acc[ni][0] * wv.x + acc[ni][1] * wv.y
                    + acc[ni][2] * wv.z + acc[ni][3] * wv.w;
#pragma unroll
            for (int o = 16; o > 0; o >>= 1) p += __shfl_xor(p, o);
            if (valid && (t & 31) == 0) node_e[n] = p;
        }
    }
}

// -------------------- t1[n,k] = sum_f a1[f] h1[n,f] Wr1[k,f] --------------------

__global__ __launch_bounds__(256) void t1_kernel(const float* __restrict__ h1,
                                                 const float* __restrict__ a1,
                                                 const float* __restrict__ Wr1,
                                                 float* __restrict__ t1) {
    int w = threadIdx.x >> 6;
    int lane = threadIdx.x & 63;
    int n = blockIdx.x * 4 + w;
    if (n >= NN) return;
    int f0 = lane, f1 = lane + 64;
    float v0 = a1[f0] * h1[(size_t)n * FF + f0];
    float v1 = a1[f1] * h1[(size_t)n * FF + f1];
    float p[NBES];
#pragma unroll
    for (int k = 0; k < NBES; k++)
        p[k] = v0 * Wr1[k * FF + f0] + v1 * Wr1[k * FF + f1];
#pragma unroll
    for (int o = 32; o > 0; o >>= 1) {
#pragma unroll
        for (int k = 0; k < NBES; k++) p[k] += __shfl_xor(p[k], o);
    }
    if (lane == 0) {
        *(float4*)&t1[(size_t)n * 8]     = make_float4(p[0], p[1], p[2], p[3]);
        *(float4*)&t1[(size_t)n * 8 + 4] = make_float4(p[4], p[5], p[6], p[7]);
    }
}

// -------------------- M[n][p0=k*10+a] = Mc + sum_k' E1[n,k'] T[k'][p0] ----------------

__global__ __launch_bounds__(256) void m_kernel(const float* __restrict__ E1,
                                                const float* __restrict__ T,
                                                const float* __restrict__ Mc,
                                                float* __restrict__ M) {
    __shared__ float sT[720];
    int t = threadIdx.x;
    for (int i = t; i < 720; i += 256) sT[i] = (i < 640) ? T[i] : Mc[i - 640];
    __syncthreads();
    int n = blockIdx.x * 256 + t;
    if (n >= NN) return;
    float4 ea = *(const float4*)&E1[(size_t)n * 8];
    float4 eb = *(const float4*)&E1[(size_t)n * 8 + 4];
    float e1v[8] = {ea.x, ea.y, ea.z, ea.w, eb.x, eb.y, eb.z, eb.w};
#pragma unroll
    for (int c = 0; c < 20; c++) {
        float4 m = *(const float4*)&sT[640 + c * 4];
#pragma unroll
        for (int kp = 0; kp < 8; kp++) {
            float4 tv = *(const float4*)&sT[kp * 80 + c * 4];
            m.x += e1v[kp] * tv.x;
            m.y += e1v[kp] * tv.y;
            m.z += e1v[kp] * tv.z;
            m.w += e1v[kp] * tv.w;
        }
        *(float4*)&M[(size_t)n * 80 + c * 4] = m;
    }
}

// -------------------- fused per-edge pass: recompute radial, dsp/drp, energy1, gv -----

#define EP_BLOCKS 512
__global__ __launch_bounds__(256) void edge_pass(const float* __restrict__ rec,
                                                 const float* __restrict__ t1,
                                                 const float* __restrict__ M,
                                                 const float* __restrict__ attrs,
                                                 const int* __restrict__ batch,
                                                 const float* __restrict__ wsh,
                                                 float4* __restrict__ gvp,
                                                 float* __restrict__ energy) {
    __shared__ float eacc[GG];
    int t = threadIdx.x;
    int lane = t & 63;
    if (t < GG) eacc[t] = 0.f;
    __syncthreads();

    for (int j0 = blockIdx.x * 256; j0 < EE; j0 += EP_BLOCKS * 256) {
        int j = j0 + t;
        bool act = (j < EE);
        int jc = act ? j : 0;
        const float* rc = rec + (size_t)jc * RECW;
        float4 q0 = *(const float4*)&rc[0];
        float4 q1 = *(const float4*)&rc[4];
        float x = q0.x, y = q0.y, z = q0.z, ivr = q0.w;
        float s0 = q1.x, s1v = q1.y;
        int snd = __float_as_int(q1.z);
        int rcv = __float_as_int(q1.w);

        // recompute radial eb/db
        float r = 1.0f / ivr;
        float u = r * (1.0f / RMAXF);
        float th = PI_F * u;
        float s1 = sinf(th), c1 = cosf(th);
        float u2 = u * u, u3 = u2 * u, u5 = u2 * u3, u6 = u3 * u3, u7 = u6 * u, u8 = u6 * u2;
        float valid = (r < RMAXF) ? 1.f : 0.f;
        float env = (1.f - 28.f * u6 + 48.f * u7 - 21.f * u8) * valid;
        float denv = (-168.f * u5 + 336.f * u6 - 168.f * u7) * (1.0f / RMAXF) * valid;
        float eb[NBES], db[NBES];
        {
            float sk = s1, skm = 0.f, ck = c1, ckm = 1.f;
            float tc = 2.f * c1;
#pragma unroll
            for (int k = 1; k <= NBES; k++) {
                float b = CCB * sk * ivr;
                eb[k - 1] = b * env;
                db[k - 1] = CCB * (((float)k * PI_F * (1.0f / RMAXF)) * ck * ivr
                                   - sk * ivr * ivr) * env
                            + b * denv;
                float sn = tc * sk - skm; skm = sk; sk = sn;
                float cn = tc * ck - ckm; ckm = ck; ck = cn;
            }
        }

        // layer 1: dsp1/drp1 via t1[snd]
        float4 ta = *(const float4*)&t1[(size_t)snd * 8];
        float4 tb = *(const float4*)&t1[(size_t)snd * 8 + 4];
        float tg[8] = {ta.x, ta.y, ta.z, ta.w, tb.x, tb.y, tb.z, tb.w};
        float dsp1 = 0.f, drp1 = 0.f;
#pragma unroll
        for (int k = 0; k < 8; k++) {
            dsp1 += eb[k] * tg[k];
            drp1 += db[k] * tg[k];
        }

        // layer 0: t0[k] = sum_a attrs[snd,a] M[rcv,k,a]
        float at[10];
#pragma unroll
        for (int i = 0; i < 5; i++) {
            float2 v = *(const float2*)&attrs[snd * 10 + 2 * i];
            at[2 * i] = v.x; at[2 * i + 1] = v.y;
        }
        const float* Mr = M + (size_t)rcv * 80;
        float dsp0 = 0.f, drp0 = 0.f;
#pragma unroll
        for (int k = 0; k < 8; k++) {
            float t0 = 0.f;
#pragma unroll
            for (int a = 0; a < 10; a++) t0 += at[a] * Mr[k * 10 + a];
            dsp0 += eb[k] * t0;
            drp0 += db[k] * t0;
        }

        // layer-1 energy contribution: s1 * dsp1, grouped by batch[rcv]
        float el = act ? s1v * dsp1 : 0.f;
        int b = act ? batch[rcv] : -1;
        int ub = __builtin_amdgcn_readfirstlane(b);
        if (__all(b == ub)) {
            float es = el;
#pragma unroll
            for (int o = 32; o > 0; o >>= 1) es += __shfl_xor(es, o);
            if (lane == 0 && ub >= 0) atomicAdd(&eacc[ub], es);
        } else {
            if (act) atomicAdd(&eacc[b], el);
        }

        // per-edge force vector (coalesced write)
        float g0x, g0y, g0z, g1x, g1y, g1z;
        shc_grad(x, y, z, wsh, g0x, g0y, g0z);
        shc_grad(x, y, z, wsh + 16, g1x, g1y, g1z);
        float gux = dsp0 * g0x + dsp1 * g1x;
        float guy = dsp0 * g0y + dsp1 * g1y;
        float guz = dsp0 * g0z + dsp1 * g1z;
        float gr = s0 * drp0 + s1v * drp1;
        float dgu = gux * x + guy * y + guz * z;
        float gvx = gr * x + ivr * (gux - dgu * x);
        float gvy = gr * y + ivr * (guy - dgu * y);
        float gvz = gr * z + ivr * (guz - dgu * z);
        if (act) gvp[j] = make_float4(gvx, gvy, gvz, 0.f);
    }
    __syncthreads();
    if (t < GG && eacc[t] != 0.f) atomicAdd(&energy[t], eacc[t]);
}

// -------------------- force gather (thread-per-node, no atomics) ----------------------

__global__ __launch_bounds__(256) void force_gather(const int* __restrict__ off_rcv,
                                                    const int* __restrict__ off_snd,
                                                    const int* __restrict__ psl_j,
                                                    const float4* __restrict__ gvp,
                                                    float* __restrict__ forces) {
    int n = blockIdx.x * 256 + threadIdx.x;
    if (n >= NN) return;
    float fx = 0.f, fy = 0.f, fz = 0.f;
    int beg = off_rcv[n], end = off_rcv[n + 1];
    for (int j = beg; j < end; j++) {
        float4 g = gvp[j];
        fx -= g.x; fy -= g.y; fz -= g.z;
    }
    beg = off_snd[n]; end = off_snd[n + 1];
    for (int s = beg; s < end; s++) {
        float4 g = gvp[psl_j[s]];
        fx += g.x; fy += g.y; fz += g.z;
    }
    forces[n * 3 + 0] = fx;
    forces[n * 3 + 1] = fy;
    forces[n * 3 + 2] = fz;
}

// -------------------- energy finalize: node_e + attrs.askip --------------------

#define EF_BLOCKS 128
__global__ __launch_bounds__(256) void efinal_kernel(const float* __restrict__ node_e,
                                                     const float* __restrict__ attrs,
                                                     const float* __restrict__ askip,
                                                     const int* __restrict__ batch,
                                                     float* __restrict__ energy) {
    __shared__ float eacc[GG];
    int t = threadIdx.x;
    if (t < GG) eacc[t] = 0.f;
    __syncthreads();
    for (int n = blockIdx.x * 256 + t; n < NN; n += EF_BLOCKS * 256) {
        float v = node_e[n];
#pragma unroll
        for (int a = 0; a < 10; a++) v += attrs[n * 10 + a] * askip[a];
        atomicAdd(&eacc[batch[n]], v);
    }
    __syncthreads();
    if (t < GG && eacc[t] != 0.f) atomicAdd(&energy[t], eacc[t]);
}

// -------------------- launch --------------------

extern "C" void kernel_launch(void* const* d_in, const int* in_sizes, int n_in,
                              void* d_out, int out_size, void* d_ws, size_t ws_size,
                              hipStream_t stream) {
    const float* pos    = (const float*)d_in[0];
    const float* attrs  = (const float*)d_in[1];
    const float* shifts = (const float*)d_in[2];
    const int*   ei     = (const int*)d_in[3];
    const int*   batch  = (const int*)d_in[4];
    const float* W_emb  = (const float*)d_in[6];
    const float* ae     = (const float*)d_in[7];
    const float* W_r    = (const float*)d_in[8];   // (2,8,F)
    const float* w_sh   = (const float*)d_in[9];   // (2,16)
    const float* W_out  = (const float*)d_in[10];  // (2,F,F)
    const float* W_skip = (const float*)d_in[11];  // (2,10,F)
    const float* w_read = (const float*)d_in[12];  // (2,F)

    const float* Wr0 = W_r;
    const float* Wr1 = W_r + NBES * FF;
    const float* Wout0 = W_out;
    const float* Wout1 = W_out + FF * FF;

    float* energy = (float*)d_out;
    float* forces = energy + GG;

    float* ws  = (float*)d_ws;
    float* h1  = ws;                        // N*F
    float* P0  = h1 + (size_t)NN * FF;      // N*80
    float* M   = P0 + (size_t)NN * 80;      // N*80
    float* E1  = M + (size_t)NN * 80;       // N*8
    float* t1  = E1 + (size_t)NN * 8;       // N*8
    float* node_e = t1 + (size_t)NN * 8;    // N
    float* rec = node_e + NN;               // EE*8
    float4* gvp = (float4*)(rec + (size_t)EE * RECW);  // EE*4 floats
    float* a1  = (float*)(gvp + EE);        // 128
    float* askip = a1 + FF;                 // 16
    float* c0  = askip + 16;                // 128
    float* D   = c0 + FF;                   // 8*128
    float* GW  = D + NBES * FF;             // 80*128
    float* T   = GW + 80 * FF;              // 640
    float* Mc  = T + 640;                   // 80

    int* cnt    = (int*)(Mc + 80);          // 2N
    int* off    = cnt + 2 * NN;             // 2(N+1)
    int* rank_r = off + 2 * (NN + 1);       // EE
    int* rank_s = rank_r + EE;              // EE
    int* jr     = rank_s + EE;              // EE
    int* psl_j  = jr + EE;                  // EE
    const int* off_rcv = off;
    const int* off_snd = off + (NN + 1);

    const int edgeBlocks = (EE + 255) / 256;
    const int nodeBlocks = (NN + 255) / 256;

    hipMemsetAsync(d_out, 0, (size_t)out_size * sizeof(float), stream);
    hipMemsetAsync(cnt, 0, (size_t)2 * NN * sizeof(int), stream);

    // CSR build: atomics only in count (rank capture); fill is atomic-free
    count_kernel<<<edgeBlocks, 256, 0, stream>>>(ei, cnt, rank_r, rank_s);
    scan_kernel<<<2, 256, 0, stream>>>(cnt, off);
    fill_kernel<<<edgeBlocks, 256, 0, stream>>>(ei, off, rank_r, rank_s, jr, psl_j);

    // small precomputes
    a1_kernel<<<1, 128, 0, stream>>>(Wout1, w_read + FF, W_skip + 10 * FF, ae, a1, askip);
    cd_kernel<<<1, 128, 0, stream>>>(Wout0, w_read, a1, Wr1, c0, D);
    gw_kernel<<<40, 256, 0, stream>>>(W_emb, Wr0, Wout0, GW);
    tmc_kernel<<<1, 256, 0, stream>>>(D, c0, W_emb, Wr0, T, Mc);

    // compact geometry records (32B sector scatter via jr)
    edge_geom<<<edgeBlocks, 256, 0, stream>>>(pos, shifts, ei, w_sh, jr, rec);

    // E1 via snd-CSR gather of records (8 lanes/node, no atomics)
    e1_csr<<<(NN * 8 + 255) / 256, 256, 0, stream>>>(rec, off_snd, psl_j, E1);

    // P0, then h1, t1, M
    p0_kernel<<<P0_BLOCKS, 256, 0, stream>>>(rec, off_rcv, attrs, P0);
    h1_gemm<<<GEMM_BLOCKS, 256, 0, stream>>>(P0, GW, attrs, W_skip, w_read, h1, node_e);
    t1_kernel<<<(NN + 3) / 4, 256, 0, stream>>>(h1, a1, Wr1, t1);
    m_kernel<<<nodeBlocks, 256, 0, stream>>>(E1, T, Mc, M);

    // fused per-edge: recompute radial, dsp/drp both layers, layer-1 energy, gv
    edge_pass<<<EP_BLOCKS, 256, 0, stream>>>(rec, t1, M, attrs, batch, w_sh, gvp, energy);

    // forces via CSR gather (no atomics)
    force_gather<<<nodeBlocks, 256, 0, stream>>>(off_rcv, off_snd, psl_j, gvp, forces);

    // energy finalize (layer-0 node energies + layer-1 skip + e0)
    efinal_kernel<<<EF_BLOCKS, 256, 0, stream>>>(node_e, attrs, askip, batch, energy);
}

// Round 13
// 412.810 us; speedup vs baseline: 2.5542x; 1.2753x over previous
//
#include <hip/hip_runtime.h>

#define NN 50000
#define EE 800000
#define GG 64
#define FF 128
#define NBES 8
#define RECW 8    // compact record: x, y, z, inv_r, s0, s1, snd, rcv  (32 B)
#define RMAXF 5.0f
#define PI_F 3.14159265358979323846f
#define NB ((NN + 255) / 256)   // 196 chunks per half

// spherical harmonic constants
#define S3  1.7320508075688772f
#define S5  2.23606797749979f
#define S15 3.872983346207417f
#define C1c 2.091650066335189f   // sqrt(35/8)
#define C2c 10.246950765959598f  // sqrt(105)
#define C3c 1.62018517460196f    // sqrt(21/8)
#define C4c 1.3228756555322954f  // sqrt(7)/2
#define C5c 5.123475382979799f   // sqrt(105)/2
#define CCB 0.6324555320336759f  // sqrt(2/5)

__device__ __forceinline__ float shc_s(float x, float y, float z, const float* __restrict__ w) {
    float x2 = x * x, y2 = y * y, z2 = z * z;
    return w[0]
        + w[1] * (S3 * x) + w[2] * (S3 * y) + w[3] * (S3 * z)
        + w[4] * (S15 * x * y) + w[5] * (S15 * y * z) + w[6] * (0.5f * S5 * (3.f * z2 - 1.f))
        + w[7] * (S15 * x * z) + w[8] * (0.5f * S15 * (x2 - y2))
        + w[9] * (C1c * y * (3.f * x2 - y2)) + w[10] * (C2c * x * y * z)
        + w[11] * (C3c * y * (5.f * z2 - 1.f)) + w[12] * (C4c * z * (5.f * z2 - 3.f))
        + w[13] * (C3c * x * (5.f * z2 - 1.f)) + w[14] * (C5c * z * (x2 - y2))
        + w[15] * (C1c * x * (x2 - 3.f * y2));
}

__device__ __forceinline__ void shc_grad(float x, float y, float z, const float* __restrict__ w,
                                         float& gx, float& gy, float& gz) {
    float x2 = x * x, y2 = y * y, z2 = z * z;
    gx = w[1] * S3 + w[4] * (S15 * y) + w[7] * (S15 * z) + w[8] * (S15 * x)
       + w[9] * (6.f * C1c * x * y) + w[10] * (C2c * y * z) + w[13] * (C3c * (5.f * z2 - 1.f))
       + w[14] * (2.f * C5c * x * z) + w[15] * (3.f * C1c * (x2 - y2));
    gy = w[2] * S3 + w[4] * (S15 * x) + w[5] * (S15 * z) - w[8] * (S15 * y)
       + w[9] * (3.f * C1c * (x2 - y2)) + w[10] * (C2c * x * z) + w[11] * (C3c * (5.f * z2 - 1.f))
       - w[14] * (2.f * C5c * y * z) - w[15] * (6.f * C1c * x * y);
    gz = w[3] * S3 + w[5] * (S15 * y) + w[6] * (3.f * S5 * z) + w[7] * (S15 * x)
       + w[10] * (C2c * x * y) + w[11] * (10.f * C3c * y * z) + w[12] * (C4c * (15.f * z2 - 3.f))
       + w[13] * (10.f * C3c * x * z) + w[14] * (C5c * (x2 - y2));
}

// -------------------- CSR build --------------------

// ranks via atomic return value (the only atomics in the build)
__global__ __launch_bounds__(256) void count_kernel(const int* __restrict__ ei,
                                                    int* __restrict__ cnt,
                                                    int* __restrict__ rank_r,
                                                    int* __restrict__ rank_s) {
    int e = blockIdx.x * 256 + threadIdx.x;
    if (e >= EE) return;
    rank_r[e] = atomicAdd(&cnt[ei[EE + e]], 1);
    rank_s[e] = atomicAdd(&cnt[NN + ei[e]], 1);
}

// phase A: per-256-chunk block sums (grid = 2*NB)
__global__ __launch_bounds__(256) void scan_partial(const int* __restrict__ cnt,
                                                    int* __restrict__ parts) {
    __shared__ int wsum[4];
    int b = blockIdx.x;
    int half = b / NB;
    int cb = b - half * NB;
    int i = cb * 256 + threadIdx.x;
    int v = (i < NN) ? cnt[(size_t)half * NN + i] : 0;
    int x = v;
#pragma unroll
    for (int o = 32; o > 0; o >>= 1) x += __shfl_xor(x, o);
    int lane = threadIdx.x & 63, wid = threadIdx.x >> 6;
    if (lane == 0) wsum[wid] = x;
    __syncthreads();
    if (threadIdx.x == 0) parts[b] = wsum[0] + wsum[1] + wsum[2] + wsum[3];
}

// phase B: exclusive scan of the NB block sums per half (in place); writes totals
__global__ __launch_bounds__(256) void scan_parts(int* __restrict__ parts,
                                                  int* __restrict__ off) {
    __shared__ int wsum[4];
    __shared__ int carry_s;
    int lane = threadIdx.x & 63, wid = threadIdx.x >> 6;
    for (int h = 0; h < 2; h++) {
        if (threadIdx.x == 0) carry_s = 0;
        __syncthreads();
        for (int base = 0; base < NB; base += 256) {
            int i = base + threadIdx.x;
            int v = (i < NB) ? parts[h * NB + i] : 0;
            int x = v;
#pragma unroll
            for (int d = 1; d < 64; d <<= 1) {
                int y = __shfl_up(x, d);
                if (lane >= d) x += y;
            }
            if (lane == 63) wsum[wid] = x;
            __syncthreads();
            int pre = 0;
#pragma unroll
            for (int w = 0; w < 4; w++) if (w < wid) pre += wsum[w];
            int total = wsum[0] + wsum[1] + wsum[2] + wsum[3];
            int carry = carry_s;
            if (i < NB) parts[h * NB + i] = carry + pre + x - v;   // exclusive
            __syncthreads();
            if (threadIdx.x == 0) carry_s = carry + total;
            __syncthreads();
        }
        if (threadIdx.x == 0) off[(size_t)h * (NN + 1) + NN] = carry_s;
        __syncthreads();
    }
}

// phase C: within-chunk exclusive scan + block prefix (grid = 2*NB)
__global__ __launch_bounds__(256) void scan_apply(const int* __restrict__ cnt,
                                                  const int* __restrict__ parts,
                                                  int* __restrict__ off) {
    __shared__ int wsum[4];
    int b = blockIdx.x;
    int half = b / NB;
    int cb = b - half * NB;
    int i = cb * 256 + threadIdx.x;
    int v = (i < NN) ? cnt[(size_t)half * NN + i] : 0;
    int lane = threadIdx.x & 63, wid = threadIdx.x >> 6;
    int x = v;
#pragma unroll
    for (int d = 1; d < 64; d <<= 1) {
        int y = __shfl_up(x, d);
        if (lane >= d) x += y;
    }
    if (lane == 63) wsum[wid] = x;
    __syncthreads();
    int pre = 0;
#pragma unroll
    for (int w = 0; w < 4; w++) if (w < wid) pre += wsum[w];
    if (i < NN) off[(size_t)half * (NN + 1) + i] = parts[b] + pre + x - v;
}

// jr[e] = rcv-slot of e (coalesced); psl_j[snd-slot] = rcv-slot (single 4B scatter)
__global__ __launch_bounds__(256) void fill_kernel(const int* __restrict__ ei,
                                                   const int* __restrict__ off,
                                                   const int* __restrict__ rank_r,
                                                   const int* __restrict__ rank_s,
                                                   int* __restrict__ jr,
                                                   int* __restrict__ psl_j) {
    int e = blockIdx.x * 256 + threadIdx.x;
    if (e >= EE) return;
    int snd = ei[e], rcv = ei[EE + e];
    int sr = off[rcv] + rank_r[e];
    int ss = off[(NN + 1) + snd] + rank_s[e];
    jr[e] = sr;
    psl_j[ss] = sr;
}

// -------------------- geometry: thread = edge (coalesced in), 32B sector scatter out --

__global__ __launch_bounds__(256) void edge_geom(const float* __restrict__ pos,
                                                 const float* __restrict__ shifts,
                                                 const int* __restrict__ ei,
                                                 const float* __restrict__ wsh,
                                                 const int* __restrict__ jr,
                                                 float* __restrict__ rec) {
    int e = blockIdx.x * 256 + threadIdx.x;
    if (e >= EE) return;
    int snd = ei[e];
    int rcv = ei[EE + e];
    float vx = pos[rcv * 3 + 0] - pos[snd * 3 + 0] + shifts[e * 3 + 0];
    float vy = pos[rcv * 3 + 1] - pos[snd * 3 + 1] + shifts[e * 3 + 1];
    float vz = pos[rcv * 3 + 2] - pos[snd * 3 + 2] + shifts[e * 3 + 2];
    float r2 = vx * vx + vy * vy + vz * vz + 1e-12f;
    float r = sqrtf(r2);
    float inv_r = 1.0f / r;
    float x = vx * inv_r, y = vy * inv_r, z = vz * inv_r;

    float s0 = shc_s(x, y, z, wsh);
    float s1v = shc_s(x, y, z, wsh + 16);

    float* rc = rec + (size_t)jr[e] * RECW;
    *(float4*)&rc[0] = make_float4(x, y, z, inv_r);
    *(float4*)&rc[4] = make_float4(s0, s1v, __int_as_float(snd), __int_as_float(rcv));
}

// -------------------- E1 over snd-CSR: 8 lanes per node, gather compact records -------
// E1[n,k] = sum_{e: snd=n} eb[k] * s1 ;  eb[k] = CCB*inv_r*env * sin((k+1)*th)

__global__ __launch_bounds__(256) void e1_csr(const float* __restrict__ rec,
                                              const int* __restrict__ off_snd,
                                              const int* __restrict__ psl_j,
                                              float* __restrict__ E1) {
    int gid = blockIdx.x * 256 + threadIdx.x;
    int n = gid >> 3;
    int k_l = gid & 7;
    if (n >= NN) return;
    float kf = (float)(k_l + 1);
    int beg = off_snd[n], end = off_snd[n + 1];
    float acc = 0.f;
    for (int s = beg; s < end; s++) {
        int j = psl_j[s];
        const float* rc = rec + (size_t)j * RECW;
        float inv_r = rc[3];
        float s1v = rc[5];
        float r = 1.0f / inv_r;
        float u = r * (1.0f / RMAXF);
        float th = PI_F * u;
        float u2 = u * u, u3 = u2 * u, u6 = u3 * u3, u7 = u6 * u, u8 = u6 * u2;
        float valid = (r < RMAXF) ? 1.f : 0.f;
        float env = (1.f - 28.f * u6 + 48.f * u7 - 21.f * u8) * valid;
        float my = sinf(kf * th);
        acc += my * (CCB * inv_r * env * s1v);
    }
    E1[(size_t)n * 8 + k_l] = acc;
}

// -------------------- small precomputes --------------------

__global__ __launch_bounds__(128) void a1_kernel(const float* __restrict__ Wout1,
                                                 const float* __restrict__ wread1,
                                                 const float* __restrict__ Wskip1,
                                                 const float* __restrict__ ae,
                                                 float* __restrict__ a1,
                                                 float* __restrict__ askip) {
    int f = threadIdx.x;
    float s = 0.f;
    for (int k = 0; k < FF; k++) s += Wout1[f * FF + k] * wread1[k];
    a1[f] = s;
    if (f < 10) {
        float t = 0.f;
        for (int k = 0; k < FF; k++) t += Wskip1[f * FF + k] * wread1[k];
        askip[f] = t + ae[f];
    }
}

// c0[f'] = sum_f wread0[f] Wout0[f',f];  D[k,f'] = sum_f a1[f] Wr1[k,f] Wout0[f',f]
__global__ __launch_bounds__(128) void cd_kernel(const float* __restrict__ Wout0,
                                                 const float* __restrict__ wread0,
                                                 const float* __restrict__ a1,
                                                 const float* __restrict__ Wr1,
                                                 float* __restrict__ c0,
                                                 float* __restrict__ D) {
    int fp = threadIdx.x;
    float c = 0.f;
    float d[NBES];
#pragma unroll
    for (int k = 0; k < NBES; k++) d[k] = 0.f;
    for (int f = 0; f < FF; f++) {
        float w = Wout0[fp * FF + f];
        c += wread0[f] * w;
        float aw = a1[f] * w;
#pragma unroll
        for (int k = 0; k < NBES; k++) d[k] += aw * Wr1[k * FF + f];
    }
    c0[fp] = c;
#pragma unroll
    for (int k = 0; k < NBES; k++) D[k * FF + fp] = d[k];
}

// GW[p=a*8+k][f'] = sum_f W_emb[a,f] Wr0[k,f] Wout0[f,f']
__global__ __launch_bounds__(256) void gw_kernel(const float* __restrict__ W_emb,
                                                 const float* __restrict__ Wr0,
                                                 const float* __restrict__ Wout0,
                                                 float* __restrict__ GW) {
    int idx = blockIdx.x * 256 + threadIdx.x;
    if (idx >= 80 * FF) return;
    int fp = idx & 127;
    int p = idx >> 7;
    int a = p >> 3, k = p & 7;
    float s = 0.f;
    for (int f = 0; f < FF; f++)
        s += W_emb[a * FF + f] * Wr0[k * FF + f] * Wout0[f * FF + fp];
    GW[p * FF + fp] = s;
}

// T[k'][p0=k*10+a] = sum_f D[k',f] W_emb[a,f] Wr0[k,f];  Mc[p0] = sum_f c0[f] W_emb Wr0
__global__ __launch_bounds__(256) void tmc_kernel(const float* __restrict__ D,
                                                  const float* __restrict__ c0,
                                                  const float* __restrict__ W_emb,
                                                  const float* __restrict__ Wr0,
                                                  float* __restrict__ T,
                                                  float* __restrict__ Mc) {
    for (int i = threadIdx.x; i < 720; i += 256) {
        if (i < 640) {
            int kp = i / 80;
            int p0 = i - kp * 80;
            int k = p0 / 10, a = p0 - k * 10;
            float s = 0.f;
            for (int f = 0; f < FF; f++)
                s += D[kp * FF + f] * W_emb[a * FF + f] * Wr0[k * FF + f];
            T[i] = s;
        } else {
            int p0 = i - 640;
            int k = p0 / 10, a = p0 - k * 10;
            float s = 0.f;
            for (int f = 0; f < FF; f++)
                s += c0[f] * W_emb[a * FF + f] * Wr0[k * FF + f];
            Mc[p0] = s;
        }
    }
}

// -------------------- P0[n, p=a*8+k] = sum_{e:rcv=n} attrs[snd,a] eb[e,k] s0_e --------

#define P0_BLOCKS 2048
__global__ __launch_bounds__(256) void p0_kernel(const float* __restrict__ rec,
                                                 const int* __restrict__ off,
                                                 const float* __restrict__ attrs,
                                                 float* __restrict__ P0) {
    int wv = (blockIdx.x * 256 + threadIdx.x) >> 6;
    int lane = threadIdx.x & 63;
    int nwaves = P0_BLOCKS * 4;
    int a_lo = lane >> 3;
    int k_l = lane & 7;
    float kf = (float)(k_l + 1);

    for (int n = wv; n < NN; n += nwaves) {
        int beg = off[n], end = off[n + 1];
        float acc = 0.f, acc2 = 0.f;
        for (int j = beg; j < end; j++) {
            const float* rc = rec + (size_t)j * RECW;
            float inv_r = rc[3];
            float s0 = rc[4];
            int snd = __float_as_int(rc[6]);
            float r = 1.0f / inv_r;
            float u = r * (1.0f / RMAXF);
            float th = PI_F * u;
            float u2 = u * u, u3 = u2 * u, u6 = u3 * u3, u7 = u6 * u, u8 = u6 * u2;
            float valid = (r < RMAXF) ? 1.f : 0.f;
            float env = (1.f - 28.f * u6 + 48.f * u7 - 21.f * u8) * valid;
            float my = sinf(kf * th);
            float es = my * (CCB * inv_r * env) * s0;
            acc += attrs[snd * 10 + a_lo] * es;
            if (lane < 16) acc2 += attrs[snd * 10 + 8 + a_lo] * es;
        }
        P0[(size_t)n * 80 + lane] = acc;
        if (lane < 16) P0[(size_t)n * 80 + 64 + lane] = acc2;
    }
}

// -------------------- h1 GEMM: h1 = P0 @ GW + attrs @ Wskip0 ; node_e = h1.wread0 ------

#define GEMM_BLOCKS 512
__global__ __launch_bounds__(256, 2) void h1_gemm(const float* __restrict__ P0,
                                                  const float* __restrict__ GW,
                                                  const float* __restrict__ attrs,
                                                  const float* __restrict__ Wskip,
                                                  const float* __restrict__ wread,
                                                  float* __restrict__ h1,
                                                  float* __restrict__ node_e) {
    __shared__ float sb[80][FF];   // 40 KB
    __shared__ float sa[32][80];   // 10 KB
    int t = threadIdx.x;
#pragma unroll
    for (int j = 0; j < 10; j++) {
        int flat4 = j * 256 + t;
        int row = flat4 >> 5;
        int col = (flat4 & 31) * 4;
        *(float4*)&sb[row][col] = *(const float4*)&GW[row * FF + col];
    }

    int g = t >> 5;
    int f0 = (t & 31) * 4;
    const int NTILES = (NN + 31) / 32;

    for (int tile = blockIdx.x; tile < NTILES; tile += GEMM_BLOCKS) {
        __syncthreads();
#pragma unroll
        for (int j = 0; j < 3; j++) {
            int flat4 = j * 256 + t;
            if (flat4 < 640) {
                int row = flat4 / 20;
                int col = (flat4 - row * 20) * 4;
                int n = tile * 32 + row;
                float4 v = make_float4(0.f, 0.f, 0.f, 0.f);
                if (n < NN) v = *(const float4*)&P0[(size_t)n * 80 + col];
                *(float4*)&sa[row][col] = v;
            }
        }
        __syncthreads();

        float acc[4][4];
#pragma unroll
        for (int i = 0; i < 4; i++)
#pragma unroll
            for (int j = 0; j < 4; j++) acc[i][j] = 0.f;

        for (int kk = 0; kk < 80; kk += 4) {
            float4 bv0 = *(const float4*)&sb[kk + 0][f0];
            float4 bv1 = *(const float4*)&sb[kk + 1][f0];
            float4 bv2 = *(const float4*)&sb[kk + 2][f0];
            float4 bv3 = *(const float4*)&sb[kk + 3][f0];
#pragma unroll
            for (int ni = 0; ni < 4; ni++) {
                float4 av = *(const float4*)&sa[g * 4 + ni][kk];
                acc[ni][0] += av.x * bv0.x + av.y * bv1.x + av.z * bv2.x + av.w * bv3.x;
                acc[ni][1] += av.x * bv0.y + av.y * bv1.y + av.z * bv2.y + av.w * bv3.y;
                acc[ni][2] += av.x * bv0.z + av.y * bv1.z + av.z * bv2.z + av.w * bv3.z;
                acc[ni][3] += av.x * bv0.w + av.y * bv1.w + av.z * bv2.w + av.w * bv3.w;
            }
        }

#pragma unroll
        for (int ni = 0; ni < 4; ni++) {
            int n = tile * 32 + g * 4 + ni;
            bool valid = (n < NN);
#pragma unroll
            for (int a = 0; a < 10; a++) {
                float att = valid ? attrs[n * 10 + a] : 0.f;
                float4 wk = *(const float4*)&Wskip[a * FF + f0];
                acc[ni][0] += att * wk.x;
                acc[ni][1] += att * wk.y;
                acc[ni][2] += att * wk.z;
                acc[ni][3] += att * wk.w;
            }
            if (valid) {
                float4 out;
                out.x = acc[ni][0]; out.y = acc[ni][1];
                out.z = acc[ni][2]; out.w = acc[ni][3];
                *(float4*)&h1[(size_t)n * FF + f0] = out;
            }
            float4 wv = *(const float4*)&wread[f0];
            float p = acc[ni][0] * wv.x + acc[ni][1] * wv.y
                    + acc[ni][2] * wv.z + acc[ni][3] * wv.w;
#pragma unroll
            for (int o = 16; o > 0; o >>= 1) p += __shfl_xor(p, o);
            if (valid && (t & 31) == 0) node_e[n] = p;
        }
    }
}

// -------------------- t1[n,k] = sum_f a1[f] h1[n,f] Wr1[k,f] --------------------

__global__ __launch_bounds__(256) void t1_kernel(const float* __restrict__ h1,
                                                 const float* __restrict__ a1,
                                                 const float* __restrict__ Wr1,
                                                 float* __restrict__ t1) {
    int w = threadIdx.x >> 6;
    int lane = threadIdx.x & 63;
    int n = blockIdx.x * 4 + w;
    if (n >= NN) return;
    int f0 = lane, f1 = lane + 64;
    float v0 = a1[f0] * h1[(size_t)n * FF + f0];
    float v1 = a1[f1] * h1[(size_t)n * FF + f1];
    float p[NBES];
#pragma unroll
    for (int k = 0; k < NBES; k++)
        p[k] = v0 * Wr1[k * FF + f0] + v1 * Wr1[k * FF + f1];
#pragma unroll
    for (int o = 32; o > 0; o >>= 1) {
#pragma unroll
        for (int k = 0; k < NBES; k++) p[k] += __shfl_xor(p[k], o);
    }
    if (lane == 0) {
        *(float4*)&t1[(size_t)n * 8]     = make_float4(p[0], p[1], p[2], p[3]);
        *(float4*)&t1[(size_t)n * 8 + 4] = make_float4(p[4], p[5], p[6], p[7]);
    }
}

// -------------------- M[n][p0=k*10+a] = Mc + sum_k' E1[n,k'] T[k'][p0] ----------------

__global__ __launch_bounds__(256) void m_kernel(const float* __restrict__ E1,
                                                const float* __restrict__ T,
                                                const float* __restrict__ Mc,
                                                float* __restrict__ M) {
    __shared__ float sT[720];
    int t = threadIdx.x;
    for (int i = t; i < 720; i += 256) sT[i] = (i < 640) ? T[i] : Mc[i - 640];
    __syncthreads();
    int n = blockIdx.x * 256 + t;
    if (n >= NN) return;
    float4 ea = *(const float4*)&E1[(size_t)n * 8];
    float4 eb = *(const float4*)&E1[(size_t)n * 8 + 4];
    float e1v[8] = {ea.x, ea.y, ea.z, ea.w, eb.x, eb.y, eb.z, eb.w};
#pragma unroll
    for (int c = 0; c < 20; c++) {
        float4 m = *(const float4*)&sT[640 + c * 4];
#pragma unroll
        for (int kp = 0; kp < 8; kp++) {
            float4 tv = *(const float4*)&sT[kp * 80 + c * 4];
            m.x += e1v[kp] * tv.x;
            m.y += e1v[kp] * tv.y;
            m.z += e1v[kp] * tv.z;
            m.w += e1v[kp] * tv.w;
        }
        *(float4*)&M[(size_t)n * 80 + c * 4] = m;
    }
}

// -------------------- fused per-edge pass: recompute radial, dsp/drp, energy1, gv -----

#define EP_BLOCKS 512
__global__ __launch_bounds__(256) void edge_pass(const float* __restrict__ rec,
                                                 const float* __restrict__ t1,
                                                 const float* __restrict__ M,
                                                 const float* __restrict__ attrs,
                                                 const int* __restrict__ batch,
                                                 const float* __restrict__ wsh,
                                                 float4* __restrict__ gvp,
                                                 float* __restrict__ energy) {
    __shared__ float eacc[GG];
    int t = threadIdx.x;
    int lane = t & 63;
    if (t < GG) eacc[t] = 0.f;
    __syncthreads();

    for (int j0 = blockIdx.x * 256; j0 < EE; j0 += EP_BLOCKS * 256) {
        int j = j0 + t;
        bool act = (j < EE);
        int jc = act ? j : 0;
        const float* rc = rec + (size_t)jc * RECW;
        float4 q0 = *(const float4*)&rc[0];
        float4 q1 = *(const float4*)&rc[4];
        float x = q0.x, y = q0.y, z = q0.z, ivr = q0.w;
        float s0 = q1.x, s1v = q1.y;
        int snd = __float_as_int(q1.z);
        int rcv = __float_as_int(q1.w);

        // recompute radial eb/db
        float r = 1.0f / ivr;
        float u = r * (1.0f / RMAXF);
        float th = PI_F * u;
        float s1 = sinf(th), c1 = cosf(th);
        float u2 = u * u, u3 = u2 * u, u5 = u2 * u3, u6 = u3 * u3, u7 = u6 * u, u8 = u6 * u2;
        float valid = (r < RMAXF) ? 1.f : 0.f;
        float env = (1.f - 28.f * u6 + 48.f * u7 - 21.f * u8) * valid;
        float denv = (-168.f * u5 + 336.f * u6 - 168.f * u7) * (1.0f / RMAXF) * valid;
        float eb[NBES], db[NBES];
        {
            float sk = s1, skm = 0.f, ck = c1, ckm = 1.f;
            float tc = 2.f * c1;
#pragma unroll
            for (int k = 1; k <= NBES; k++) {
                float b = CCB * sk * ivr;
                eb[k - 1] = b * env;
                db[k - 1] = CCB * (((float)k * PI_F * (1.0f / RMAXF)) * ck * ivr
                                   - sk * ivr * ivr) * env
                            + b * denv;
                float sn = tc * sk - skm; skm = sk; sk = sn;
                float cn = tc * ck - ckm; ckm = ck; ck = cn;
            }
        }

        // layer 1: dsp1/drp1 via t1[snd]
        float4 ta = *(const float4*)&t1[(size_t)snd * 8];
        float4 tb = *(const float4*)&t1[(size_t)snd * 8 + 4];
        float tg[8] = {ta.x, ta.y, ta.z, ta.w, tb.x, tb.y, tb.z, tb.w};
        float dsp1 = 0.f, drp1 = 0.f;
#pragma unroll
        for (int k = 0; k < 8; k++) {
            dsp1 += eb[k] * tg[k];
            drp1 += db[k] * tg[k];
        }

        // layer 0: t0[k] = sum_a attrs[snd,a] M[rcv,k,a]
        float at[10];
#pragma unroll
        for (int i = 0; i < 5; i++) {
            float2 v = *(const float2*)&attrs[snd * 10 + 2 * i];
            at[2 * i] = v.x; at[2 * i + 1] = v.y;
        }
        const float* Mr = M + (size_t)rcv * 80;
        float dsp0 = 0.f, drp0 = 0.f;
#pragma unroll
        for (int k = 0; k < 8; k++) {
            float t0 = 0.f;
#pragma unroll
            for (int a = 0; a < 10; a++) t0 += at[a] * Mr[k * 10 + a];
            dsp0 += eb[k] * t0;
            drp0 += db[k] * t0;
        }

        // layer-1 energy contribution: s1 * dsp1, grouped by batch[rcv]
        float el = act ? s1v * dsp1 : 0.f;
        int b = act ? batch[rcv] : -1;
        int ub = __builtin_amdgcn_readfirstlane(b);
        if (__all(b == ub)) {
            float es = el;
#pragma unroll
            for (int o = 32; o > 0; o >>= 1) es += __shfl_xor(es, o);
            if (lane == 0 && ub >= 0) atomicAdd(&eacc[ub], es);
        } else {
            if (act) atomicAdd(&eacc[b], el);
        }

        // per-edge force vector (coalesced write)
        float g0x, g0y, g0z, g1x, g1y, g1z;
        shc_grad(x, y, z, wsh, g0x, g0y, g0z);
        shc_grad(x, y, z, wsh + 16, g1x, g1y, g1z);
        float gux = dsp0 * g0x + dsp1 * g1x;
        float guy = dsp0 * g0y + dsp1 * g1y;
        float guz = dsp0 * g0z + dsp1 * g1z;
        float gr = s0 * drp0 + s1v * drp1;
        float dgu = gux * x + guy * y + guz * z;
        float gvx = gr * x + ivr * (gux - dgu * x);
        float gvy = gr * y + ivr * (guy - dgu * y);
        float gvz = gr * z + ivr * (guz - dgu * z);
        if (act) gvp[j] = make_float4(gvx, gvy, gvz, 0.f);
    }
    __syncthreads();
    if (t < GG && eacc[t] != 0.f) atomicAdd(&energy[t], eacc[t]);
}

// -------------------- force gather (thread-per-node, no atomics) ----------------------

__global__ __launch_bounds__(256) void force_gather(const int* __restrict__ off_rcv,
                                                    const int* __restrict__ off_snd,
                                                    const int* __restrict__ psl_j,
                                                    const float4* __restrict__ gvp,
                                                    float* __restrict__ forces) {
    int n = blockIdx.x * 256 + threadIdx.x;
    if (n >= NN) return;
    float fx = 0.f, fy = 0.f, fz = 0.f;
    int beg = off_rcv[n], end = off_rcv[n + 1];
    for (int j = beg; j < end; j++) {
        float4 g = gvp[j];
        fx -= g.x; fy -= g.y; fz -= g.z;
    }
    beg = off_snd[n]; end = off_snd[n + 1];
    for (int s = beg; s < end; s++) {
        float4 g = gvp[psl_j[s]];
        fx += g.x; fy += g.y; fz += g.z;
    }
    forces[n * 3 + 0] = fx;
    forces[n * 3 + 1] = fy;
    forces[n * 3 + 2] = fz;
}

// -------------------- energy finalize: node_e + attrs.askip --------------------

#define EF_BLOCKS 128
__global__ __launch_bounds__(256) void efinal_kernel(const float* __restrict__ node_e,
                                                     const float* __restrict__ attrs,
                                                     const float* __restrict__ askip,
                                                     const int* __restrict__ batch,
                                                     float* __restrict__ energy) {
    __shared__ float eacc[GG];
    int t = threadIdx.x;
    if (t < GG) eacc[t] = 0.f;
    __syncthreads();
    for (int n = blockIdx.x * 256 + t; n < NN; n += EF_BLOCKS * 256) {
        float v = node_e[n];
#pragma unroll
        for (int a = 0; a < 10; a++) v += attrs[n * 10 + a] * askip[a];
        atomicAdd(&eacc[batch[n]], v);
    }
    __syncthreads();
    if (t < GG && eacc[t] != 0.f) atomicAdd(&energy[t], eacc[t]);
}

// -------------------- launch --------------------

extern "C" void kernel_launch(void* const* d_in, const int* in_sizes, int n_in,
                              void* d_out, int out_size, void* d_ws, size_t ws_size,
                              hipStream_t stream) {
    const float* pos    = (const float*)d_in[0];
    const float* attrs  = (const float*)d_in[1];
    const float* shifts = (const float*)d_in[2];
    const int*   ei     = (const int*)d_in[3];
    const int*   batch  = (const int*)d_in[4];
    const float* W_emb  = (const float*)d_in[6];
    const float* ae     = (const float*)d_in[7];
    const float* W_r    = (const float*)d_in[8];   // (2,8,F)
    const float* w_sh   = (const float*)d_in[9];   // (2,16)
    const float* W_out  = (const float*)d_in[10];  // (2,F,F)
    const float* W_skip = (const float*)d_in[11];  // (2,10,F)
    const float* w_read = (const float*)d_in[12];  // (2,F)

    const float* Wr0 = W_r;
    const float* Wr1 = W_r + NBES * FF;
    const float* Wout0 = W_out;
    const float* Wout1 = W_out + FF * FF;

    float* energy = (float*)d_out;
    float* forces = energy + GG;

    float* ws  = (float*)d_ws;
    float* h1  = ws;                        // N*F
    float* P0  = h1 + (size_t)NN * FF;      // N*80
    float* M   = P0 + (size_t)NN * 80;      // N*80
    float* E1  = M + (size_t)NN * 80;       // N*8
    float* t1  = E1 + (size_t)NN * 8;       // N*8
    float* node_e = t1 + (size_t)NN * 8;    // N
    float* rec = node_e + NN;               // EE*8
    float4* gvp = (float4*)(rec + (size_t)EE * RECW);  // EE*4 floats
    float* a1  = (float*)(gvp + EE);        // 128
    float* askip = a1 + FF;                 // 16
    float* c0  = askip + 16;                // 128
    float* D   = c0 + FF;                   // 8*128
    float* GW  = D + NBES * FF;             // 80*128
    float* T   = GW + 80 * FF;              // 640
    float* Mc  = T + 640;                   // 80

    int* cnt    = (int*)(Mc + 80);          // 2N
    int* off    = cnt + 2 * NN;             // 2(N+1)
    int* rank_r = off + 2 * (NN + 1);       // EE
    int* rank_s = rank_r + EE;              // EE
    int* jr     = rank_s + EE;              // EE
    int* psl_j  = jr + EE;                  // EE
    int* parts  = psl_j + EE;               // 2*NB
    const int* off_rcv = off;
    const int* off_snd = off + (NN + 1);

    const int edgeBlocks = (EE + 255) / 256;
    const int nodeBlocks = (NN + 255) / 256;

    hipMemsetAsync(d_out, 0, (size_t)out_size * sizeof(float), stream);
    hipMemsetAsync(cnt, 0, (size_t)2 * NN * sizeof(int), stream);

    // CSR build: atomics only in count (rank capture); parallel 3-phase scan
    count_kernel<<<edgeBlocks, 256, 0, stream>>>(ei, cnt, rank_r, rank_s);
    scan_partial<<<2 * NB, 256, 0, stream>>>(cnt, parts);
    scan_parts<<<1, 256, 0, stream>>>(parts, off);
    scan_apply<<<2 * NB, 256, 0, stream>>>(cnt, parts, off);
    fill_kernel<<<edgeBlocks, 256, 0, stream>>>(ei, off, rank_r, rank_s, jr, psl_j);

    // small precomputes
    a1_kernel<<<1, 128, 0, stream>>>(Wout1, w_read + FF, W_skip + 10 * FF, ae, a1, askip);
    cd_kernel<<<1, 128, 0, stream>>>(Wout0, w_read, a1, Wr1, c0, D);
    gw_kernel<<<40, 256, 0, stream>>>(W_emb, Wr0, Wout0, GW);
    tmc_kernel<<<1, 256, 0, stream>>>(D, c0, W_emb, Wr0, T, Mc);

    // compact geometry records (32B sector scatter via jr)
    edge_geom<<<edgeBlocks, 256, 0, stream>>>(pos, shifts, ei, w_sh, jr, rec);

    // E1 via snd-CSR gather of records (8 lanes/node, no atomics)
    e1_csr<<<(NN * 8 + 255) / 256, 256, 0, stream>>>(rec, off_snd, psl_j, E1);

    // P0, then h1, t1, M
    p0_kernel<<<P0_BLOCKS, 256, 0, stream>>>(rec, off_rcv, attrs, P0);
    h1_gemm<<<GEMM_BLOCKS, 256, 0, stream>>>(P0, GW, attrs, W_skip, w_read, h1, node_e);
    t1_kernel<<<(NN + 3) / 4, 256, 0, stream>>>(h1, a1, Wr1, t1);
    m_kernel<<<nodeBlocks, 256, 0, stream>>>(E1, T, Mc, M);

    // fused per-edge: recompute radial, dsp/drp both layers, layer-1 energy, gv
    edge_pass<<<EP_BLOCKS, 256, 0, stream>>>(rec, t1, M, attrs, batch, w_sh, gvp, energy);

    // forces via CSR gather (no atomics)
    force_gather<<<nodeBlocks, 256, 0, stream>>>(off_rcv, off_snd, psl_j, gvp, forces);

    // energy finalize (layer-0 node energies + layer-1 skip + e0)
    efinal_kernel<<<EF_BLOCKS, 256, 0, stream>>>(node_e, attrs, askip, batch, energy);
}

// Round 14
// 402.359 us; speedup vs baseline: 2.6206x; 1.0260x over previous
//
#include <hip/hip_runtime.h>

#define NN 50000
#define EE 800000
#define GG 64
#define FF 128
#define NBES 8
#define RECW 8    // compact record: x, y, z, inv_r, s0, s1, snd, rcv  (32 B)
#define RMAXF 5.0f
#define PI_F 3.14159265358979323846f
#define NB ((NN + 255) / 256)   // 196 chunks per half

// spherical harmonic constants
#define S3  1.7320508075688772f
#define S5  2.23606797749979f
#define S15 3.872983346207417f
#define C1c 2.091650066335189f   // sqrt(35/8)
#define C2c 10.246950765959598f  // sqrt(105)
#define C3c 1.62018517460196f    // sqrt(21/8)
#define C4c 1.3228756555322954f  // sqrt(7)/2
#define C5c 5.123475382979799f   // sqrt(105)/2
#define CCB 0.6324555320336759f  // sqrt(2/5)

__device__ __forceinline__ float shc_s(float x, float y, float z, const float* __restrict__ w) {
    float x2 = x * x, y2 = y * y, z2 = z * z;
    return w[0]
        + w[1] * (S3 * x) + w[2] * (S3 * y) + w[3] * (S3 * z)
        + w[4] * (S15 * x * y) + w[5] * (S15 * y * z) + w[6] * (0.5f * S5 * (3.f * z2 - 1.f))
        + w[7] * (S15 * x * z) + w[8] * (0.5f * S15 * (x2 - y2))
        + w[9] * (C1c * y * (3.f * x2 - y2)) + w[10] * (C2c * x * y * z)
        + w[11] * (C3c * y * (5.f * z2 - 1.f)) + w[12] * (C4c * z * (5.f * z2 - 3.f))
        + w[13] * (C3c * x * (5.f * z2 - 1.f)) + w[14] * (C5c * z * (x2 - y2))
        + w[15] * (C1c * x * (x2 - 3.f * y2));
}

__device__ __forceinline__ void shc_grad(float x, float y, float z, const float* __restrict__ w,
                                         float& gx, float& gy, float& gz) {
    float x2 = x * x, y2 = y * y, z2 = z * z;
    gx = w[1] * S3 + w[4] * (S15 * y) + w[7] * (S15 * z) + w[8] * (S15 * x)
       + w[9] * (6.f * C1c * x * y) + w[10] * (C2c * y * z) + w[13] * (C3c * (5.f * z2 - 1.f))
       + w[14] * (2.f * C5c * x * z) + w[15] * (3.f * C1c * (x2 - y2));
    gy = w[2] * S3 + w[4] * (S15 * x) + w[5] * (S15 * z) - w[8] * (S15 * y)
       + w[9] * (3.f * C1c * (x2 - y2)) + w[10] * (C2c * x * z) + w[11] * (C3c * (5.f * z2 - 1.f))
       - w[14] * (2.f * C5c * y * z) - w[15] * (6.f * C1c * x * y);
    gz = w[3] * S3 + w[5] * (S15 * y) + w[6] * (3.f * S5 * z) + w[7] * (S15 * x)
       + w[10] * (C2c * x * y) + w[11] * (10.f * C3c * y * z) + w[12] * (C4c * (15.f * z2 - 3.f))
       + w[13] * (10.f * C3c * x * z) + w[14] * (C5c * (x2 - y2));
}

// -------------------- CSR build --------------------

// ranks via atomic return value (the only atomics in the build)
__global__ __launch_bounds__(256) void count_kernel(const int* __restrict__ ei,
                                                    int* __restrict__ cnt,
                                                    int* __restrict__ rank_r,
                                                    int* __restrict__ rank_s) {
    int e = blockIdx.x * 256 + threadIdx.x;
    if (e >= EE) return;
    rank_r[e] = atomicAdd(&cnt[ei[EE + e]], 1);
    rank_s[e] = atomicAdd(&cnt[NN + ei[e]], 1);
}

// phase A: per-256-chunk block sums (grid = 2*NB)
__global__ __launch_bounds__(256) void scan_partial(const int* __restrict__ cnt,
                                                    int* __restrict__ parts) {
    __shared__ int wsum[4];
    int b = blockIdx.x;
    int half = b / NB;
    int cb = b - half * NB;
    int i = cb * 256 + threadIdx.x;
    int v = (i < NN) ? cnt[(size_t)half * NN + i] : 0;
    int x = v;
#pragma unroll
    for (int o = 32; o > 0; o >>= 1) x += __shfl_xor(x, o);
    int lane = threadIdx.x & 63, wid = threadIdx.x >> 6;
    if (lane == 0) wsum[wid] = x;
    __syncthreads();
    if (threadIdx.x == 0) parts[b] = wsum[0] + wsum[1] + wsum[2] + wsum[3];
}

// phase B: exclusive scan of the NB block sums per half (in place); writes totals
__global__ __launch_bounds__(256) void scan_parts(int* __restrict__ parts,
                                                  int* __restrict__ off) {
    __shared__ int wsum[4];
    __shared__ int carry_s;
    int lane = threadIdx.x & 63, wid = threadIdx.x >> 6;
    for (int h = 0; h < 2; h++) {
        if (threadIdx.x == 0) carry_s = 0;
        __syncthreads();
        for (int base = 0; base < NB; base += 256) {
            int i = base + threadIdx.x;
            int v = (i < NB) ? parts[h * NB + i] : 0;
            int x = v;
#pragma unroll
            for (int d = 1; d < 64; d <<= 1) {
                int y = __shfl_up(x, d);
                if (lane >= d) x += y;
            }
            if (lane == 63) wsum[wid] = x;
            __syncthreads();
            int pre = 0;
#pragma unroll
            for (int w = 0; w < 4; w++) if (w < wid) pre += wsum[w];
            int total = wsum[0] + wsum[1] + wsum[2] + wsum[3];
            int carry = carry_s;
            if (i < NB) parts[h * NB + i] = carry + pre + x - v;   // exclusive
            __syncthreads();
            if (threadIdx.x == 0) carry_s = carry + total;
            __syncthreads();
        }
        if (threadIdx.x == 0) off[(size_t)h * (NN + 1) + NN] = carry_s;
        __syncthreads();
    }
}

// phase C: within-chunk exclusive scan + block prefix (grid = 2*NB)
__global__ __launch_bounds__(256) void scan_apply(const int* __restrict__ cnt,
                                                  const int* __restrict__ parts,
                                                  int* __restrict__ off) {
    __shared__ int wsum[4];
    int b = blockIdx.x;
    int half = b / NB;
    int cb = b - half * NB;
    int i = cb * 256 + threadIdx.x;
    int v = (i < NN) ? cnt[(size_t)half * NN + i] : 0;
    int lane = threadIdx.x & 63, wid = threadIdx.x >> 6;
    int x = v;
#pragma unroll
    for (int d = 1; d < 64; d <<= 1) {
        int y = __shfl_up(x, d);
        if (lane >= d) x += y;
    }
    if (lane == 63) wsum[wid] = x;
    __syncthreads();
    int pre = 0;
#pragma unroll
    for (int w = 0; w < 4; w++) if (w < wid) pre += wsum[w];
    if (i < NN) off[(size_t)half * (NN + 1) + i] = parts[b] + pre + x - v;
}

// jr[e] = rcv-slot; js[e] = snd-slot (both coalesced); psl_j[snd-slot] = rcv-slot
__global__ __launch_bounds__(256) void fill_kernel(const int* __restrict__ ei,
                                                   const int* __restrict__ off,
                                                   const int* __restrict__ rank_r,
                                                   const int* __restrict__ rank_s,
                                                   int* __restrict__ jr,
                                                   int* __restrict__ js,
                                                   int* __restrict__ psl_j) {
    int e = blockIdx.x * 256 + threadIdx.x;
    if (e >= EE) return;
    int snd = ei[e], rcv = ei[EE + e];
    int sr = off[rcv] + rank_r[e];
    int ss = off[(NN + 1) + snd] + rank_s[e];
    jr[e] = sr;
    js[e] = ss;
    psl_j[ss] = sr;
}

// -------------------- geometry: thread = edge; rec + ebs0 (rcv order) + ebs1 (snd) ----

__global__ __launch_bounds__(256) void edge_geom(const float* __restrict__ pos,
                                                 const float* __restrict__ shifts,
                                                 const int* __restrict__ ei,
                                                 const float* __restrict__ wsh,
                                                 const int* __restrict__ jr,
                                                 const int* __restrict__ js,
                                                 float* __restrict__ rec,
                                                 float* __restrict__ ebs0,
                                                 float* __restrict__ ebs1) {
    int e = blockIdx.x * 256 + threadIdx.x;
    if (e >= EE) return;
    int snd = ei[e];
    int rcv = ei[EE + e];
    float vx = pos[rcv * 3 + 0] - pos[snd * 3 + 0] + shifts[e * 3 + 0];
    float vy = pos[rcv * 3 + 1] - pos[snd * 3 + 1] + shifts[e * 3 + 1];
    float vz = pos[rcv * 3 + 2] - pos[snd * 3 + 2] + shifts[e * 3 + 2];
    float r2 = vx * vx + vy * vy + vz * vz + 1e-12f;
    float r = sqrtf(r2);
    float inv_r = 1.0f / r;
    float x = vx * inv_r, y = vy * inv_r, z = vz * inv_r;

    float s0 = shc_s(x, y, z, wsh);
    float s1v = shc_s(x, y, z, wsh + 16);

    float* rc = rec + (size_t)jr[e] * RECW;
    *(float4*)&rc[0] = make_float4(x, y, z, inv_r);
    *(float4*)&rc[4] = make_float4(s0, s1v, __int_as_float(snd), __int_as_float(rcv));

    // radial eb[k] once per edge (not per lane-group)
    float u = r * (1.0f / RMAXF);
    float th = PI_F * u;
    float s1 = sinf(th), c1 = cosf(th);
    float u2 = u * u, u3 = u2 * u, u6 = u3 * u3, u7 = u6 * u, u8 = u6 * u2;
    float valid = (r < RMAXF) ? 1.f : 0.f;
    float env = (1.f - 28.f * u6 + 48.f * u7 - 21.f * u8) * valid;
    float base = CCB * inv_r * env;
    float ebv[NBES];
    {
        float sk = s1, skm = 0.f;
        float tc = 2.f * c1;
#pragma unroll
        for (int k = 0; k < NBES; k++) {
            ebv[k] = sk * base;
            float sn = tc * sk - skm; skm = sk; sk = sn;
        }
    }
    float* p0p = ebs0 + (size_t)jr[e] * 8;
    *(float4*)&p0p[0] = make_float4(ebv[0] * s0, ebv[1] * s0, ebv[2] * s0, ebv[3] * s0);
    *(float4*)&p0p[4] = make_float4(ebv[4] * s0, ebv[5] * s0, ebv[6] * s0, ebv[7] * s0);
    float* p1p = ebs1 + (size_t)js[e] * 8;
    *(float4*)&p1p[0] = make_float4(ebv[0] * s1v, ebv[1] * s1v, ebv[2] * s1v, ebv[3] * s1v);
    *(float4*)&p1p[4] = make_float4(ebv[4] * s1v, ebv[5] * s1v, ebv[6] * s1v, ebv[7] * s1v);
}

// -------------------- E1: contiguous stream over snd-ordered ebs1 ---------------------
// E1[n,k] = sum_{s in [off_snd[n], off_snd[n+1])} ebs1[s*8+k]

__global__ __launch_bounds__(256) void e1_csr(const float* __restrict__ ebs1,
                                              const int* __restrict__ off_snd,
                                              float* __restrict__ E1) {
    int gid = blockIdx.x * 256 + threadIdx.x;
    int n = gid >> 3;
    int k_l = gid & 7;
    if (n >= NN) return;
    int beg = off_snd[n], end = off_snd[n + 1];
    float acc = 0.f;
    for (int s = beg; s < end; s++) acc += ebs1[(size_t)s * 8 + k_l];
    E1[(size_t)n * 8 + k_l] = acc;
}

// -------------------- small precomputes --------------------

__global__ __launch_bounds__(128) void a1_kernel(const float* __restrict__ Wout1,
                                                 const float* __restrict__ wread1,
                                                 const float* __restrict__ Wskip1,
                                                 const float* __restrict__ ae,
                                                 float* __restrict__ a1,
                                                 float* __restrict__ askip) {
    int f = threadIdx.x;
    float s = 0.f;
    for (int k = 0; k < FF; k++) s += Wout1[f * FF + k] * wread1[k];
    a1[f] = s;
    if (f < 10) {
        float t = 0.f;
        for (int k = 0; k < FF; k++) t += Wskip1[f * FF + k] * wread1[k];
        askip[f] = t + ae[f];
    }
}

// c0[f'] = sum_f wread0[f] Wout0[f',f];  D[k,f'] = sum_f a1[f] Wr1[k,f] Wout0[f',f]
__global__ __launch_bounds__(128) void cd_kernel(const float* __restrict__ Wout0,
                                                 const float* __restrict__ wread0,
                                                 const float* __restrict__ a1,
                                                 const float* __restrict__ Wr1,
                                                 float* __restrict__ c0,
                                                 float* __restrict__ D) {
    int fp = threadIdx.x;
    float c = 0.f;
    float d[NBES];
#pragma unroll
    for (int k = 0; k < NBES; k++) d[k] = 0.f;
    for (int f = 0; f < FF; f++) {
        float w = Wout0[fp * FF + f];
        c += wread0[f] * w;
        float aw = a1[f] * w;
#pragma unroll
        for (int k = 0; k < NBES; k++) d[k] += aw * Wr1[k * FF + f];
    }
    c0[fp] = c;
#pragma unroll
    for (int k = 0; k < NBES; k++) D[k * FF + fp] = d[k];
}

// GW[p=a*8+k][f'] = sum_f W_emb[a,f] Wr0[k,f] Wout0[f,f']
__global__ __launch_bounds__(256) void gw_kernel(const float* __restrict__ W_emb,
                                                 const float* __restrict__ Wr0,
                                                 const float* __restrict__ Wout0,
                                                 float* __restrict__ GW) {
    int idx = blockIdx.x * 256 + threadIdx.x;
    if (idx >= 80 * FF) return;
    int fp = idx & 127;
    int p = idx >> 7;
    int a = p >> 3, k = p & 7;
    float s = 0.f;
    for (int f = 0; f < FF; f++)
        s += W_emb[a * FF + f] * Wr0[k * FF + f] * Wout0[f * FF + fp];
    GW[p * FF + fp] = s;
}

// T[k'][p0=k*10+a] = sum_f D[k',f] W_emb[a,f] Wr0[k,f];  Mc[p0] = sum_f c0[f] W_emb Wr0
__global__ __launch_bounds__(256) void tmc_kernel(const float* __restrict__ D,
                                                  const float* __restrict__ c0,
                                                  const float* __restrict__ W_emb,
                                                  const float* __restrict__ Wr0,
                                                  float* __restrict__ T,
                                                  float* __restrict__ Mc) {
    for (int i = threadIdx.x; i < 720; i += 256) {
        if (i < 640) {
            int kp = i / 80;
            int p0 = i - kp * 80;
            int k = p0 / 10, a = p0 - k * 10;
            float s = 0.f;
            for (int f = 0; f < FF; f++)
                s += D[kp * FF + f] * W_emb[a * FF + f] * Wr0[k * FF + f];
            T[i] = s;
        } else {
            int p0 = i - 640;
            int k = p0 / 10, a = p0 - k * 10;
            float s = 0.f;
            for (int f = 0; f < FF; f++)
                s += c0[f] * W_emb[a * FF + f] * Wr0[k * FF + f];
            Mc[p0] = s;
        }
    }
}

// -------------------- P0[n, p=a*8+k] = sum_{e:rcv=n} attrs[snd,a] ebs0[j,k] -----------

#define P0_BLOCKS 2048
__global__ __launch_bounds__(256) void p0_kernel(const float* __restrict__ rec,
                                                 const float* __restrict__ ebs0,
                                                 const int* __restrict__ off,
                                                 const float* __restrict__ attrs,
                                                 float* __restrict__ P0) {
    int wv = (blockIdx.x * 256 + threadIdx.x) >> 6;
    int lane = threadIdx.x & 63;
    int nwaves = P0_BLOCKS * 4;
    int a_lo = lane >> 3;
    int k_l = lane & 7;

    for (int n = wv; n < NN; n += nwaves) {
        int beg = off[n], end = off[n + 1];
        float acc = 0.f, acc2 = 0.f;
        for (int j = beg; j < end; j++) {
            float es = ebs0[(size_t)j * 8 + k_l];
            int snd = __float_as_int(rec[(size_t)j * RECW + 6]);
            acc += attrs[snd * 10 + a_lo] * es;
            if (lane < 16) acc2 += attrs[snd * 10 + 8 + a_lo] * es;
        }
        P0[(size_t)n * 80 + lane] = acc;
        if (lane < 16) P0[(size_t)n * 80 + 64 + lane] = acc2;
    }
}

// -------------------- h1 GEMM: h1 = P0 @ GW + attrs @ Wskip0 ; node_e = h1.wread0 ------

#define GEMM_BLOCKS 512
__global__ __launch_bounds__(256, 2) void h1_gemm(const float* __restrict__ P0,
                                                  const float* __restrict__ GW,
                                                  const float* __restrict__ attrs,
                                                  const float* __restrict__ Wskip,
                                                  const float* __restrict__ wread,
                                                  float* __restrict__ h1,
                                                  float* __restrict__ node_e) {
    __shared__ float sb[80][FF];   // 40 KB
    __shared__ float sa[32][80];   // 10 KB
    int t = threadIdx.x;
#pragma unroll
    for (int j = 0; j < 10; j++) {
        int flat4 = j * 256 + t;
        int row = flat4 >> 5;
        int col = (flat4 & 31) * 4;
        *(float4*)&sb[row][col] = *(const float4*)&GW[row * FF + col];
    }

    int g = t >> 5;
    int f0 = (t & 31) * 4;
    const int NTILES = (NN + 31) / 32;

    for (int tile = blockIdx.x; tile < NTILES; tile += GEMM_BLOCKS) {
        __syncthreads();
#pragma unroll
        for (int j = 0; j < 3; j++) {
            int flat4 = j * 256 + t;
            if (flat4 < 640) {
                int row = flat4 / 20;
                int col = (flat4 - row * 20) * 4;
                int n = tile * 32 + row;
                float4 v = make_float4(0.f, 0.f, 0.f, 0.f);
                if (n < NN) v = *(const float4*)&P0[(size_t)n * 80 + col];
                *(float4*)&sa[row][col] = v;
            }
        }
        __syncthreads();

        float acc[4][4];
#pragma unroll
        for (int i = 0; i < 4; i++)
#pragma unroll
            for (int j = 0; j < 4; j++) acc[i][j] = 0.f;

        for (int kk = 0; kk < 80; kk += 4) {
            float4 bv0 = *(const float4*)&sb[kk + 0][f0];
            float4 bv1 = *(const float4*)&sb[kk + 1][f0];
            float4 bv2 = *(const float4*)&sb[kk + 2][f0];
            float4 bv3 = *(const float4*)&sb[kk + 3][f0];
#pragma unroll
            for (int ni = 0; ni < 4; ni++) {
                float4 av = *(const float4*)&sa[g * 4 + ni][kk];
                acc[ni][0] += av.x * bv0.x + av.y * bv1.x + av.z * bv2.x + av.w * bv3.x;
                acc[ni][1] += av.x * bv0.y + av.y * bv1.y + av.z * bv2.y + av.w * bv3.y;
                acc[ni][2] += av.x * bv0.z + av.y * bv1.z + av.z * bv2.z + av.w * bv3.z;
                acc[ni][3] += av.x * bv0.w + av.y * bv1.w + av.z * bv2.w + av.w * bv3.w;
            }
        }

#pragma unroll
        for (int ni = 0; ni < 4; ni++) {
            int n = tile * 32 + g * 4 + ni;
            bool valid = (n < NN);
#pragma unroll
            for (int a = 0; a < 10; a++) {
                float att = valid ? attrs[n * 10 + a] : 0.f;
                float4 wk = *(const float4*)&Wskip[a * FF + f0];
                acc[ni][0] += att * wk.x;
                acc[ni][1] += att * wk.y;
                acc[ni][2] += att * wk.z;
                acc[ni][3] += att * wk.w;
            }
            if (valid) {
                float4 out;
                out.x = acc[ni][0]; out.y = acc[ni][1];
                out.z = acc[ni][2]; out.w = acc[ni][3];
                *(float4*)&h1[(size_t)n * FF + f0] = out;
            }
            float4 wv = *(const float4*)&wread[f0];
            float p = acc[ni][0] * wv.x + acc[ni][1] * wv.y
                    + acc[ni][2] * wv.z + acc[ni][3] * wv.w;
#pragma unroll
            for (int o = 16; o > 0; o >>= 1) p += __shfl_xor(p, o);
            if (valid && (t & 31) == 0) node_e[n] = p;
        }
    }
}

// -------------------- t1[n,k] = sum_f a1[f] h1[n,f] Wr1[k,f] --------------------

__global__ __launch_bounds__(256) void t1_kernel(const float* __restrict__ h1,
                                                 const float* __restrict__ a1,
                                                 const float* __restrict__ Wr1,
                                                 float* __restrict__ t1) {
    int w = threadIdx.x >> 6;
    int lane = threadIdx.x & 63;
    int n = blockIdx.x * 4 + w;
    if (n >= NN) return;
    int f0 = lane, f1 = lane + 64;
    float v0 = a1[f0] * h1[(size_t)n * FF + f0];
    float v1 = a1[f1] * h1[(size_t)n * FF + f1];
    float p[NBES];
#pragma unroll
    for (int k = 0; k < NBES; k++)
        p[k] = v0 * Wr1[k * FF + f0] + v1 * Wr1[k * FF + f1];
#pragma unroll
    for (int o = 32; o > 0; o >>= 1) {
#pragma unroll
        for (int k = 0; k < NBES; k++) p[k] += __shfl_xor(p[k], o);
    }
    if (lane == 0) {
        *(float4*)&t1[(size_t)n * 8]     = make_float4(p[0], p[1], p[2], p[3]);
        *(float4*)&t1[(size_t)n * 8 + 4] = make_float4(p[4], p[5], p[6], p[7]);
    }
}

// -------------------- M[n][p0=k*10+a] = Mc + sum_k' E1[n,k'] T[k'][p0] ----------------

__global__ __launch_bounds__(256) void m_kernel(const float* __restrict__ E1,
                                                const float* __restrict__ T,
                                                const float* __restrict__ Mc,
                                                float* __restrict__ M) {
    __shared__ float sT[720];
    int t = threadIdx.x;
    for (int i = t; i < 720; i += 256) sT[i] = (i < 640) ? T[i] : Mc[i - 640];
    __syncthreads();
    int n = blockIdx.x * 256 + t;
    if (n >= NN) return;
    float4 ea = *(const float4*)&E1[(size_t)n * 8];
    float4 eb = *(const float4*)&E1[(size_t)n * 8 + 4];
    float e1v[8] = {ea.x, ea.y, ea.z, ea.w, eb.x, eb.y, eb.z, eb.w};
#pragma unroll
    for (int c = 0; c < 20; c++) {
        float4 m = *(const float4*)&sT[640 + c * 4];
#pragma unroll
        for (int kp = 0; kp < 8; kp++) {
            float4 tv = *(const float4*)&sT[kp * 80 + c * 4];
            m.x += e1v[kp] * tv.x;
            m.y += e1v[kp] * tv.y;
            m.z += e1v[kp] * tv.z;
            m.w += e1v[kp] * tv.w;
        }
        *(float4*)&M[(size_t)n * 80 + c * 4] = m;
    }
}

// -------------------- fused per-edge pass: recompute radial, dsp/drp, energy1, gv -----

#define EP_BLOCKS 512
__global__ __launch_bounds__(256) void edge_pass(const float* __restrict__ rec,
                                                 const float* __restrict__ t1,
                                                 const float* __restrict__ M,
                                                 const float* __restrict__ attrs,
                                                 const int* __restrict__ batch,
                                                 const float* __restrict__ wsh,
                                                 float4* __restrict__ gvp,
                                                 float* __restrict__ energy) {
    __shared__ float eacc[GG];
    int t = threadIdx.x;
    int lane = t & 63;
    if (t < GG) eacc[t] = 0.f;
    __syncthreads();

    for (int j0 = blockIdx.x * 256; j0 < EE; j0 += EP_BLOCKS * 256) {
        int j = j0 + t;
        bool act = (j < EE);
        int jc = act ? j : 0;
        const float* rc = rec + (size_t)jc * RECW;
        float4 q0 = *(const float4*)&rc[0];
        float4 q1 = *(const float4*)&rc[4];
        float x = q0.x, y = q0.y, z = q0.z, ivr = q0.w;
        float s0 = q1.x, s1v = q1.y;
        int snd = __float_as_int(q1.z);
        int rcv = __float_as_int(q1.w);

        // recompute radial eb/db
        float r = 1.0f / ivr;
        float u = r * (1.0f / RMAXF);
        float th = PI_F * u;
        float s1 = sinf(th), c1 = cosf(th);
        float u2 = u * u, u3 = u2 * u, u5 = u2 * u3, u6 = u3 * u3, u7 = u6 * u, u8 = u6 * u2;
        float valid = (r < RMAXF) ? 1.f : 0.f;
        float env = (1.f - 28.f * u6 + 48.f * u7 - 21.f * u8) * valid;
        float denv = (-168.f * u5 + 336.f * u6 - 168.f * u7) * (1.0f / RMAXF) * valid;
        float eb[NBES], db[NBES];
        {
            float sk = s1, skm = 0.f, ck = c1, ckm = 1.f;
            float tc = 2.f * c1;
#pragma unroll
            for (int k = 1; k <= NBES; k++) {
                float b = CCB * sk * ivr;
                eb[k - 1] = b * env;
                db[k - 1] = CCB * (((float)k * PI_F * (1.0f / RMAXF)) * ck * ivr
                                   - sk * ivr * ivr) * env
                            + b * denv;
                float sn = tc * sk - skm; skm = sk; sk = sn;
                float cn = tc * ck - ckm; ckm = ck; ck = cn;
            }
        }

        // layer 1: dsp1/drp1 via t1[snd]
        float4 ta = *(const float4*)&t1[(size_t)snd * 8];
        float4 tb = *(const float4*)&t1[(size_t)snd * 8 + 4];
        float tg[8] = {ta.x, ta.y, ta.z, ta.w, tb.x, tb.y, tb.z, tb.w};
        float dsp1 = 0.f, drp1 = 0.f;
#pragma unroll
        for (int k = 0; k < 8; k++) {
            dsp1 += eb[k] * tg[k];
            drp1 += db[k] * tg[k];
        }

        // layer 0: t0[k] = sum_a attrs[snd,a] M[rcv,k,a]
        float at[10];
#pragma unroll
        for (int i = 0; i < 5; i++) {
            float2 v = *(const float2*)&attrs[snd * 10 + 2 * i];
            at[2 * i] = v.x; at[2 * i + 1] = v.y;
        }
        const float* Mr = M + (size_t)rcv * 80;
        float dsp0 = 0.f, drp0 = 0.f;
#pragma unroll
        for (int k = 0; k < 8; k++) {
            float t0 = 0.f;
#pragma unroll
            for (int a = 0; a < 10; a++) t0 += at[a] * Mr[k * 10 + a];
            dsp0 += eb[k] * t0;
            drp0 += db[k] * t0;
        }

        // layer-1 energy contribution: s1 * dsp1, grouped by batch[rcv]
        float el = act ? s1v * dsp1 : 0.f;
        int b = act ? batch[rcv] : -1;
        int ub = __builtin_amdgcn_readfirstlane(b);
        if (__all(b == ub)) {
            float es = el;
#pragma unroll
            for (int o = 32; o > 0; o >>= 1) es += __shfl_xor(es, o);
            if (lane == 0 && ub >= 0) atomicAdd(&eacc[ub], es);
        } else {
            if (act) atomicAdd(&eacc[b], el);
        }

        // per-edge force vector (coalesced write)
        float g0x, g0y, g0z, g1x, g1y, g1z;
        shc_grad(x, y, z, wsh, g0x, g0y, g0z);
        shc_grad(x, y, z, wsh + 16, g1x, g1y, g1z);
        float gux = dsp0 * g0x + dsp1 * g1x;
        float guy = dsp0 * g0y + dsp1 * g1y;
        float guz = dsp0 * g0z + dsp1 * g1z;
        float gr = s0 * drp0 + s1v * drp1;
        float dgu = gux * x + guy * y + guz * z;
        float gvx = gr * x + ivr * (gux - dgu * x);
        float gvy = gr * y + ivr * (guy - dgu * y);
        float gvz = gr * z + ivr * (guz - dgu * z);
        if (act) gvp[j] = make_float4(gvx, gvy, gvz, 0.f);
    }
    __syncthreads();
    if (t < GG && eacc[t] != 0.f) atomicAdd(&energy[t], eacc[t]);
}

// -------------------- force gather (thread-per-node, no atomics) ----------------------

__global__ __launch_bounds__(256) void force_gather(const int* __restrict__ off_rcv,
                                                    const int* __restrict__ off_snd,
                                                    const int* __restrict__ psl_j,
                                                    const float4* __restrict__ gvp,
                                                    float* __restrict__ forces) {
    int n = blockIdx.x * 256 + threadIdx.x;
    if (n >= NN) return;
    float fx = 0.f, fy = 0.f, fz = 0.f;
    int beg = off_rcv[n], end = off_rcv[n + 1];
    for (int j = beg; j < end; j++) {
        float4 g = gvp[j];
        fx -= g.x; fy -= g.y; fz -= g.z;
    }
    beg = off_snd[n]; end = off_snd[n + 1];
    for (int s = beg; s < end; s++) {
        float4 g = gvp[psl_j[s]];
        fx += g.x; fy += g.y; fz += g.z;
    }
    forces[n * 3 + 0] = fx;
    forces[n * 3 + 1] = fy;
    forces[n * 3 + 2] = fz;
}

// -------------------- energy finalize: node_e + attrs.askip --------------------

#define EF_BLOCKS 128
__global__ __launch_bounds__(256) void efinal_kernel(const float* __restrict__ node_e,
                                                     const float* __restrict__ attrs,
                                                     const float* __restrict__ askip,
                                                     const int* __restrict__ batch,
                                                     float* __restrict__ energy) {
    __shared__ float eacc[GG];
    int t = threadIdx.x;
    if (t < GG) eacc[t] = 0.f;
    __syncthreads();
    for (int n = blockIdx.x * 256 + t; n < NN; n += EF_BLOCKS * 256) {
        float v = node_e[n];
#pragma unroll
        for (int a = 0; a < 10; a++) v += attrs[n * 10 + a] * askip[a];
        atomicAdd(&eacc[batch[n]], v);
    }
    __syncthreads();
    if (t < GG && eacc[t] != 0.f) atomicAdd(&energy[t], eacc[t]);
}

// -------------------- launch --------------------

extern "C" void kernel_launch(void* const* d_in, const int* in_sizes, int n_in,
                              void* d_out, int out_size, void* d_ws, size_t ws_size,
                              hipStream_t stream) {
    const float* pos    = (const float*)d_in[0];
    const float* attrs  = (const float*)d_in[1];
    const float* shifts = (const float*)d_in[2];
    const int*   ei     = (const int*)d_in[3];
    const int*   batch  = (const int*)d_in[4];
    const float* W_emb  = (const float*)d_in[6];
    const float* ae     = (const float*)d_in[7];
    const float* W_r    = (const float*)d_in[8];   // (2,8,F)
    const float* w_sh   = (const float*)d_in[9];   // (2,16)
    const float* W_out  = (const float*)d_in[10];  // (2,F,F)
    const float* W_skip = (const float*)d_in[11];  // (2,10,F)
    const float* w_read = (const float*)d_in[12];  // (2,F)

    const float* Wr0 = W_r;
    const float* Wr1 = W_r + NBES * FF;
    const float* Wout0 = W_out;
    const float* Wout1 = W_out + FF * FF;

    float* energy = (float*)d_out;
    float* forces = energy + GG;

    float* ws  = (float*)d_ws;
    float* h1  = ws;                        // N*F
    float* P0  = h1 + (size_t)NN * FF;      // N*80
    float* M   = P0 + (size_t)NN * 80;      // N*80
    float* E1  = M + (size_t)NN * 80;       // N*8
    float* t1  = E1 + (size_t)NN * 8;       // N*8
    float* node_e = t1 + (size_t)NN * 8;    // N
    float* rec = node_e + NN;               // EE*8
    float* ebs0 = rec + (size_t)EE * RECW;  // EE*8
    float* ebs1 = ebs0 + (size_t)EE * 8;    // EE*8
    float4* gvp = (float4*)(ebs1 + (size_t)EE * 8);  // EE*4 floats
    float* a1  = (float*)(gvp + EE);        // 128
    float* askip = a1 + FF;                 // 16
    float* c0  = askip + 16;                // 128
    float* D   = c0 + FF;                   // 8*128
    float* GW  = D + NBES * FF;             // 80*128
    float* T   = GW + 80 * FF;              // 640
    float* Mc  = T + 640;                   // 80

    int* cnt    = (int*)(Mc + 80);          // 2N
    int* off    = cnt + 2 * NN;             // 2(N+1)
    int* rank_r = off + 2 * (NN + 1);       // EE
    int* rank_s = rank_r + EE;              // EE
    int* jr     = rank_s + EE;              // EE
    int* js     = jr + EE;                  // EE
    int* psl_j  = js + EE;                  // EE
    int* parts  = psl_j + EE;               // 2*NB
    const int* off_rcv = off;
    const int* off_snd = off + (NN + 1);

    const int edgeBlocks = (EE + 255) / 256;
    const int nodeBlocks = (NN + 255) / 256;

    hipMemsetAsync(d_out, 0, (size_t)out_size * sizeof(float), stream);
    hipMemsetAsync(cnt, 0, (size_t)2 * NN * sizeof(int), stream);

    // CSR build: atomics only in count (rank capture); parallel 3-phase scan
    count_kernel<<<edgeBlocks, 256, 0, stream>>>(ei, cnt, rank_r, rank_s);
    scan_partial<<<2 * NB, 256, 0, stream>>>(cnt, parts);
    scan_parts<<<1, 256, 0, stream>>>(parts, off);
    scan_apply<<<2 * NB, 256, 0, stream>>>(cnt, parts, off);
    fill_kernel<<<edgeBlocks, 256, 0, stream>>>(ei, off, rank_r, rank_s, jr, js, psl_j);

    // small precomputes
    a1_kernel<<<1, 128, 0, stream>>>(Wout1, w_read + FF, W_skip + 10 * FF, ae, a1, askip);
    cd_kernel<<<1, 128, 0, stream>>>(Wout0, w_read, a1, Wr1, c0, D);
    gw_kernel<<<40, 256, 0, stream>>>(W_emb, Wr0, Wout0, GW);
    tmc_kernel<<<1, 256, 0, stream>>>(D, c0, W_emb, Wr0, T, Mc);

    // geometry records + eb*s0 (rcv order) + eb*s1 (snd order)
    edge_geom<<<edgeBlocks, 256, 0, stream>>>(pos, shifts, ei, w_sh, jr, js,
                                              rec, ebs0, ebs1);

    // E1: contiguous stream over ebs1 (no atomics, no transcendentals)
    e1_csr<<<(NN * 8 + 255) / 256, 256, 0, stream>>>(ebs1, off_snd, E1);

    // P0 (pure gather+FMA), then h1, t1, M
    p0_kernel<<<P0_BLOCKS, 256, 0, stream>>>(rec, ebs0, off_rcv, attrs, P0);
    h1_gemm<<<GEMM_BLOCKS, 256, 0, stream>>>(P0, GW, attrs, W_skip, w_read, h1, node_e);
    t1_kernel<<<(NN + 3) / 4, 256, 0, stream>>>(h1, a1, Wr1, t1);
    m_kernel<<<nodeBlocks, 256, 0, stream>>>(E1, T, Mc, M);

    // fused per-edge: recompute radial, dsp/drp both layers, layer-1 energy, gv
    edge_pass<<<EP_BLOCKS, 256, 0, stream>>>(rec, t1, M, attrs, batch, w_sh, gvp, energy);

    // forces via CSR gather (no atomics)
    force_gather<<<nodeBlocks, 256, 0, stream>>>(off_rcv, off_snd, psl_j, gvp, forces);

    // energy finalize (layer-0 node energies + layer-1 skip + e0)
    efinal_kernel<<<EF_BLOCKS, 256, 0, stream>>>(node_e, attrs, askip, batch, energy);
}

// Round 15
// 352.653 us; speedup vs baseline: 2.9899x; 1.1410x over previous
//
#include <hip/hip_runtime.h>

#define NN 50000
#define EE 800000
#define GG 64
#define FF 128
#define NBES 8
#define RECW 8    // compact record: x, y, z, inv_r, s0, s1, snd, rcv  (32 B)
#define RMAXF 5.0f
#define PI_F 3.14159265358979323846f
#define NB ((NN + 255) / 256)   // 196 chunks per half

// spherical harmonic constants
#define S3  1.7320508075688772f
#define S5  2.23606797749979f
#define S15 3.872983346207417f
#define C1c 2.091650066335189f   // sqrt(35/8)
#define C2c 10.246950765959598f  // sqrt(105)
#define C3c 1.62018517460196f    // sqrt(21/8)
#define C4c 1.3228756555322954f  // sqrt(7)/2
#define C5c 5.123475382979799f   // sqrt(105)/2
#define CCB 0.6324555320336759f  // sqrt(2/5)

__device__ __forceinline__ float shc_s(float x, float y, float z, const float* __restrict__ w) {
    float x2 = x * x, y2 = y * y, z2 = z * z;
    return w[0]
        + w[1] * (S3 * x) + w[2] * (S3 * y) + w[3] * (S3 * z)
        + w[4] * (S15 * x * y) + w[5] * (S15 * y * z) + w[6] * (0.5f * S5 * (3.f * z2 - 1.f))
        + w[7] * (S15 * x * z) + w[8] * (0.5f * S15 * (x2 - y2))
        + w[9] * (C1c * y * (3.f * x2 - y2)) + w[10] * (C2c * x * y * z)
        + w[11] * (C3c * y * (5.f * z2 - 1.f)) + w[12] * (C4c * z * (5.f * z2 - 3.f))
        + w[13] * (C3c * x * (5.f * z2 - 1.f)) + w[14] * (C5c * z * (x2 - y2))
        + w[15] * (C1c * x * (x2 - 3.f * y2));
}

__device__ __forceinline__ void shc_grad(float x, float y, float z, const float* __restrict__ w,
                                         float& gx, float& gy, float& gz) {
    float x2 = x * x, y2 = y * y, z2 = z * z;
    gx = w[1] * S3 + w[4] * (S15 * y) + w[7] * (S15 * z) + w[8] * (S15 * x)
       + w[9] * (6.f * C1c * x * y) + w[10] * (C2c * y * z) + w[13] * (C3c * (5.f * z2 - 1.f))
       + w[14] * (2.f * C5c * x * z) + w[15] * (3.f * C1c * (x2 - y2));
    gy = w[2] * S3 + w[4] * (S15 * x) + w[5] * (S15 * z) - w[8] * (S15 * y)
       + w[9] * (3.f * C1c * (x2 - y2)) + w[10] * (C2c * x * z) + w[11] * (C3c * (5.f * z2 - 1.f))
       - w[14] * (2.f * C5c * y * z) - w[15] * (6.f * C1c * x * y);
    gz = w[3] * S3 + w[5] * (S15 * y) + w[6] * (3.f * S5 * z) + w[7] * (S15 * x)
       + w[10] * (C2c * x * y) + w[11] * (10.f * C3c * y * z) + w[12] * (C4c * (15.f * z2 - 3.f))
       + w[13] * (10.f * C3c * x * z) + w[14] * (C5c * (x2 - y2));
}

// -------------------- CSR build --------------------

// ranks via atomic return value (the only atomics in the build)
__global__ __launch_bounds__(256) void count_kernel(const int* __restrict__ ei,
                                                    int* __restrict__ cnt,
                                                    int* __restrict__ rank_r,
                                                    int* __restrict__ rank_s) {
    int e = blockIdx.x * 256 + threadIdx.x;
    if (e >= EE) return;
    rank_r[e] = atomicAdd(&cnt[ei[EE + e]], 1);
    rank_s[e] = atomicAdd(&cnt[NN + ei[e]], 1);
}

// phase A: per-256-chunk block sums (grid = 2*NB)
__global__ __launch_bounds__(256) void scan_partial(const int* __restrict__ cnt,
                                                    int* __restrict__ parts) {
    __shared__ int wsum[4];
    int b = blockIdx.x;
    int half = b / NB;
    int cb = b - half * NB;
    int i = cb * 256 + threadIdx.x;
    int v = (i < NN) ? cnt[(size_t)half * NN + i] : 0;
    int x = v;
#pragma unroll
    for (int o = 32; o > 0; o >>= 1) x += __shfl_xor(x, o);
    int lane = threadIdx.x & 63, wid = threadIdx.x >> 6;
    if (lane == 0) wsum[wid] = x;
    __syncthreads();
    if (threadIdx.x == 0) parts[b] = wsum[0] + wsum[1] + wsum[2] + wsum[3];
}

// phase B: exclusive scan of the NB block sums per half (in place); writes totals
__global__ __launch_bounds__(256) void scan_parts(int* __restrict__ parts,
                                                  int* __restrict__ off) {
    __shared__ int wsum[4];
    __shared__ int carry_s;
    int lane = threadIdx.x & 63, wid = threadIdx.x >> 6;
    for (int h = 0; h < 2; h++) {
        if (threadIdx.x == 0) carry_s = 0;
        __syncthreads();
        for (int base = 0; base < NB; base += 256) {
            int i = base + threadIdx.x;
            int v = (i < NB) ? parts[h * NB + i] : 0;
            int x = v;
#pragma unroll
            for (int d = 1; d < 64; d <<= 1) {
                int y = __shfl_up(x, d);
                if (lane >= d) x += y;
            }
            if (lane == 63) wsum[wid] = x;
            __syncthreads();
            int pre = 0;
#pragma unroll
            for (int w = 0; w < 4; w++) if (w < wid) pre += wsum[w];
            int total = wsum[0] + wsum[1] + wsum[2] + wsum[3];
            int carry = carry_s;
            if (i < NB) parts[h * NB + i] = carry + pre + x - v;   // exclusive
            __syncthreads();
            if (threadIdx.x == 0) carry_s = carry + total;
            __syncthreads();
        }
        if (threadIdx.x == 0) off[(size_t)h * (NN + 1) + NN] = carry_s;
        __syncthreads();
    }
}

// phase C: within-chunk exclusive scan + block prefix (grid = 2*NB)
__global__ __launch_bounds__(256) void scan_apply(const int* __restrict__ cnt,
                                                  const int* __restrict__ parts,
                                                  int* __restrict__ off) {
    __shared__ int wsum[4];
    int b = blockIdx.x;
    int half = b / NB;
    int cb = b - half * NB;
    int i = cb * 256 + threadIdx.x;
    int v = (i < NN) ? cnt[(size_t)half * NN + i] : 0;
    int lane = threadIdx.x & 63, wid = threadIdx.x >> 6;
    int x = v;
#pragma unroll
    for (int d = 1; d < 64; d <<= 1) {
        int y = __shfl_up(x, d);
        if (lane >= d) x += y;
    }
    if (lane == 63) wsum[wid] = x;
    __syncthreads();
    int pre = 0;
#pragma unroll
    for (int w = 0; w < 4; w++) if (w < wid) pre += wsum[w];
    if (i < NN) off[(size_t)half * (NN + 1) + i] = parts[b] + pre + x - v;
}

// jr[e] = rcv-slot; js[e] = snd-slot (both coalesced); psl_j[snd-slot] = rcv-slot
__global__ __launch_bounds__(256) void fill_kernel(const int* __restrict__ ei,
                                                   const int* __restrict__ off,
                                                   const int* __restrict__ rank_r,
                                                   const int* __restrict__ rank_s,
                                                   int* __restrict__ jr,
                                                   int* __restrict__ js,
                                                   int* __restrict__ psl_j) {
    int e = blockIdx.x * 256 + threadIdx.x;
    if (e >= EE) return;
    int snd = ei[e], rcv = ei[EE + e];
    int sr = off[rcv] + rank_r[e];
    int ss = off[(NN + 1) + snd] + rank_s[e];
    jr[e] = sr;
    js[e] = ss;
    psl_j[ss] = sr;
}

// -------------------- geometry: thread = edge; rec + ebs0 (rcv order) + ebs1 (snd) ----

__global__ __launch_bounds__(256) void edge_geom(const float* __restrict__ pos,
                                                 const float* __restrict__ shifts,
                                                 const int* __restrict__ ei,
                                                 const float* __restrict__ wsh,
                                                 const int* __restrict__ jr,
                                                 const int* __restrict__ js,
                                                 float* __restrict__ rec,
                                                 float* __restrict__ ebs0,
                                                 float* __restrict__ ebs1) {
    int e = blockIdx.x * 256 + threadIdx.x;
    if (e >= EE) return;
    int snd = ei[e];
    int rcv = ei[EE + e];
    float vx = pos[rcv * 3 + 0] - pos[snd * 3 + 0] + shifts[e * 3 + 0];
    float vy = pos[rcv * 3 + 1] - pos[snd * 3 + 1] + shifts[e * 3 + 1];
    float vz = pos[rcv * 3 + 2] - pos[snd * 3 + 2] + shifts[e * 3 + 2];
    float r2 = vx * vx + vy * vy + vz * vz + 1e-12f;
    float r = sqrtf(r2);
    float inv_r = 1.0f / r;
    float x = vx * inv_r, y = vy * inv_r, z = vz * inv_r;

    float s0 = shc_s(x, y, z, wsh);
    float s1v = shc_s(x, y, z, wsh + 16);

    float* rc = rec + (size_t)jr[e] * RECW;
    *(float4*)&rc[0] = make_float4(x, y, z, inv_r);
    *(float4*)&rc[4] = make_float4(s0, s1v, __int_as_float(snd), __int_as_float(rcv));

    // radial eb[k] once per edge
    float u = r * (1.0f / RMAXF);
    float th = PI_F * u;
    float s1 = sinf(th), c1 = cosf(th);
    float u2 = u * u, u3 = u2 * u, u6 = u3 * u3, u7 = u6 * u, u8 = u6 * u2;
    float valid = (r < RMAXF) ? 1.f : 0.f;
    float env = (1.f - 28.f * u6 + 48.f * u7 - 21.f * u8) * valid;
    float base = CCB * inv_r * env;
    float ebv[NBES];
    {
        float sk = s1, skm = 0.f;
        float tc = 2.f * c1;
#pragma unroll
        for (int k = 0; k < NBES; k++) {
            ebv[k] = sk * base;
            float sn = tc * sk - skm; skm = sk; sk = sn;
        }
    }
    float* p0p = ebs0 + (size_t)jr[e] * 8;
    *(float4*)&p0p[0] = make_float4(ebv[0] * s0, ebv[1] * s0, ebv[2] * s0, ebv[3] * s0);
    *(float4*)&p0p[4] = make_float4(ebv[4] * s0, ebv[5] * s0, ebv[6] * s0, ebv[7] * s0);
    float* p1p = ebs1 + (size_t)js[e] * 8;
    *(float4*)&p1p[0] = make_float4(ebv[0] * s1v, ebv[1] * s1v, ebv[2] * s1v, ebv[3] * s1v);
    *(float4*)&p1p[4] = make_float4(ebv[4] * s1v, ebv[5] * s1v, ebv[6] * s1v, ebv[7] * s1v);
}

// -------------------- E1: contiguous stream over snd-ordered ebs1 ---------------------

__global__ __launch_bounds__(256) void e1_csr(const float* __restrict__ ebs1,
                                              const int* __restrict__ off_snd,
                                              float* __restrict__ E1) {
    int gid = blockIdx.x * 256 + threadIdx.x;
    int n = gid >> 3;
    int k_l = gid & 7;
    if (n >= NN) return;
    int beg = off_snd[n], end = off_snd[n + 1];
    float acc = 0.f;
    for (int s = beg; s < end; s++) acc += ebs1[(size_t)s * 8 + k_l];
    E1[(size_t)n * 8 + k_l] = acc;
}

// -------------------- small precomputes --------------------

__global__ __launch_bounds__(128) void a1_kernel(const float* __restrict__ Wout1,
                                                 const float* __restrict__ wread1,
                                                 const float* __restrict__ Wskip1,
                                                 const float* __restrict__ ae,
                                                 float* __restrict__ a1,
                                                 float* __restrict__ askip) {
    int f = threadIdx.x;
    float s = 0.f;
    for (int k = 0; k < FF; k++) s += Wout1[f * FF + k] * wread1[k];
    a1[f] = s;
    if (f < 10) {
        float t = 0.f;
        for (int k = 0; k < FF; k++) t += Wskip1[f * FF + k] * wread1[k];
        askip[f] = t + ae[f];
    }
}

// c0[f'] = sum_f wread0[f] Wout0[f',f];  D[k,f'] = sum_f a1[f] Wr1[k,f] Wout0[f',f]
__global__ __launch_bounds__(128) void cd_kernel(const float* __restrict__ Wout0,
                                                 const float* __restrict__ wread0,
                                                 const float* __restrict__ a1,
                                                 const float* __restrict__ Wr1,
                                                 float* __restrict__ c0,
                                                 float* __restrict__ D) {
    int fp = threadIdx.x;
    float c = 0.f;
    float d[NBES];
#pragma unroll
    for (int k = 0; k < NBES; k++) d[k] = 0.f;
    for (int f = 0; f < FF; f++) {
        float w = Wout0[fp * FF + f];
        c += wread0[f] * w;
        float aw = a1[f] * w;
#pragma unroll
        for (int k = 0; k < NBES; k++) d[k] += aw * Wr1[k * FF + f];
    }
    c0[fp] = c;
#pragma unroll
    for (int k = 0; k < NBES; k++) D[k * FF + fp] = d[k];
}

// GW[p=a*8+k][f'] = sum_f W_emb[a,f] Wr0[k,f] Wout0[f,f']
__global__ __launch_bounds__(256) void gw_kernel(const float* __restrict__ W_emb,
                                                 const float* __restrict__ Wr0,
                                                 const float* __restrict__ Wout0,
                                                 float* __restrict__ GW) {
    int idx = blockIdx.x * 256 + threadIdx.x;
    if (idx >= 80 * FF) return;
    int fp = idx & 127;
    int p = idx >> 7;
    int a = p >> 3, k = p & 7;
    float s = 0.f;
    for (int f = 0; f < FF; f++)
        s += W_emb[a * FF + f] * Wr0[k * FF + f] * Wout0[f * FF + fp];
    GW[p * FF + fp] = s;
}

// T[k'][p0=k*10+a] = sum_f D[k',f] W_emb[a,f] Wr0[k,f];  Mc[p0] = sum_f c0[f] W_emb Wr0
__global__ __launch_bounds__(256) void tmc_kernel(const float* __restrict__ D,
                                                  const float* __restrict__ c0,
                                                  const float* __restrict__ W_emb,
                                                  const float* __restrict__ Wr0,
                                                  float* __restrict__ T,
                                                  float* __restrict__ Mc) {
    for (int i = threadIdx.x; i < 720; i += 256) {
        if (i < 640) {
            int kp = i / 80;
            int p0 = i - kp * 80;
            int k = p0 / 10, a = p0 - k * 10;
            float s = 0.f;
            for (int f = 0; f < FF; f++)
                s += D[kp * FF + f] * W_emb[a * FF + f] * Wr0[k * FF + f];
            T[i] = s;
        } else {
            int p0 = i - 640;
            int k = p0 / 10, a = p0 - k * 10;
            float s = 0.f;
            for (int f = 0; f < FF; f++)
                s += c0[f] * W_emb[a * FF + f] * Wr0[k * FF + f];
            Mc[p0] = s;
        }
    }
}

// -------------------- P0: lane-parallel edges (8 edges x 8 k per wave iteration) ------
// P0[n, p=a*8+k] = sum_{slots j of n} attrs[snd_j, a] * ebs0[j, k]

#define P0_BLOCKS 2048
__global__ __launch_bounds__(256) void p0_kernel(const float* __restrict__ rec,
                                                 const float* __restrict__ ebs0,
                                                 const int* __restrict__ off,
                                                 const float* __restrict__ attrs,
                                                 float* __restrict__ P0) {
    int wv = (blockIdx.x * 256 + threadIdx.x) >> 6;
    int lane = threadIdx.x & 63;
    int nwaves = P0_BLOCKS * 4;
    int jsub = lane >> 3;   // which of 8 edges this lane covers
    int k_l = lane & 7;     // which bessel component

    for (int n = wv; n < NN; n += nwaves) {
        int beg = off[n], end = off[n + 1];
        float acc[10];
#pragma unroll
        for (int a = 0; a < 10; a++) acc[a] = 0.f;
        for (int i = beg; i < end; i += 8) {
            int j = i + jsub;
            bool v = (j < end);
            int jc = v ? j : beg;
            float es = ebs0[(size_t)jc * 8 + k_l];   // coalesced 256B per wave
            if (!v) es = 0.f;
            int snd = __float_as_int(rec[(size_t)jc * RECW + 6]);
            const float* at = attrs + (size_t)snd * 10;
#pragma unroll
            for (int a = 0; a < 10; a++) acc[a] += at[a] * es;
        }
        // reduce across the 8 jsub groups (k stays within lanes k, k+8, ..., k+56)
#pragma unroll
        for (int a = 0; a < 10; a++) {
            acc[a] += __shfl_xor(acc[a], 8);
            acc[a] += __shfl_xor(acc[a], 16);
            acc[a] += __shfl_xor(acc[a], 32);
        }
        if (jsub == 0) {
#pragma unroll
            for (int a = 0; a < 10; a++)
                P0[(size_t)n * 80 + a * 8 + k_l] = acc[a];
        }
    }
}

// -------------------- h1 GEMM: h1 = P0 @ GW + attrs @ Wskip0 ; node_e = h1.wread0 ------

#define GEMM_BLOCKS 512
__global__ __launch_bounds__(256, 2) void h1_gemm(const float* __restrict__ P0,
                                                  const float* __restrict__ GW,
                                                  const float* __restrict__ attrs,
                                                  const float* __restrict__ Wskip,
                                                  const float* __restrict__ wread,
                                                  float* __restrict__ h1,
                                                  float* __restrict__ node_e) {
    __shared__ float sb[80][FF];   // 40 KB
    __shared__ float sa[32][80];   // 10 KB
    int t = threadIdx.x;
#pragma unroll
    for (int j = 0; j < 10; j++) {
        int flat4 = j * 256 + t;
        int row = flat4 >> 5;
        int col = (flat4 & 31) * 4;
        *(float4*)&sb[row][col] = *(const float4*)&GW[row * FF + col];
    }

    int g = t >> 5;
    int f0 = (t & 31) * 4;
    const int NTILES = (NN + 31) / 32;

    for (int tile = blockIdx.x; tile < NTILES; tile += GEMM_BLOCKS) {
        __syncthreads();
#pragma unroll
        for (int j = 0; j < 3; j++) {
            int flat4 = j * 256 + t;
            if (flat4 < 640) {
                int row = flat4 / 20;
                int col = (flat4 - row * 20) * 4;
                int n = tile * 32 + row;
                float4 v = make_float4(0.f, 0.f, 0.f, 0.f);
                if (n < NN) v = *(const float4*)&P0[(size_t)n * 80 + col];
                *(float4*)&sa[row][col] = v;
            }
        }
        __syncthreads();

        float acc[4][4];
#pragma unroll
        for (int i = 0; i < 4; i++)
#pragma unroll
            for (int j = 0; j < 4; j++) acc[i][j] = 0.f;

        for (int kk = 0; kk < 80; kk += 4) {
            float4 bv0 = *(const float4*)&sb[kk + 0][f0];
            float4 bv1 = *(const float4*)&sb[kk + 1][f0];
            float4 bv2 = *(const float4*)&sb[kk + 2][f0];
            float4 bv3 = *(const float4*)&sb[kk + 3][f0];
#pragma unroll
            for (int ni = 0; ni < 4; ni++) {
                float4 av = *(const float4*)&sa[g * 4 + ni][kk];
                acc[ni][0] += av.x * bv0.x + av.y * bv1.x + av.z * bv2.x + av.w * bv3.x;
                acc[ni][1] += av.x * bv0.y + av.y * bv1.y + av.z * bv2.y + av.w * bv3.y;
                acc[ni][2] += av.x * bv0.z + av.y * bv1.z + av.z * bv2.z + av.w * bv3.z;
                acc[ni][3] += av.x * bv0.w + av.y * bv1.w + av.z * bv2.w + av.w * bv3.w;
            }
        }

#pragma unroll
        for (int ni = 0; ni < 4; ni++) {
            int n = tile * 32 + g * 4 + ni;
            bool valid = (n < NN);
#pragma unroll
            for (int a = 0; a < 10; a++) {
                float att = valid ? attrs[n * 10 + a] : 0.f;
                float4 wk = *(const float4*)&Wskip[a * FF + f0];
                acc[ni][0] += att * wk.x;
                acc[ni][1] += att * wk.y;
                acc[ni][2] += att * wk.z;
                acc[ni][3] += att * wk.w;
            }
            if (valid) {
                float4 out;
                out.x = acc[ni][0]; out.y = acc[ni][1];
                out.z = acc[ni][2]; out.w = acc[ni][3];
                *(float4*)&h1[(size_t)n * FF + f0] = out;
            }
            float4 wv = *(const float4*)&wread[f0];
            float p = acc[ni][0] * wv.x + acc[ni][1] * wv.y
                    + acc[ni][2] * wv.z + acc[ni][3] * wv.w;
#pragma unroll
            for (int o = 16; o > 0; o >>= 1) p += __shfl_xor(p, o);
            if (valid && (t & 31) == 0) node_e[n] = p;
        }
    }
}

// -------------------- t1[n,k] = sum_f a1[f] h1[n,f] Wr1[k,f] --------------------

__global__ __launch_bounds__(256) void t1_kernel(const float* __restrict__ h1,
                                                 const float* __restrict__ a1,
                                                 const float* __restrict__ Wr1,
                                                 float* __restrict__ t1) {
    int w = threadIdx.x >> 6;
    int lane = threadIdx.x & 63;
    int n = blockIdx.x * 4 + w;
    if (n >= NN) return;
    int f0 = lane, f1 = lane + 64;
    float v0 = a1[f0] * h1[(size_t)n * FF + f0];
    float v1 = a1[f1] * h1[(size_t)n * FF + f1];
    float p[NBES];
#pragma unroll
    for (int k = 0; k < NBES; k++)
        p[k] = v0 * Wr1[k * FF + f0] + v1 * Wr1[k * FF + f1];
#pragma unroll
    for (int o = 32; o > 0; o >>= 1) {
#pragma unroll
        for (int k = 0; k < NBES; k++) p[k] += __shfl_xor(p[k], o);
    }
    if (lane == 0) {
        *(float4*)&t1[(size_t)n * 8]     = make_float4(p[0], p[1], p[2], p[3]);
        *(float4*)&t1[(size_t)n * 8 + 4] = make_float4(p[4], p[5], p[6], p[7]);
    }
}

// -------------------- M[n][p0=k*10+a] = Mc + sum_k' E1[n,k'] T[k'][p0] ----------------

__global__ __launch_bounds__(256) void m_kernel(const float* __restrict__ E1,
                                                const float* __restrict__ T,
                                                const float* __restrict__ Mc,
                                                float* __restrict__ M) {
    __shared__ float sT[720];
    int t = threadIdx.x;
    for (int i = t; i < 720; i += 256) sT[i] = (i < 640) ? T[i] : Mc[i - 640];
    __syncthreads();
    int n = blockIdx.x * 256 + t;
    if (n >= NN) return;
    float4 ea = *(const float4*)&E1[(size_t)n * 8];
    float4 eb = *(const float4*)&E1[(size_t)n * 8 + 4];
    float e1v[8] = {ea.x, ea.y, ea.z, ea.w, eb.x, eb.y, eb.z, eb.w};
#pragma unroll
    for (int c = 0; c < 20; c++) {
        float4 m = *(const float4*)&sT[640 + c * 4];
#pragma unroll
        for (int kp = 0; kp < 8; kp++) {
            float4 tv = *(const float4*)&sT[kp * 80 + c * 4];
            m.x += e1v[kp] * tv.x;
            m.y += e1v[kp] * tv.y;
            m.z += e1v[kp] * tv.z;
            m.w += e1v[kp] * tv.w;
        }
        *(float4*)&M[(size_t)n * 80 + c * 4] = m;
    }
}

// -------------------- fused per-edge pass: recompute radial, dsp/drp, energy1, gv -----

#define EP_BLOCKS 512
__global__ __launch_bounds__(256) void edge_pass(const float* __restrict__ rec,
                                                 const float* __restrict__ t1,
                                                 const float* __restrict__ M,
                                                 const float* __restrict__ attrs,
                                                 const int* __restrict__ batch,
                                                 const float* __restrict__ wsh,
                                                 float4* __restrict__ gvp,
                                                 float* __restrict__ energy) {
    __shared__ float eacc[GG];
    int t = threadIdx.x;
    int lane = t & 63;
    if (t < GG) eacc[t] = 0.f;
    __syncthreads();

    for (int j0 = blockIdx.x * 256; j0 < EE; j0 += EP_BLOCKS * 256) {
        int j = j0 + t;
        bool act = (j < EE);
        int jc = act ? j : 0;
        const float* rc = rec + (size_t)jc * RECW;
        float4 q0 = *(const float4*)&rc[0];
        float4 q1 = *(const float4*)&rc[4];
        float x = q0.x, y = q0.y, z = q0.z, ivr = q0.w;
        float s0 = q1.x, s1v = q1.y;
        int snd = __float_as_int(q1.z);
        int rcv = __float_as_int(q1.w);

        // recompute radial eb/db
        float r = 1.0f / ivr;
        float u = r * (1.0f / RMAXF);
        float th = PI_F * u;
        float s1 = sinf(th), c1 = cosf(th);
        float u2 = u * u, u3 = u2 * u, u5 = u2 * u3, u6 = u3 * u3, u7 = u6 * u, u8 = u6 * u2;
        float valid = (r < RMAXF) ? 1.f : 0.f;
        float env = (1.f - 28.f * u6 + 48.f * u7 - 21.f * u8) * valid;
        float denv = (-168.f * u5 + 336.f * u6 - 168.f * u7) * (1.0f / RMAXF) * valid;
        float eb[NBES], db[NBES];
        {
            float sk = s1, skm = 0.f, ck = c1, ckm = 1.f;
            float tc = 2.f * c1;
#pragma unroll
            for (int k = 1; k <= NBES; k++) {
                float b = CCB * sk * ivr;
                eb[k - 1] = b * env;
                db[k - 1] = CCB * (((float)k * PI_F * (1.0f / RMAXF)) * ck * ivr
                                   - sk * ivr * ivr) * env
                            + b * denv;
                float sn = tc * sk - skm; skm = sk; sk = sn;
                float cn = tc * ck - ckm; ckm = ck; ck = cn;
            }
        }

        // layer 1: dsp1/drp1 via t1[snd]
        float4 ta = *(const float4*)&t1[(size_t)snd * 8];
        float4 tb = *(const float4*)&t1[(size_t)snd * 8 + 4];
        float tg[8] = {ta.x, ta.y, ta.z, ta.w, tb.x, tb.y, tb.z, tb.w};
        float dsp1 = 0.f, drp1 = 0.f;
#pragma unroll
        for (int k = 0; k < 8; k++) {
            dsp1 += eb[k] * tg[k];
            drp1 += db[k] * tg[k];
        }

        // layer 0: t0[k] = sum_a attrs[snd,a] M[rcv,k,a]
        float at[10];
#pragma unroll
        for (int i = 0; i < 5; i++) {
            float2 v = *(const float2*)&attrs[snd * 10 + 2 * i];
            at[2 * i] = v.x; at[2 * i + 1] = v.y;
        }
        const float* Mr = M + (size_t)rcv * 80;
        float dsp0 = 0.f, drp0 = 0.f;
#pragma unroll
        for (int k = 0; k < 8; k++) {
            float t0 = 0.f;
#pragma unroll
            for (int a = 0; a < 10; a++) t0 += at[a] * Mr[k * 10 + a];
            dsp0 += eb[k] * t0;
            drp0 += db[k] * t0;
        }

        // layer-1 energy contribution: s1 * dsp1, grouped by batch[rcv]
        float el = act ? s1v * dsp1 : 0.f;
        int b = act ? batch[rcv] : -1;
        int ub = __builtin_amdgcn_readfirstlane(b);
        if (__all(b == ub)) {
            float es = el;
#pragma unroll
            for (int o = 32; o > 0; o >>= 1) es += __shfl_xor(es, o);
            if (lane == 0 && ub >= 0) atomicAdd(&eacc[ub], es);
        } else {
            if (act) atomicAdd(&eacc[b], el);
        }

        // per-edge force vector (coalesced write)
        float g0x, g0y, g0z, g1x, g1y, g1z;
        shc_grad(x, y, z, wsh, g0x, g0y, g0z);
        shc_grad(x, y, z, wsh + 16, g1x, g1y, g1z);
        float gux = dsp0 * g0x + dsp1 * g1x;
        float guy = dsp0 * g0y + dsp1 * g1y;
        float guz = dsp0 * g0z + dsp1 * g1z;
        float gr = s0 * drp0 + s1v * drp1;
        float dgu = gux * x + guy * y + guz * z;
        float gvx = gr * x + ivr * (gux - dgu * x);
        float gvy = gr * y + ivr * (guy - dgu * y);
        float gvz = gr * z + ivr * (guz - dgu * z);
        if (act) gvp[j] = make_float4(gvx, gvy, gvz, 0.f);
    }
    __syncthreads();
    if (t < GG && eacc[t] != 0.f) atomicAdd(&energy[t], eacc[t]);
}

// -------------------- force gather (thread-per-node, no atomics) ----------------------

__global__ __launch_bounds__(256) void force_gather(const int* __restrict__ off_rcv,
                                                    const int* __restrict__ off_snd,
                                                    const int* __restrict__ psl_j,
                                                    const float4* __restrict__ gvp,
                                                    float* __restrict__ forces) {
    int n = blockIdx.x * 256 + threadIdx.x;
    if (n >= NN) return;
    float fx = 0.f, fy = 0.f, fz = 0.f;
    int beg = off_rcv[n], end = off_rcv[n + 1];
    for (int j = beg; j < end; j++) {
        float4 g = gvp[j];
        fx -= g.x; fy -= g.y; fz -= g.z;
    }
    beg = off_snd[n]; end = off_snd[n + 1];
    for (int s = beg; s < end; s++) {
        float4 g = gvp[psl_j[s]];
        fx += g.x; fy += g.y; fz += g.z;
    }
    forces[n * 3 + 0] = fx;
    forces[n * 3 + 1] = fy;
    forces[n * 3 + 2] = fz;
}

// -------------------- energy finalize: node_e + attrs.askip --------------------

#define EF_BLOCKS 128
__global__ __launch_bounds__(256) void efinal_kernel(const float* __restrict__ node_e,
                                                     const float* __restrict__ attrs,
                                                     const float* __restrict__ askip,
                                                     const int* __restrict__ batch,
                                                     float* __restrict__ energy) {
    __shared__ float eacc[GG];
    int t = threadIdx.x;
    if (t < GG) eacc[t] = 0.f;
    __syncthreads();
    for (int n = blockIdx.x * 256 + t; n < NN; n += EF_BLOCKS * 256) {
        float v = node_e[n];
#pragma unroll
        for (int a = 0; a < 10; a++) v += attrs[n * 10 + a] * askip[a];
        atomicAdd(&eacc[batch[n]], v);
    }
    __syncthreads();
    if (t < GG && eacc[t] != 0.f) atomicAdd(&energy[t], eacc[t]);
}

// -------------------- launch --------------------

extern "C" void kernel_launch(void* const* d_in, const int* in_sizes, int n_in,
                              void* d_out, int out_size, void* d_ws, size_t ws_size,
                              hipStream_t stream) {
    const float* pos    = (const float*)d_in[0];
    const float* attrs  = (const float*)d_in[1];
    const float* shifts = (const float*)d_in[2];
    const int*   ei     = (const int*)d_in[3];
    const int*   batch  = (const int*)d_in[4];
    const float* W_emb  = (const float*)d_in[6];
    const float* ae     = (const float*)d_in[7];
    const float* W_r    = (const float*)d_in[8];   // (2,8,F)
    const float* w_sh   = (const float*)d_in[9];   // (2,16)
    const float* W_out  = (const float*)d_in[10];  // (2,F,F)
    const float* W_skip = (const float*)d_in[11];  // (2,10,F)
    const float* w_read = (const float*)d_in[12];  // (2,F)

    const float* Wr0 = W_r;
    const float* Wr1 = W_r + NBES * FF;
    const float* Wout0 = W_out;
    const float* Wout1 = W_out + FF * FF;

    float* energy = (float*)d_out;
    float* forces = energy + GG;

    float* ws  = (float*)d_ws;
    float* h1  = ws;                        // N*F
    float* P0  = h1 + (size_t)NN * FF;      // N*80
    float* M   = P0 + (size_t)NN * 80;      // N*80
    float* E1  = M + (size_t)NN * 80;       // N*8
    float* t1  = E1 + (size_t)NN * 8;       // N*8
    float* node_e = t1 + (size_t)NN * 8;    // N
    float* rec = node_e + NN;               // EE*8
    float* ebs0 = rec + (size_t)EE * RECW;  // EE*8
    float* ebs1 = ebs0 + (size_t)EE * 8;    // EE*8
    float4* gvp = (float4*)(ebs1 + (size_t)EE * 8);  // EE*4 floats
    float* a1  = (float*)(gvp + EE);        // 128
    float* askip = a1 + FF;                 // 16
    float* c0  = askip + 16;                // 128
    float* D   = c0 + FF;                   // 8*128
    float* GW  = D + NBES * FF;             // 80*128
    float* T   = GW + 80 * FF;              // 640
    float* Mc  = T + 640;                   // 80

    int* cnt    = (int*)(Mc + 80);          // 2N
    int* off    = cnt + 2 * NN;             // 2(N+1)
    int* rank_r = off + 2 * (NN + 1);       // EE
    int* rank_s = rank_r + EE;              // EE
    int* jr     = rank_s + EE;              // EE
    int* js     = jr + EE;                  // EE
    int* psl_j  = js + EE;                  // EE
    int* parts  = psl_j + EE;               // 2*NB
    const int* off_rcv = off;
    const int* off_snd = off + (NN + 1);

    const int edgeBlocks = (EE + 255) / 256;
    const int nodeBlocks = (NN + 255) / 256;

    hipMemsetAsync(d_out, 0, (size_t)out_size * sizeof(float), stream);
    hipMemsetAsync(cnt, 0, (size_t)2 * NN * sizeof(int), stream);

    // CSR build: atomics only in count (rank capture); parallel 3-phase scan
    count_kernel<<<edgeBlocks, 256, 0, stream>>>(ei, cnt, rank_r, rank_s);
    scan_partial<<<2 * NB, 256, 0, stream>>>(cnt, parts);
    scan_parts<<<1, 256, 0, stream>>>(parts, off);
    scan_apply<<<2 * NB, 256, 0, stream>>>(cnt, parts, off);
    fill_kernel<<<edgeBlocks, 256, 0, stream>>>(ei, off, rank_r, rank_s, jr, js, psl_j);

    // small precomputes
    a1_kernel<<<1, 128, 0, stream>>>(Wout1, w_read + FF, W_skip + 10 * FF, ae, a1, askip);
    cd_kernel<<<1, 128, 0, stream>>>(Wout0, w_read, a1, Wr1, c0, D);
    gw_kernel<<<40, 256, 0, stream>>>(W_emb, Wr0, Wout0, GW);
    tmc_kernel<<<1, 256, 0, stream>>>(D, c0, W_emb, Wr0, T, Mc);

    // geometry records + eb*s0 (rcv order) + eb*s1 (snd order)
    edge_geom<<<edgeBlocks, 256, 0, stream>>>(pos, shifts, ei, w_sh, jr, js,
                                              rec, ebs0, ebs1);

    // E1: contiguous stream over ebs1 (no atomics, no transcendentals)
    e1_csr<<<(NN * 8 + 255) / 256, 256, 0, stream>>>(ebs1, off_snd, E1);

    // P0 (lane-parallel edges), then h1, t1, M
    p0_kernel<<<P0_BLOCKS, 256, 0, stream>>>(rec, ebs0, off_rcv, attrs, P0);
    h1_gemm<<<GEMM_BLOCKS, 256, 0, stream>>>(P0, GW, attrs, W_skip, w_read, h1, node_e);
    t1_kernel<<<(NN + 3) / 4, 256, 0, stream>>>(h1, a1, Wr1, t1);
    m_kernel<<<nodeBlocks, 256, 0, stream>>>(E1, T, Mc, M);

    // fused per-edge: recompute radial, dsp/drp both layers, layer-1 energy, gv
    edge_pass<<<EP_BLOCKS, 256, 0, stream>>>(rec, t1, M, attrs, batch, w_sh, gvp, energy);

    // forces via CSR gather (no atomics)
    force_gather<<<nodeBlocks, 256, 0, stream>>>(off_rcv, off_snd, psl_j, gvp, forces);

    // energy finalize (layer-0 node energies + layer-1 skip + e0)
    efinal_kernel<<<EF_BLOCKS, 256, 0, stream>>>(node_e, attrs, askip, batch, energy);
}

// Round 16
// 336.059 us; speedup vs baseline: 3.1376x; 1.0494x over previous
//
#include <hip/hip_runtime.h>

#define NN 50000
#define EE 800000
#define GG 64
#define FF 128
#define NBES 8
#define RECW 8    // compact record: x, y, z, inv_r, s0, s1, snd, rcv  (32 B)
#define RMAXF 5.0f
#define PI_F 3.14159265358979323846f
#define NB ((NN + 255) / 256)   // 196 chunks per half
#define CSTR 8    // counter stride: one counter per 32B sector

// spherical harmonic constants
#define S3  1.7320508075688772f
#define S5  2.23606797749979f
#define S15 3.872983346207417f
#define C1c 2.091650066335189f   // sqrt(35/8)
#define C2c 10.246950765959598f  // sqrt(105)
#define C3c 1.62018517460196f    // sqrt(21/8)
#define C4c 1.3228756555322954f  // sqrt(7)/2
#define C5c 5.123475382979799f   // sqrt(105)/2
#define CCB 0.6324555320336759f  // sqrt(2/5)

__device__ __forceinline__ float shc_s(float x, float y, float z, const float* __restrict__ w) {
    float x2 = x * x, y2 = y * y, z2 = z * z;
    return w[0]
        + w[1] * (S3 * x) + w[2] * (S3 * y) + w[3] * (S3 * z)
        + w[4] * (S15 * x * y) + w[5] * (S15 * y * z) + w[6] * (0.5f * S5 * (3.f * z2 - 1.f))
        + w[7] * (S15 * x * z) + w[8] * (0.5f * S15 * (x2 - y2))
        + w[9] * (C1c * y * (3.f * x2 - y2)) + w[10] * (C2c * x * y * z)
        + w[11] * (C3c * y * (5.f * z2 - 1.f)) + w[12] * (C4c * z * (5.f * z2 - 3.f))
        + w[13] * (C3c * x * (5.f * z2 - 1.f)) + w[14] * (C5c * z * (x2 - y2))
        + w[15] * (C1c * x * (x2 - 3.f * y2));
}

__device__ __forceinline__ void shc_grad(float x, float y, float z, const float* __restrict__ w,
                                         float& gx, float& gy, float& gz) {
    float x2 = x * x, y2 = y * y, z2 = z * z;
    gx = w[1] * S3 + w[4] * (S15 * y) + w[7] * (S15 * z) + w[8] * (S15 * x)
       + w[9] * (6.f * C1c * x * y) + w[10] * (C2c * y * z) + w[13] * (C3c * (5.f * z2 - 1.f))
       + w[14] * (2.f * C5c * x * z) + w[15] * (3.f * C1c * (x2 - y2));
    gy = w[2] * S3 + w[4] * (S15 * x) + w[5] * (S15 * z) - w[8] * (S15 * y)
       + w[9] * (3.f * C1c * (x2 - y2)) + w[10] * (C2c * x * z) + w[11] * (C3c * (5.f * z2 - 1.f))
       - w[14] * (2.f * C5c * y * z) - w[15] * (6.f * C1c * x * y);
    gz = w[3] * S3 + w[5] * (S15 * y) + w[6] * (3.f * S5 * z) + w[7] * (S15 * x)
       + w[10] * (C2c * x * y) + w[11] * (10.f * C3c * y * z) + w[12] * (C4c * (15.f * z2 - 3.f))
       + w[13] * (10.f * C3c * x * z) + w[14] * (C5c * (x2 - y2));
}

// -------------------- CSR build --------------------

// ranks via atomic return; counters padded to one per 32B sector
__global__ __launch_bounds__(256) void count_kernel(const int* __restrict__ ei,
                                                    int* __restrict__ cnt,
                                                    int* __restrict__ rank_r,
                                                    int* __restrict__ rank_s) {
    int e = blockIdx.x * 256 + threadIdx.x;
    if (e >= EE) return;
    rank_r[e] = atomicAdd(&cnt[(size_t)ei[EE + e] * CSTR], 1);
    rank_s[e] = atomicAdd(&cnt[(size_t)(NN + ei[e]) * CSTR], 1);
}

// phase A: per-256-chunk block sums (grid = 2*NB)
__global__ __launch_bounds__(256) void scan_partial(const int* __restrict__ cnt,
                                                    int* __restrict__ parts) {
    __shared__ int wsum[4];
    int b = blockIdx.x;
    int half = b / NB;
    int cb = b - half * NB;
    int i = cb * 256 + threadIdx.x;
    int v = (i < NN) ? cnt[(size_t)(half * NN + i) * CSTR] : 0;
    int x = v;
#pragma unroll
    for (int o = 32; o > 0; o >>= 1) x += __shfl_xor(x, o);
    int lane = threadIdx.x & 63, wid = threadIdx.x >> 6;
    if (lane == 0) wsum[wid] = x;
    __syncthreads();
    if (threadIdx.x == 0) parts[b] = wsum[0] + wsum[1] + wsum[2] + wsum[3];
}

// phase B: exclusive scan of the NB block sums per half (in place); writes totals
__global__ __launch_bounds__(256) void scan_parts(int* __restrict__ parts,
                                                  int* __restrict__ off) {
    __shared__ int wsum[4];
    __shared__ int carry_s;
    int lane = threadIdx.x & 63, wid = threadIdx.x >> 6;
    for (int h = 0; h < 2; h++) {
        if (threadIdx.x == 0) carry_s = 0;
        __syncthreads();
        for (int base = 0; base < NB; base += 256) {
            int i = base + threadIdx.x;
            int v = (i < NB) ? parts[h * NB + i] : 0;
            int x = v;
#pragma unroll
            for (int d = 1; d < 64; d <<= 1) {
                int y = __shfl_up(x, d);
                if (lane >= d) x += y;
            }
            if (lane == 63) wsum[wid] = x;
            __syncthreads();
            int pre = 0;
#pragma unroll
            for (int w = 0; w < 4; w++) if (w < wid) pre += wsum[w];
            int total = wsum[0] + wsum[1] + wsum[2] + wsum[3];
            int carry = carry_s;
            if (i < NB) parts[h * NB + i] = carry + pre + x - v;   // exclusive
            __syncthreads();
            if (threadIdx.x == 0) carry_s = carry + total;
            __syncthreads();
        }
        if (threadIdx.x == 0) off[(size_t)h * (NN + 1) + NN] = carry_s;
        __syncthreads();
    }
}

// phase C: within-chunk exclusive scan + block prefix (grid = 2*NB)
__global__ __launch_bounds__(256) void scan_apply(const int* __restrict__ cnt,
                                                  const int* __restrict__ parts,
                                                  int* __restrict__ off) {
    __shared__ int wsum[4];
    int b = blockIdx.x;
    int half = b / NB;
    int cb = b - half * NB;
    int i = cb * 256 + threadIdx.x;
    int v = (i < NN) ? cnt[(size_t)(half * NN + i) * CSTR] : 0;
    int lane = threadIdx.x & 63, wid = threadIdx.x >> 6;
    int x = v;
#pragma unroll
    for (int d = 1; d < 64; d <<= 1) {
        int y = __shfl_up(x, d);
        if (lane >= d) x += y;
    }
    if (lane == 63) wsum[wid] = x;
    __syncthreads();
    int pre = 0;
#pragma unroll
    for (int w = 0; w < 4; w++) if (w < wid) pre += wsum[w];
    if (i < NN) off[(size_t)half * (NN + 1) + i] = parts[b] + pre + x - v;
}

// jr[e] = rcv-slot; js[e] = snd-slot (both coalesced); psl_j[snd-slot] = rcv-slot
__global__ __launch_bounds__(256) void fill_kernel(const int* __restrict__ ei,
                                                   const int* __restrict__ off,
                                                   const int* __restrict__ rank_r,
                                                   const int* __restrict__ rank_s,
                                                   int* __restrict__ jr,
                                                   int* __restrict__ js,
                                                   int* __restrict__ psl_j) {
    int e = blockIdx.x * 256 + threadIdx.x;
    if (e >= EE) return;
    int snd = ei[e], rcv = ei[EE + e];
    int sr = off[rcv] + rank_r[e];
    int ss = off[(NN + 1) + snd] + rank_s[e];
    jr[e] = sr;
    js[e] = ss;
    psl_j[ss] = sr;
}

// -------------------- geometry: thread = edge; rec (rcv order) + ebs1 (snd order) -----

__global__ __launch_bounds__(256) void edge_geom(const float* __restrict__ pos,
                                                 const float* __restrict__ shifts,
                                                 const int* __restrict__ ei,
                                                 const float* __restrict__ wsh,
                                                 const int* __restrict__ jr,
                                                 const int* __restrict__ js,
                                                 float* __restrict__ rec,
                                                 float* __restrict__ ebs1) {
    int e = blockIdx.x * 256 + threadIdx.x;
    if (e >= EE) return;
    int snd = ei[e];
    int rcv = ei[EE + e];
    float vx = pos[rcv * 3 + 0] - pos[snd * 3 + 0] + shifts[e * 3 + 0];
    float vy = pos[rcv * 3 + 1] - pos[snd * 3 + 1] + shifts[e * 3 + 1];
    float vz = pos[rcv * 3 + 2] - pos[snd * 3 + 2] + shifts[e * 3 + 2];
    float r2 = vx * vx + vy * vy + vz * vz + 1e-12f;
    float r = sqrtf(r2);
    float inv_r = 1.0f / r;
    float x = vx * inv_r, y = vy * inv_r, z = vz * inv_r;

    float s0 = shc_s(x, y, z, wsh);
    float s1v = shc_s(x, y, z, wsh + 16);

    float* rc = rec + (size_t)jr[e] * RECW;
    *(float4*)&rc[0] = make_float4(x, y, z, inv_r);
    *(float4*)&rc[4] = make_float4(s0, s1v, __int_as_float(snd), __int_as_float(rcv));

    // radial eb[k] once per edge -> ebs1 = eb * s1 (snd-slot order)
    float u = r * (1.0f / RMAXF);
    float th = PI_F * u;
    float s1 = sinf(th), c1 = cosf(th);
    float u2 = u * u, u3 = u2 * u, u6 = u3 * u3, u7 = u6 * u, u8 = u6 * u2;
    float valid = (r < RMAXF) ? 1.f : 0.f;
    float env = (1.f - 28.f * u6 + 48.f * u7 - 21.f * u8) * valid;
    float base = CCB * inv_r * env * s1v;
    float ebv[NBES];
    {
        float sk = s1, skm = 0.f;
        float tc = 2.f * c1;
#pragma unroll
        for (int k = 0; k < NBES; k++) {
            ebv[k] = sk * base;
            float sn = tc * sk - skm; skm = sk; sk = sn;
        }
    }
    float* p1p = ebs1 + (size_t)js[e] * 8;
    *(float4*)&p1p[0] = make_float4(ebv[0], ebv[1], ebv[2], ebv[3]);
    *(float4*)&p1p[4] = make_float4(ebv[4], ebv[5], ebv[6], ebv[7]);
}

// -------------------- E1: contiguous stream over snd-ordered ebs1 ---------------------

__global__ __launch_bounds__(256) void e1_csr(const float* __restrict__ ebs1,
                                              const int* __restrict__ off_snd,
                                              float* __restrict__ E1) {
    int gid = blockIdx.x * 256 + threadIdx.x;
    int n = gid >> 3;
    int k_l = gid & 7;
    if (n >= NN) return;
    int beg = off_snd[n], end = off_snd[n + 1];
    float acc = 0.f;
    for (int s = beg; s < end; s++) acc += ebs1[(size_t)s * 8 + k_l];
    E1[(size_t)n * 8 + k_l] = acc;
}

// -------------------- small precomputes --------------------

__global__ __launch_bounds__(128) void a1_kernel(const float* __restrict__ Wout1,
                                                 const float* __restrict__ wread1,
                                                 const float* __restrict__ Wskip1,
                                                 const float* __restrict__ ae,
                                                 float* __restrict__ a1,
                                                 float* __restrict__ askip) {
    int f = threadIdx.x;
    float s = 0.f;
    for (int k = 0; k < FF; k++) s += Wout1[f * FF + k] * wread1[k];
    a1[f] = s;
    if (f < 10) {
        float t = 0.f;
        for (int k = 0; k < FF; k++) t += Wskip1[f * FF + k] * wread1[k];
        askip[f] = t + ae[f];
    }
}

// c0[f'] = sum_f wread0[f] Wout0[f',f];  D[k,f'] = sum_f a1[f] Wr1[k,f] Wout0[f',f]
__global__ __launch_bounds__(128) void cd_kernel(const float* __restrict__ Wout0,
                                                 const float* __restrict__ wread0,
                                                 const float* __restrict__ a1,
                                                 const float* __restrict__ Wr1,
                                                 float* __restrict__ c0,
                                                 float* __restrict__ D) {
    int fp = threadIdx.x;
    float c = 0.f;
    float d[NBES];
#pragma unroll
    for (int k = 0; k < NBES; k++) d[k] = 0.f;
    for (int f = 0; f < FF; f++) {
        float w = Wout0[fp * FF + f];
        c += wread0[f] * w;
        float aw = a1[f] * w;
#pragma unroll
        for (int k = 0; k < NBES; k++) d[k] += aw * Wr1[k * FF + f];
    }
    c0[fp] = c;
#pragma unroll
    for (int k = 0; k < NBES; k++) D[k * FF + fp] = d[k];
}

// GW[p=a*8+k][f'] = sum_f W_emb[a,f] Wr0[k,f] Wout0[f,f']
__global__ __launch_bounds__(256) void gw_kernel(const float* __restrict__ W_emb,
                                                 const float* __restrict__ Wr0,
                                                 const float* __restrict__ Wout0,
                                                 float* __restrict__ GW) {
    int idx = blockIdx.x * 256 + threadIdx.x;
    if (idx >= 80 * FF) return;
    int fp = idx & 127;
    int p = idx >> 7;
    int a = p >> 3, k = p & 7;
    float s = 0.f;
    for (int f = 0; f < FF; f++)
        s += W_emb[a * FF + f] * Wr0[k * FF + f] * Wout0[f * FF + fp];
    GW[p * FF + fp] = s;
}

// T[k'][p0=k*10+a] = sum_f D[k',f] W_emb[a,f] Wr0[k,f];  Mc[p0] = sum_f c0[f] W_emb Wr0
__global__ __launch_bounds__(256) void tmc_kernel(const float* __restrict__ D,
                                                  const float* __restrict__ c0,
                                                  const float* __restrict__ W_emb,
                                                  const float* __restrict__ Wr0,
                                                  float* __restrict__ T,
                                                  float* __restrict__ Mc) {
    for (int i = threadIdx.x; i < 720; i += 256) {
        if (i < 640) {
            int kp = i / 80;
            int p0 = i - kp * 80;
            int k = p0 / 10, a = p0 - k * 10;
            float s = 0.f;
            for (int f = 0; f < FF; f++)
                s += D[kp * FF + f] * W_emb[a * FF + f] * Wr0[k * FF + f];
            T[i] = s;
        } else {
            int p0 = i - 640;
            int k = p0 / 10, a = p0 - k * 10;
            float s = 0.f;
            for (int f = 0; f < FF; f++)
                s += c0[f] * W_emb[a * FF + f] * Wr0[k * FF + f];
            Mc[p0] = s;
        }
    }
}

// -------------------- P0: lane-parallel edges, recompute es from rec ------------------
// P0[n, p=a*8+k] = sum_{slots j of n} attrs[snd_j, a] * eb[j,k] * s0_j

#define P0_BLOCKS 2048
__global__ __launch_bounds__(256) void p0_kernel(const float* __restrict__ rec,
                                                 const int* __restrict__ off,
                                                 const float* __restrict__ attrs,
                                                 float* __restrict__ P0) {
    int wv = (blockIdx.x * 256 + threadIdx.x) >> 6;
    int lane = threadIdx.x & 63;
    int nwaves = P0_BLOCKS * 4;
    int jsub = lane >> 3;   // which of 8 edges this lane covers
    int k_l = lane & 7;     // which bessel component
    float kf = (float)(k_l + 1);

    for (int n = wv; n < NN; n += nwaves) {
        int beg = off[n], end = off[n + 1];
        float acc[10];
#pragma unroll
        for (int a = 0; a < 10; a++) acc[a] = 0.f;
        for (int i = beg; i < end; i += 8) {
            int j = i + jsub;
            bool v = (j < end);
            int jc = v ? j : beg;
            const float* rc = rec + (size_t)jc * RECW;
            float ivr = rc[3];
            float s0 = rc[4];
            int snd = __float_as_int(rc[6]);
            float r = 1.0f / ivr;
            float u = r * (1.0f / RMAXF);
            float th = PI_F * u;
            float u2 = u * u, u3 = u2 * u, u6 = u3 * u3, u7 = u6 * u, u8 = u6 * u2;
            float valid = (r < RMAXF && v) ? 1.f : 0.f;
            float env = (1.f - 28.f * u6 + 48.f * u7 - 21.f * u8) * valid;
            float es = sinf(kf * th) * (CCB * ivr * env) * s0;
            const float* at = attrs + (size_t)snd * 10;
#pragma unroll
            for (int a = 0; a < 10; a++) acc[a] += at[a] * es;
        }
        // reduce across the 8 jsub groups
#pragma unroll
        for (int a = 0; a < 10; a++) {
            acc[a] += __shfl_xor(acc[a], 8);
            acc[a] += __shfl_xor(acc[a], 16);
            acc[a] += __shfl_xor(acc[a], 32);
        }
        if (jsub == 0) {
#pragma unroll
            for (int a = 0; a < 10; a++)
                P0[(size_t)n * 80 + a * 8 + k_l] = acc[a];
        }
    }
}

// -------------------- h1 GEMM: h1 = P0 @ GW + attrs @ Wskip0 ; node_e = h1.wread0 ------

#define GEMM_BLOCKS 512
__global__ __launch_bounds__(256, 2) void h1_gemm(const float* __restrict__ P0,
                                                  const float* __restrict__ GW,
                                                  const float* __restrict__ attrs,
                                                  const float* __restrict__ Wskip,
                                                  const float* __restrict__ wread,
                                                  float* __restrict__ h1,
                                                  float* __restrict__ node_e) {
    __shared__ float sb[80][FF];   // 40 KB
    __shared__ float sa[32][80];   // 10 KB
    int t = threadIdx.x;
#pragma unroll
    for (int j = 0; j < 10; j++) {
        int flat4 = j * 256 + t;
        int row = flat4 >> 5;
        int col = (flat4 & 31) * 4;
        *(float4*)&sb[row][col] = *(const float4*)&GW[row * FF + col];
    }

    int g = t >> 5;
    int f0 = (t & 31) * 4;
    const int NTILES = (NN + 31) / 32;

    for (int tile = blockIdx.x; tile < NTILES; tile += GEMM_BLOCKS) {
        __syncthreads();
#pragma unroll
        for (int j = 0; j < 3; j++) {
            int flat4 = j * 256 + t;
            if (flat4 < 640) {
                int row = flat4 / 20;
                int col = (flat4 - row * 20) * 4;
                int n = tile * 32 + row;
                float4 v = make_float4(0.f, 0.f, 0.f, 0.f);
                if (n < NN) v = *(const float4*)&P0[(size_t)n * 80 + col];
                *(float4*)&sa[row][col] = v;
            }
        }
        __syncthreads();

        float acc[4][4];
#pragma unroll
        for (int i = 0; i < 4; i++)
#pragma unroll
            for (int j = 0; j < 4; j++) acc[i][j] = 0.f;

        for (int kk = 0; kk < 80; kk += 4) {
            float4 bv0 = *(const float4*)&sb[kk + 0][f0];
            float4 bv1 = *(const float4*)&sb[kk + 1][f0];
            float4 bv2 = *(const float4*)&sb[kk + 2][f0];
            float4 bv3 = *(const float4*)&sb[kk + 3][f0];
#pragma unroll
            for (int ni = 0; ni < 4; ni++) {
                float4 av = *(const float4*)&sa[g * 4 + ni][kk];
                acc[ni][0] += av.x * bv0.x + av.y * bv1.x + av.z * bv2.x + av.w * bv3.x;
                acc[ni][1] += av.x * bv0.y + av.y * bv1.y + av.z * bv2.y + av.w * bv3.y;
                acc[ni][2] += av.x * bv0.z + av.y * bv1.z + av.z * bv2.z + av.w * bv3.z;
                acc[ni][3] += av.x * bv0.w + av.y * bv1.w + av.z * bv2.w + av.w * bv3.w;
            }
        }

#pragma unroll
        for (int ni = 0; ni < 4; ni++) {
            int n = tile * 32 + g * 4 + ni;
            bool valid = (n < NN);
#pragma unroll
            for (int a = 0; a < 10; a++) {
                float att = valid ? attrs[n * 10 + a] : 0.f;
                float4 wk = *(const float4*)&Wskip[a * FF + f0];
                acc[ni][0] += att * wk.x;
                acc[ni][1] += att * wk.y;
                acc[ni][2] += att * wk.z;
                acc[ni][3] += att * wk.w;
            }
            if (valid) {
                float4 out;
                out.x = acc[ni][0]; out.y = acc[ni][1];
                out.z = acc[ni][2]; out.w = acc[ni][3];
                *(float4*)&h1[(size_t)n * FF + f0] = out;
            }
            float4 wv = *(const float4*)&wread[f0];
            float p = acc[ni][0] * wv.x + acc[ni][1] * wv.y
                    + acc[ni][2] * wv.z + acc[ni][3] * wv.w;
#pragma unroll
            for (int o = 16; o > 0; o >>= 1) p += __shfl_xor(p, o);
            if (valid && (t & 31) == 0) node_e[n] = p;
        }
    }
}

// -------------------- t1[n,k] = sum_f a1[f] h1[n,f] Wr1[k,f] --------------------

__global__ __launch_bounds__(256) void t1_kernel(const float* __restrict__ h1,
                                                 const float* __restrict__ a1,
                                                 const float* __restrict__ Wr1,
                                                 float* __restrict__ t1) {
    int w = threadIdx.x >> 6;
    int lane = threadIdx.x & 63;
    int n = blockIdx.x * 4 + w;
    if (n >= NN) return;
    int f0 = lane, f1 = lane + 64;
    float v0 = a1[f0] * h1[(size_t)n * FF + f0];
    float v1 = a1[f1] * h1[(size_t)n * FF + f1];
    float p[NBES];
#pragma unroll
    for (int k = 0; k < NBES; k++)
        p[k] = v0 * Wr1[k * FF + f0] + v1 * Wr1[k * FF + f1];
#pragma unroll
    for (int o = 32; o > 0; o >>= 1) {
#pragma unroll
        for (int k = 0; k < NBES; k++) p[k] += __shfl_xor(p[k], o);
    }
    if (lane == 0) {
        *(float4*)&t1[(size_t)n * 8]     = make_float4(p[0], p[1], p[2], p[3]);
        *(float4*)&t1[(size_t)n * 8 + 4] = make_float4(p[4], p[5], p[6], p[7]);
    }
}

// -------------------- M[n][p0=k*10+a] = Mc + sum_k' E1[n,k'] T[k'][p0] ----------------

__global__ __launch_bounds__(256) void m_kernel(const float* __restrict__ E1,
                                                const float* __restrict__ T,
                                                const float* __restrict__ Mc,
                                                float* __restrict__ M) {
    __shared__ float sT[720];
    int t = threadIdx.x;
    for (int i = t; i < 720; i += 256) sT[i] = (i < 640) ? T[i] : Mc[i - 640];
    __syncthreads();
    int n = blockIdx.x * 256 + t;
    if (n >= NN) return;
    float4 ea = *(const float4*)&E1[(size_t)n * 8];
    float4 eb = *(const float4*)&E1[(size_t)n * 8 + 4];
    float e1v[8] = {ea.x, ea.y, ea.z, ea.w, eb.x, eb.y, eb.z, eb.w};
#pragma unroll
    for (int c = 0; c < 20; c++) {
        float4 m = *(const float4*)&sT[640 + c * 4];
#pragma unroll
        for (int kp = 0; kp < 8; kp++) {
            float4 tv = *(const float4*)&sT[kp * 80 + c * 4];
            m.x += e1v[kp] * tv.x;
            m.y += e1v[kp] * tv.y;
            m.z += e1v[kp] * tv.z;
            m.w += e1v[kp] * tv.w;
        }
        *(float4*)&M[(size_t)n * 80 + c * 4] = m;
    }
}

// -------------------- fused per-edge pass: recompute radial, dsp/drp, energy1, gv -----

#define EP_BLOCKS 512
__global__ __launch_bounds__(256) void edge_pass(const float* __restrict__ rec,
                                                 const float* __restrict__ t1,
                                                 const float* __restrict__ M,
                                                 const float* __restrict__ attrs,
                                                 const int* __restrict__ batch,
                                                 const float* __restrict__ wsh,
                                                 float4* __restrict__ gvp,
                                                 float* __restrict__ energy) {
    __shared__ float eacc[GG];
    int t = threadIdx.x;
    int lane = t & 63;
    if (t < GG) eacc[t] = 0.f;
    __syncthreads();

    for (int j0 = blockIdx.x * 256; j0 < EE; j0 += EP_BLOCKS * 256) {
        int j = j0 + t;
        bool act = (j < EE);
        int jc = act ? j : 0;
        const float* rc = rec + (size_t)jc * RECW;
        float4 q0 = *(const float4*)&rc[0];
        float4 q1 = *(const float4*)&rc[4];
        float x = q0.x, y = q0.y, z = q0.z, ivr = q0.w;
        float s0 = q1.x, s1v = q1.y;
        int snd = __float_as_int(q1.z);
        int rcv = __float_as_int(q1.w);

        // recompute radial eb/db
        float r = 1.0f / ivr;
        float u = r * (1.0f / RMAXF);
        float th = PI_F * u;
        float s1 = sinf(th), c1 = cosf(th);
        float u2 = u * u, u3 = u2 * u, u5 = u2 * u3, u6 = u3 * u3, u7 = u6 * u, u8 = u6 * u2;
        float valid = (r < RMAXF) ? 1.f : 0.f;
        float env = (1.f - 28.f * u6 + 48.f * u7 - 21.f * u8) * valid;
        float denv = (-168.f * u5 + 336.f * u6 - 168.f * u7) * (1.0f / RMAXF) * valid;
        float eb[NBES], db[NBES];
        {
            float sk = s1, skm = 0.f, ck = c1, ckm = 1.f;
            float tc = 2.f * c1;
#pragma unroll
            for (int k = 1; k <= NBES; k++) {
                float b = CCB * sk * ivr;
                eb[k - 1] = b * env;
                db[k - 1] = CCB * (((float)k * PI_F * (1.0f / RMAXF)) * ck * ivr
                                   - sk * ivr * ivr) * env
                            + b * denv;
                float sn = tc * sk - skm; skm = sk; sk = sn;
                float cn = tc * ck - ckm; ckm = ck; ck = cn;
            }
        }

        // layer 1: dsp1/drp1 via t1[snd]
        float4 ta = *(const float4*)&t1[(size_t)snd * 8];
        float4 tb = *(const float4*)&t1[(size_t)snd * 8 + 4];
        float tg[8] = {ta.x, ta.y, ta.z, ta.w, tb.x, tb.y, tb.z, tb.w};
        float dsp1 = 0.f, drp1 = 0.f;
#pragma unroll
        for (int k = 0; k < 8; k++) {
            dsp1 += eb[k] * tg[k];
            drp1 += db[k] * tg[k];
        }

        // layer 0: t0[k] = sum_a attrs[snd,a] M[rcv,k,a]
        float at[10];
#pragma unroll
        for (int i = 0; i < 5; i++) {
            float2 v = *(const float2*)&attrs[snd * 10 + 2 * i];
            at[2 * i] = v.x; at[2 * i + 1] = v.y;
        }
        const float* Mr = M + (size_t)rcv * 80;
        float dsp0 = 0.f, drp0 = 0.f;
#pragma unroll
        for (int k = 0; k < 8; k++) {
            float t0 = 0.f;
#pragma unroll
            for (int a = 0; a < 10; a++) t0 += at[a] * Mr[k * 10 + a];
            dsp0 += eb[k] * t0;
            drp0 += db[k] * t0;
        }

        // layer-1 energy contribution: s1 * dsp1, grouped by batch[rcv]
        float el = act ? s1v * dsp1 : 0.f;
        int b = act ? batch[rcv] : -1;
        int ub = __builtin_amdgcn_readfirstlane(b);
        if (__all(b == ub)) {
            float es = el;
#pragma unroll
            for (int o = 32; o > 0; o >>= 1) es += __shfl_xor(es, o);
            if (lane == 0 && ub >= 0) atomicAdd(&eacc[ub], es);
        } else {
            if (act) atomicAdd(&eacc[b], el);
        }

        // per-edge force vector (coalesced write)
        float g0x, g0y, g0z, g1x, g1y, g1z;
        shc_grad(x, y, z, wsh, g0x, g0y, g0z);
        shc_grad(x, y, z, wsh + 16, g1x, g1y, g1z);
        float gux = dsp0 * g0x + dsp1 * g1x;
        float guy = dsp0 * g0y + dsp1 * g1y;
        float guz = dsp0 * g0z + dsp1 * g1z;
        float gr = s0 * drp0 + s1v * drp1;
        float dgu = gux * x + guy * y + guz * z;
        float gvx = gr * x + ivr * (gux - dgu * x);
        float gvy = gr * y + ivr * (guy - dgu * y);
        float gvz = gr * z + ivr * (guz - dgu * z);
        if (act) gvp[j] = make_float4(gvx, gvy, gvz, 0.f);
    }
    __syncthreads();
    if (t < GG && eacc[t] != 0.f) atomicAdd(&energy[t], eacc[t]);
}

// -------------------- force gather (thread-per-node, no atomics) ----------------------

__global__ __launch_bounds__(256) void force_gather(const int* __restrict__ off_rcv,
                                                    const int* __restrict__ off_snd,
                                                    const int* __restrict__ psl_j,
                                                    const float4* __restrict__ gvp,
                                                    float* __restrict__ forces) {
    int n = blockIdx.x * 256 + threadIdx.x;
    if (n >= NN) return;
    float fx = 0.f, fy = 0.f, fz = 0.f;
    int beg = off_rcv[n], end = off_rcv[n + 1];
    for (int j = beg; j < end; j++) {
        float4 g = gvp[j];
        fx -= g.x; fy -= g.y; fz -= g.z;
    }
    beg = off_snd[n]; end = off_snd[n + 1];
    for (int s = beg; s < end; s++) {
        float4 g = gvp[psl_j[s]];
        fx += g.x; fy += g.y; fz += g.z;
    }
    forces[n * 3 + 0] = fx;
    forces[n * 3 + 1] = fy;
    forces[n * 3 + 2] = fz;
}

// -------------------- energy finalize: node_e + attrs.askip --------------------

#define EF_BLOCKS 128
__global__ __launch_bounds__(256) void efinal_kernel(const float* __restrict__ node_e,
                                                     const float* __restrict__ attrs,
                                                     const float* __restrict__ askip,
                                                     const int* __restrict__ batch,
                                                     float* __restrict__ energy) {
    __shared__ float eacc[GG];
    int t = threadIdx.x;
    if (t < GG) eacc[t] = 0.f;
    __syncthreads();
    for (int n = blockIdx.x * 256 + t; n < NN; n += EF_BLOCKS * 256) {
        float v = node_e[n];
#pragma unroll
        for (int a = 0; a < 10; a++) v += attrs[n * 10 + a] * askip[a];
        atomicAdd(&eacc[batch[n]], v);
    }
    __syncthreads();
    if (t < GG && eacc[t] != 0.f) atomicAdd(&energy[t], eacc[t]);
}

// -------------------- launch --------------------

extern "C" void kernel_launch(void* const* d_in, const int* in_sizes, int n_in,
                              void* d_out, int out_size, void* d_ws, size_t ws_size,
                              hipStream_t stream) {
    const float* pos    = (const float*)d_in[0];
    const float* attrs  = (const float*)d_in[1];
    const float* shifts = (const float*)d_in[2];
    const int*   ei     = (const int*)d_in[3];
    const int*   batch  = (const int*)d_in[4];
    const float* W_emb  = (const float*)d_in[6];
    const float* ae     = (const float*)d_in[7];
    const float* W_r    = (const float*)d_in[8];   // (2,8,F)
    const float* w_sh   = (const float*)d_in[9];   // (2,16)
    const float* W_out  = (const float*)d_in[10];  // (2,F,F)
    const float* W_skip = (const float*)d_in[11];  // (2,10,F)
    const float* w_read = (const float*)d_in[12];  // (2,F)

    const float* Wr0 = W_r;
    const float* Wr1 = W_r + NBES * FF;
    const float* Wout0 = W_out;
    const float* Wout1 = W_out + FF * FF;

    float* energy = (float*)d_out;
    float* forces = energy + GG;

    float* ws  = (float*)d_ws;
    float* h1  = ws;                        // N*F
    float* P0  = h1 + (size_t)NN * FF;      // N*80
    float* M   = P0 + (size_t)NN * 80;      // N*80
    float* E1  = M + (size_t)NN * 80;       // N*8
    float* t1  = E1 + (size_t)NN * 8;       // N*8
    float* node_e = t1 + (size_t)NN * 8;    // N
    float* rec = node_e + NN;               // EE*8
    float* ebs1 = rec + (size_t)EE * RECW;  // EE*8
    float4* gvp = (float4*)(ebs1 + (size_t)EE * 8);  // EE*4 floats
    float* a1  = (float*)(gvp + EE);        // 128
    float* askip = a1 + FF;                 // 16
    float* c0  = askip + 16;                // 128
    float* D   = c0 + FF;                   // 8*128
    float* GW  = D + NBES * FF;             // 80*128
    float* T   = GW + 80 * FF;              // 640
    float* Mc  = T + 640;                   // 80

    int* cnt    = (int*)(Mc + 80);          // 2N*CSTR (padded counters)
    int* off    = cnt + (size_t)2 * NN * CSTR;  // 2(N+1)
    int* rank_r = off + 2 * (NN + 1);       // EE
    int* rank_s = rank_r + EE;              // EE
    int* jr     = rank_s + EE;              // EE
    int* js     = jr + EE;                  // EE
    int* psl_j  = js + EE;                  // EE
    int* parts  = psl_j + EE;               // 2*NB
    const int* off_rcv = off;
    const int* off_snd = off + (NN + 1);

    const int edgeBlocks = (EE + 255) / 256;
    const int nodeBlocks = (NN + 255) / 256;

    hipMemsetAsync(d_out, 0, (size_t)out_size * sizeof(float), stream);
    hipMemsetAsync(cnt, 0, (size_t)2 * NN * CSTR * sizeof(int), stream);

    // CSR build: sector-padded histogram atomics; parallel 3-phase scan
    count_kernel<<<edgeBlocks, 256, 0, stream>>>(ei, cnt, rank_r, rank_s);
    scan_partial<<<2 * NB, 256, 0, stream>>>(cnt, parts);
    scan_parts<<<1, 256, 0, stream>>>(parts, off);
    scan_apply<<<2 * NB, 256, 0, stream>>>(cnt, parts, off);
    fill_kernel<<<edgeBlocks, 256, 0, stream>>>(ei, off, rank_r, rank_s, jr, js, psl_j);

    // small precomputes
    a1_kernel<<<1, 128, 0, stream>>>(Wout1, w_read + FF, W_skip + 10 * FF, ae, a1, askip);
    cd_kernel<<<1, 128, 0, stream>>>(Wout0, w_read, a1, Wr1, c0, D);
    gw_kernel<<<40, 256, 0, stream>>>(W_emb, Wr0, Wout0, GW);
    tmc_kernel<<<1, 256, 0, stream>>>(D, c0, W_emb, Wr0, T, Mc);

    // geometry records (rcv order) + eb*s1 (snd order); ebs0 eliminated
    edge_geom<<<edgeBlocks, 256, 0, stream>>>(pos, shifts, ei, w_sh, jr, js, rec, ebs1);

    // E1: contiguous stream over ebs1
    e1_csr<<<(NN * 8 + 255) / 256, 256, 0, stream>>>(ebs1, off_snd, E1);

    // P0 (lane-parallel edges, recompute es from rec), then h1, t1, M
    p0_kernel<<<P0_BLOCKS, 256, 0, stream>>>(rec, off_rcv, attrs, P0);
    h1_gemm<<<GEMM_BLOCKS, 256, 0, stream>>>(P0, GW, attrs, W_skip, w_read, h1, node_e);
    t1_kernel<<<(NN + 3) / 4, 256, 0, stream>>>(h1, a1, Wr1, t1);
    m_kernel<<<nodeBlocks, 256, 0, stream>>>(E1, T, Mc, M);

    // fused per-edge: recompute radial, dsp/drp both layers, layer-1 energy, gv
    edge_pass<<<EP_BLOCKS, 256, 0, stream>>>(rec, t1, M, attrs, batch, w_sh, gvp, energy);

    // forces via CSR gather (no atomics)
    force_gather<<<nodeBlocks, 256, 0, stream>>>(off_rcv, off_snd, psl_j, gvp, forces);

    // energy finalize (layer-0 node energies + layer-1 skip + e0)
    efinal_kernel<<<EF_BLOCKS, 256, 0, stream>>>(node_e, attrs, askip, batch, energy);
}